// Round 1
// baseline (11167.117 us; speedup 1.0000x reference)
//
#include <hip/hip_runtime.h>
#include <math.h>

#define N_NODES 50000
#define N_EDGES 1600000
#define HID 256
// eps = 0

// ---------------------------------------------------------------- layer 1 ---
// per-edge: msg = relu(x[src] + edge_attr@We1 + be1)  (2 channels); atomic to aggr1
__global__ void edge1_kernel(const float* __restrict__ x,
                             const int* __restrict__ src,
                             const int* __restrict__ dst,
                             const float* __restrict__ ea,
                             const float* __restrict__ We1,   // [7][2]
                             const float* __restrict__ be1,   // [2]
                             float* __restrict__ aggr1) {     // [N][2] zeroed
    int e = blockIdx.x * blockDim.x + threadIdx.x;
    if (e >= N_EDGES) return;
    int s = src[e], d = dst[e];
    float m0 = be1[0], m1 = be1[1];
#pragma unroll
    for (int i = 0; i < 7; ++i) {
        float a = ea[e * 7 + i];
        m0 = fmaf(a, We1[i * 2 + 0], m0);
        m1 = fmaf(a, We1[i * 2 + 1], m1);
    }
    m0 = fmaxf(m0 + x[s * 2 + 0], 0.f);
    m1 = fmaxf(m1 + x[s * 2 + 1], 0.f);
    atomicAdd(&aggr1[d * 2 + 0], m0);
    atomicAdd(&aggr1[d * 2 + 1], m1);
}

// h1r = relu((x + aggr1) @ W1 + b1)   [N][256]
__global__ void node1_kernel(const float* __restrict__ x,
                             const float* __restrict__ aggr1,
                             const float* __restrict__ W1,    // [2][256]
                             const float* __restrict__ b1,    // [256]
                             float* __restrict__ hr) {
    int idx = blockIdx.x * blockDim.x + threadIdx.x;
    int n = idx >> 6;
    if (n >= N_NODES) return;
    int c = (idx & 63) * 4;
    float t0 = x[n * 2 + 0] + aggr1[n * 2 + 0];
    float t1 = x[n * 2 + 1] + aggr1[n * 2 + 1];
    float4 w0 = *(const float4*)&W1[c];
    float4 w1 = *(const float4*)&W1[256 + c];
    float4 bb = *(const float4*)&b1[c];
    float4 r;
    r.x = fmaxf(fmaf(t0, w0.x, fmaf(t1, w1.x, bb.x)), 0.f);
    r.y = fmaxf(fmaf(t0, w0.y, fmaf(t1, w1.y, bb.y)), 0.f);
    r.z = fmaxf(fmaf(t0, w0.z, fmaf(t1, w1.z, bb.z)), 0.f);
    r.w = fmaxf(fmaf(t0, w0.w, fmaf(t1, w1.w, bb.w)), 0.f);
    *(float4*)&hr[n * HID + c] = r;
}

// ------------------------------------------------------------ layers 2..3 ---
// one wave per edge (grid-stride). lane owns 4 channels; We2 cols in registers.
// accum pre-initialized with hr (the (1+eps)*h term); we atomically add msgs.
__global__ __launch_bounds__(256) void edge2_kernel(
        const float* __restrict__ hr,     // gather source [N][256]
        const int* __restrict__ src,
        const int* __restrict__ dst,
        const float* __restrict__ ea,     // [E][7]
        const float* __restrict__ We2,    // [7][256]
        const float* __restrict__ be2,    // [256]
        float* __restrict__ accum) {      // [N][256] pre-init = hr
    const int lane = threadIdx.x & 63;
    const int wid = threadIdx.x >> 6;     // 0..3
    const int c4 = lane * 4;
    float4 w[7];
#pragma unroll
    for (int i = 0; i < 7; ++i) w[i] = *(const float4*)&We2[i * HID + c4];
    const float4 bb = *(const float4*)&be2[c4];
    const int wavesTotal = gridDim.x * 4;
    for (int e = blockIdx.x * 4 + wid; e < N_EDGES; e += wavesTotal) {
        int s = src[e], d = dst[e];
        float4 m = bb;
#pragma unroll
        for (int i = 0; i < 7; ++i) {
            float a = ea[e * 7 + i];
            m.x = fmaf(a, w[i].x, m.x);
            m.y = fmaf(a, w[i].y, m.y);
            m.z = fmaf(a, w[i].z, m.z);
            m.w = fmaf(a, w[i].w, m.w);
        }
        const float4 hv = *(const float4*)&hr[(size_t)s * HID + c4];
        m.x = fmaxf(m.x + hv.x, 0.f);
        m.y = fmaxf(m.y + hv.y, 0.f);
        m.z = fmaxf(m.z + hv.z, 0.f);
        m.w = fmaxf(m.w + hv.w, 0.f);
        float* ap = &accum[(size_t)d * HID + c4];
        atomicAdd(ap + 0, m.x);
        atomicAdd(ap + 1, m.y);
        atomicAdd(ap + 2, m.z);
        atomicAdd(ap + 3, m.w);
    }
}

// out = relu(T @ W2 + b2), T = accum = h + aggr.  64-node x 256-col tile.
#define BN 64
#define BK 32
#define TPITCH 36
#define WPITCH 260
__global__ __launch_bounds__(256) void node2_kernel(
        const float* __restrict__ T,    // [N][256]
        const float* __restrict__ W,    // [256][256]
        const float* __restrict__ b,    // [256]
        float* __restrict__ out) {      // [N][256] (relu'd)
    __shared__ float Ts[BN * TPITCH];
    __shared__ float Ws[BK * WPITCH];
    const int t = threadIdx.x;
    const int n0 = blockIdx.x * BN;
    const int cc = t & 31;   // cols 8*cc .. 8*cc+7
    const int nn = t >> 5;   // nodes n0 + nn*8 .. +7
    float acc[8][8];
#pragma unroll
    for (int i = 0; i < 8; ++i)
#pragma unroll
        for (int j = 0; j < 8; ++j) acc[i][j] = 0.f;

    for (int k0 = 0; k0 < HID; k0 += BK) {
        __syncthreads();
        {   // stage T: rows t>>2, 8 floats at koff=(t&3)*8
            int row = t >> 2;
            int koff = (t & 3) * 8;
            int n = n0 + row;
            float4 v0 = make_float4(0.f, 0.f, 0.f, 0.f), v1 = v0;
            if (n < N_NODES) {
                v0 = *(const float4*)&T[(size_t)n * HID + k0 + koff];
                v1 = *(const float4*)&T[(size_t)n * HID + k0 + koff + 4];
            }
            *(float4*)&Ts[row * TPITCH + koff] = v0;
            *(float4*)&Ts[row * TPITCH + koff + 4] = v1;
        }
        {   // stage W: row t>>3, 8 float4s at cols (t&7)*4 + i*32
            int row = t >> 3;
            int cbase = (t & 7) * 4;
            const float* wg = &W[(size_t)(k0 + row) * HID];
            float* wl = &Ws[row * WPITCH];
#pragma unroll
            for (int i = 0; i < 8; ++i)
                *(float4*)&wl[cbase + i * 32] = *(const float4*)&wg[cbase + i * 32];
        }
        __syncthreads();
#pragma unroll
        for (int k = 0; k < BK; ++k) {
            float4 wa = *(const float4*)&Ws[k * WPITCH + cc * 8];
            float4 wb = *(const float4*)&Ws[k * WPITCH + cc * 8 + 4];
#pragma unroll
            for (int i = 0; i < 8; ++i) {
                float a = Ts[(nn * 8 + i) * TPITCH + k];
                acc[i][0] = fmaf(a, wa.x, acc[i][0]);
                acc[i][1] = fmaf(a, wa.y, acc[i][1]);
                acc[i][2] = fmaf(a, wa.z, acc[i][2]);
                acc[i][3] = fmaf(a, wa.w, acc[i][3]);
                acc[i][4] = fmaf(a, wb.x, acc[i][4]);
                acc[i][5] = fmaf(a, wb.y, acc[i][5]);
                acc[i][6] = fmaf(a, wb.z, acc[i][6]);
                acc[i][7] = fmaf(a, wb.w, acc[i][7]);
            }
        }
    }
    float4 b0 = *(const float4*)&b[cc * 8];
    float4 b1v = *(const float4*)&b[cc * 8 + 4];
#pragma unroll
    for (int i = 0; i < 8; ++i) {
        int n = n0 + nn * 8 + i;
        if (n < N_NODES) {
            float4 r0, r1;
            r0.x = fmaxf(acc[i][0] + b0.x, 0.f);
            r0.y = fmaxf(acc[i][1] + b0.y, 0.f);
            r0.z = fmaxf(acc[i][2] + b0.z, 0.f);
            r0.w = fmaxf(acc[i][3] + b0.w, 0.f);
            r1.x = fmaxf(acc[i][4] + b1v.x, 0.f);
            r1.y = fmaxf(acc[i][5] + b1v.y, 0.f);
            r1.z = fmaxf(acc[i][6] + b1v.z, 0.f);
            r1.w = fmaxf(acc[i][7] + b1v.w, 0.f);
            *(float4*)&out[(size_t)n * HID + cc * 8] = r0;
            *(float4*)&out[(size_t)n * HID + cc * 8 + 4] = r1;
        }
    }
}

// ------------------------------------------------------------------ final ---
// out[n] = sigmoid(dot(hr[n], Wend) + bend); one wave per node
__global__ void end_kernel(const float* __restrict__ hr,
                           const float* __restrict__ Wend,  // [256]
                           const float* __restrict__ bend,  // [1]
                           float* __restrict__ out) {
    int n = blockIdx.x * 4 + (threadIdx.x >> 6);
    if (n >= N_NODES) return;
    int lane = threadIdx.x & 63;
    float4 h4 = *(const float4*)&hr[(size_t)n * HID + lane * 4];
    float4 w4 = *(const float4*)&Wend[lane * 4];
    float s = h4.x * w4.x + h4.y * w4.y + h4.z * w4.z + h4.w * w4.w;
#pragma unroll
    for (int off = 32; off > 0; off >>= 1) s += __shfl_down(s, off);
    if (lane == 0) out[n] = 1.f / (1.f + expf(-(s + bend[0])));
}

// ------------------------------------------------------------------ launch ---
extern "C" void kernel_launch(void* const* d_in, const int* in_sizes, int n_in,
                              void* d_out, int out_size, void* d_ws, size_t ws_size,
                              hipStream_t stream) {
    const float* x    = (const float*)d_in[0];
    const int*   ei   = (const int*)d_in[1];
    const float* ea   = (const float*)d_in[2];
    const float* We1  = (const float*)d_in[3];
    const float* be1  = (const float*)d_in[4];
    const float* W1   = (const float*)d_in[5];
    const float* b1   = (const float*)d_in[6];
    const float* We2  = (const float*)d_in[7];
    const float* be2  = (const float*)d_in[8];
    const float* W2   = (const float*)d_in[9];
    const float* b2   = (const float*)d_in[10];
    const float* Wend = (const float*)d_in[11];
    const float* bend = (const float*)d_in[12];
    float* out = (float*)d_out;

    const int* src = ei;
    const int* dst = ei + N_EDGES;

    const size_t HN = (size_t)N_NODES * HID;          // 12.8M floats
    float* A     = (float*)d_ws;                      // hr (current)
    float* B     = A + HN;                            // accum = h + aggr
    float* aggr1 = B + HN;                            // [N][2]

    // ---- layer 1
    hipMemsetAsync(aggr1, 0, (size_t)N_NODES * 2 * sizeof(float), stream);
    edge1_kernel<<<(N_EDGES + 255) / 256, 256, 0, stream>>>(x, src, dst, ea, We1, be1, aggr1);
    node1_kernel<<<(N_NODES * 64 + 255) / 256, 256, 0, stream>>>(x, aggr1, W1, b1, A);

    // ---- layers 2 and 3 (shared weights)
    for (int l = 0; l < 2; ++l) {
        hipMemcpyAsync(B, A, HN * sizeof(float), hipMemcpyDeviceToDevice, stream);
        edge2_kernel<<<8192, 256, 0, stream>>>(A, src, dst, ea, We2, be2, B);
        node2_kernel<<<(N_NODES + BN - 1) / BN, 256, 0, stream>>>(B, W2, b2, A);
    }

    // ---- head
    end_kernel<<<(N_NODES + 3) / 4, 256, 0, stream>>>(A, Wend, bend, out);
}

// Round 2
// 1318.268 us; speedup vs baseline: 8.4711x; 8.4711x over previous
//
#include <hip/hip_runtime.h>
#include <math.h>

#define N_NODES 50000
#define N_EDGES 1600000
#define HID 256
// eps = 0

// ---------------------------------------------------------------- CSR build ---
__global__ void hist_kernel(const int* __restrict__ dst, int* __restrict__ deg) {
    int e = blockIdx.x * blockDim.x + threadIdx.x;
    if (e < N_EDGES) atomicAdd(&deg[dst[e]], 1);
}

// single-block exclusive scan: 256 threads, each owns a contiguous chunk
__global__ __launch_bounds__(256) void scan_kernel(const int* __restrict__ deg,
                                                   int* __restrict__ base) {
    __shared__ int sums[256];
    const int CHUNK = (N_NODES + 255) / 256;  // 196
    const int t = threadIdx.x;
    const int start = t * CHUNK;
    int s = 0;
    for (int i = 0; i < CHUNK; ++i) {
        int idx = start + i;
        if (idx < N_NODES) s += deg[idx];
    }
    sums[t] = s;
    __syncthreads();
    // Kogge-Stone inclusive scan in LDS
    for (int off = 1; off < 256; off <<= 1) {
        int v = (t >= off) ? sums[t - off] : 0;
        __syncthreads();
        sums[t] += v;
        __syncthreads();
    }
    int run = (t == 0) ? 0 : sums[t - 1];  // exclusive offset of this chunk
    for (int i = 0; i < CHUNK; ++i) {
        int idx = start + i;
        if (idx < N_NODES) {
            base[idx] = run;
            run += deg[idx];
        }
    }
    if (t == 255) base[N_NODES] = run;  // total = N_EDGES
}

__global__ void scatter_kernel(const int* __restrict__ src,
                               const int* __restrict__ dst,
                               const int* __restrict__ base,
                               int* __restrict__ cursor,
                               int* __restrict__ csr_src,
                               int* __restrict__ csr_eid) {
    int e = blockIdx.x * blockDim.x + threadIdx.x;
    if (e >= N_EDGES) return;
    int d = dst[e];
    int pos = base[d] + atomicAdd(&cursor[d], 1);
    csr_src[pos] = src[e];
    csr_eid[pos] = e;
}

// ---------------------------------------------------------------- layer 1 ---
// per-edge: msg = relu(x[src] + edge_attr@We1 + be1)  (2 channels); atomic to aggr1
__global__ void edge1_kernel(const float* __restrict__ x,
                             const int* __restrict__ src,
                             const int* __restrict__ dst,
                             const float* __restrict__ ea,
                             const float* __restrict__ We1,   // [7][2]
                             const float* __restrict__ be1,   // [2]
                             float* __restrict__ aggr1) {     // [N][2] zeroed
    int e = blockIdx.x * blockDim.x + threadIdx.x;
    if (e >= N_EDGES) return;
    int s = src[e], d = dst[e];
    float m0 = be1[0], m1 = be1[1];
#pragma unroll
    for (int i = 0; i < 7; ++i) {
        float a = ea[e * 7 + i];
        m0 = fmaf(a, We1[i * 2 + 0], m0);
        m1 = fmaf(a, We1[i * 2 + 1], m1);
    }
    m0 = fmaxf(m0 + x[s * 2 + 0], 0.f);
    m1 = fmaxf(m1 + x[s * 2 + 1], 0.f);
    atomicAdd(&aggr1[d * 2 + 0], m0);
    atomicAdd(&aggr1[d * 2 + 1], m1);
}

// h1r = relu((x + aggr1) @ W1 + b1)   [N][256]
__global__ void node1_kernel(const float* __restrict__ x,
                             const float* __restrict__ aggr1,
                             const float* __restrict__ W1,    // [2][256]
                             const float* __restrict__ b1,    // [256]
                             float* __restrict__ hr) {
    int idx = blockIdx.x * blockDim.x + threadIdx.x;
    int n = idx >> 6;
    if (n >= N_NODES) return;
    int c = (idx & 63) * 4;
    float t0 = x[n * 2 + 0] + aggr1[n * 2 + 0];
    float t1 = x[n * 2 + 1] + aggr1[n * 2 + 1];
    float4 w0 = *(const float4*)&W1[c];
    float4 w1 = *(const float4*)&W1[256 + c];
    float4 bb = *(const float4*)&b1[c];
    float4 r;
    r.x = fmaxf(fmaf(t0, w0.x, fmaf(t1, w1.x, bb.x)), 0.f);
    r.y = fmaxf(fmaf(t0, w0.y, fmaf(t1, w1.y, bb.y)), 0.f);
    r.z = fmaxf(fmaf(t0, w0.z, fmaf(t1, w1.z, bb.z)), 0.f);
    r.w = fmaxf(fmaf(t0, w0.w, fmaf(t1, w1.w, bb.w)), 0.f);
    *(float4*)&hr[n * HID + c] = r;
}

// ------------------------------------------------------------ layers 2..3 ---
// CSR gather: one wave per destination node. Lane owns 4 channels; We2 cols in
// registers; accumulate in registers (init = h[n], the (1+eps)*h term).
__global__ __launch_bounds__(256) void aggr2_kernel(
        const float* __restrict__ hr,       // gather source [N][256]
        const int* __restrict__ csr_src,    // [E] sorted by dst
        const int* __restrict__ csr_eid,    // [E]
        const float* __restrict__ ea,       // [E][7]
        const float* __restrict__ We2,      // [7][256]
        const float* __restrict__ be2,      // [256]
        const int* __restrict__ base,       // [N+1]
        float* __restrict__ accum) {        // [N][256] out
    const int lane = threadIdx.x & 63;
    const int wid = threadIdx.x >> 6;       // 0..3
    const int n = blockIdx.x * 4 + wid;
    if (n >= N_NODES) return;
    const int c4 = lane * 4;
    float4 w[7];
#pragma unroll
    for (int i = 0; i < 7; ++i) w[i] = *(const float4*)&We2[i * HID + c4];
    const float4 bb = *(const float4*)&be2[c4];

    float4 acc = *(const float4*)&hr[(size_t)n * HID + c4];
    const int s0 = base[n], s1 = base[n + 1];

    int pos = s0;
    int sp = 0, ep = 0;
    if (pos < s1) { sp = csr_src[pos]; ep = csr_eid[pos]; }
    while (pos < s1) {
        const int s = sp, e = ep;
        const int nxt = pos + 1;
        if (nxt < s1) { sp = csr_src[nxt]; ep = csr_eid[nxt]; }  // prefetch
        const float4 hv = *(const float4*)&hr[(size_t)s * HID + c4];
        float a0 = ea[e * 7 + 0], a1 = ea[e * 7 + 1], a2 = ea[e * 7 + 2],
              a3 = ea[e * 7 + 3], a4 = ea[e * 7 + 4], a5 = ea[e * 7 + 5],
              a6 = ea[e * 7 + 6];
        float4 m = bb;
        m.x = fmaf(a0, w[0].x, m.x); m.y = fmaf(a0, w[0].y, m.y);
        m.z = fmaf(a0, w[0].z, m.z); m.w = fmaf(a0, w[0].w, m.w);
        m.x = fmaf(a1, w[1].x, m.x); m.y = fmaf(a1, w[1].y, m.y);
        m.z = fmaf(a1, w[1].z, m.z); m.w = fmaf(a1, w[1].w, m.w);
        m.x = fmaf(a2, w[2].x, m.x); m.y = fmaf(a2, w[2].y, m.y);
        m.z = fmaf(a2, w[2].z, m.z); m.w = fmaf(a2, w[2].w, m.w);
        m.x = fmaf(a3, w[3].x, m.x); m.y = fmaf(a3, w[3].y, m.y);
        m.z = fmaf(a3, w[3].z, m.z); m.w = fmaf(a3, w[3].w, m.w);
        m.x = fmaf(a4, w[4].x, m.x); m.y = fmaf(a4, w[4].y, m.y);
        m.z = fmaf(a4, w[4].z, m.z); m.w = fmaf(a4, w[4].w, m.w);
        m.x = fmaf(a5, w[5].x, m.x); m.y = fmaf(a5, w[5].y, m.y);
        m.z = fmaf(a5, w[5].z, m.z); m.w = fmaf(a5, w[5].w, m.w);
        m.x = fmaf(a6, w[6].x, m.x); m.y = fmaf(a6, w[6].y, m.y);
        m.z = fmaf(a6, w[6].z, m.z); m.w = fmaf(a6, w[6].w, m.w);
        acc.x += fmaxf(m.x + hv.x, 0.f);
        acc.y += fmaxf(m.y + hv.y, 0.f);
        acc.z += fmaxf(m.z + hv.z, 0.f);
        acc.w += fmaxf(m.w + hv.w, 0.f);
        pos = nxt;
    }
    *(float4*)&accum[(size_t)n * HID + c4] = acc;
}

// out = relu(T @ W2 + b2), T = accum = h + aggr.  64-node x 256-col tile.
#define BN 64
#define BK 32
#define TPITCH 36
#define WPITCH 260
__global__ __launch_bounds__(256) void node2_kernel(
        const float* __restrict__ T,    // [N][256]
        const float* __restrict__ W,    // [256][256]
        const float* __restrict__ b,    // [256]
        float* __restrict__ out) {      // [N][256] (relu'd)
    __shared__ float Ts[BN * TPITCH];
    __shared__ float Ws[BK * WPITCH];
    const int t = threadIdx.x;
    const int n0 = blockIdx.x * BN;
    const int cc = t & 31;   // cols 8*cc .. 8*cc+7
    const int nn = t >> 5;   // nodes n0 + nn*8 .. +7
    float acc[8][8];
#pragma unroll
    for (int i = 0; i < 8; ++i)
#pragma unroll
        for (int j = 0; j < 8; ++j) acc[i][j] = 0.f;

    for (int k0 = 0; k0 < HID; k0 += BK) {
        __syncthreads();
        {   // stage T
            int row = t >> 2;
            int koff = (t & 3) * 8;
            int n = n0 + row;
            float4 v0 = make_float4(0.f, 0.f, 0.f, 0.f), v1 = v0;
            if (n < N_NODES) {
                v0 = *(const float4*)&T[(size_t)n * HID + k0 + koff];
                v1 = *(const float4*)&T[(size_t)n * HID + k0 + koff + 4];
            }
            *(float4*)&Ts[row * TPITCH + koff] = v0;
            *(float4*)&Ts[row * TPITCH + koff + 4] = v1;
        }
        {   // stage W
            int row = t >> 3;
            int cbase = (t & 7) * 4;
            const float* wg = &W[(size_t)(k0 + row) * HID];
            float* wl = &Ws[row * WPITCH];
#pragma unroll
            for (int i = 0; i < 8; ++i)
                *(float4*)&wl[cbase + i * 32] = *(const float4*)&wg[cbase + i * 32];
        }
        __syncthreads();
#pragma unroll
        for (int k = 0; k < BK; ++k) {
            float4 wa = *(const float4*)&Ws[k * WPITCH + cc * 8];
            float4 wb = *(const float4*)&Ws[k * WPITCH + cc * 8 + 4];
#pragma unroll
            for (int i = 0; i < 8; ++i) {
                float a = Ts[(nn * 8 + i) * TPITCH + k];
                acc[i][0] = fmaf(a, wa.x, acc[i][0]);
                acc[i][1] = fmaf(a, wa.y, acc[i][1]);
                acc[i][2] = fmaf(a, wa.z, acc[i][2]);
                acc[i][3] = fmaf(a, wa.w, acc[i][3]);
                acc[i][4] = fmaf(a, wb.x, acc[i][4]);
                acc[i][5] = fmaf(a, wb.y, acc[i][5]);
                acc[i][6] = fmaf(a, wb.z, acc[i][6]);
                acc[i][7] = fmaf(a, wb.w, acc[i][7]);
            }
        }
    }
    float4 b0 = *(const float4*)&b[cc * 8];
    float4 b1v = *(const float4*)&b[cc * 8 + 4];
#pragma unroll
    for (int i = 0; i < 8; ++i) {
        int n = n0 + nn * 8 + i;
        if (n < N_NODES) {
            float4 r0, r1;
            r0.x = fmaxf(acc[i][0] + b0.x, 0.f);
            r0.y = fmaxf(acc[i][1] + b0.y, 0.f);
            r0.z = fmaxf(acc[i][2] + b0.z, 0.f);
            r0.w = fmaxf(acc[i][3] + b0.w, 0.f);
            r1.x = fmaxf(acc[i][4] + b1v.x, 0.f);
            r1.y = fmaxf(acc[i][5] + b1v.y, 0.f);
            r1.z = fmaxf(acc[i][6] + b1v.z, 0.f);
            r1.w = fmaxf(acc[i][7] + b1v.w, 0.f);
            *(float4*)&out[(size_t)n * HID + cc * 8] = r0;
            *(float4*)&out[(size_t)n * HID + cc * 8 + 4] = r1;
        }
    }
}

// ------------------------------------------------------------------ final ---
__global__ void end_kernel(const float* __restrict__ hr,
                           const float* __restrict__ Wend,  // [256]
                           const float* __restrict__ bend,  // [1]
                           float* __restrict__ out) {
    int n = blockIdx.x * 4 + (threadIdx.x >> 6);
    if (n >= N_NODES) return;
    int lane = threadIdx.x & 63;
    float4 h4 = *(const float4*)&hr[(size_t)n * HID + lane * 4];
    float4 w4 = *(const float4*)&Wend[lane * 4];
    float s = h4.x * w4.x + h4.y * w4.y + h4.z * w4.z + h4.w * w4.w;
#pragma unroll
    for (int off = 32; off > 0; off >>= 1) s += __shfl_down(s, off);
    if (lane == 0) out[n] = 1.f / (1.f + expf(-(s + bend[0])));
}

// ------------------------------------------------------------------ launch ---
extern "C" void kernel_launch(void* const* d_in, const int* in_sizes, int n_in,
                              void* d_out, int out_size, void* d_ws, size_t ws_size,
                              hipStream_t stream) {
    const float* x    = (const float*)d_in[0];
    const int*   ei   = (const int*)d_in[1];
    const float* ea   = (const float*)d_in[2];
    const float* We1  = (const float*)d_in[3];
    const float* be1  = (const float*)d_in[4];
    const float* W1   = (const float*)d_in[5];
    const float* b1   = (const float*)d_in[6];
    const float* We2  = (const float*)d_in[7];
    const float* be2  = (const float*)d_in[8];
    const float* W2   = (const float*)d_in[9];
    const float* b2   = (const float*)d_in[10];
    const float* Wend = (const float*)d_in[11];
    const float* bend = (const float*)d_in[12];
    float* out = (float*)d_out;

    const int* src = ei;
    const int* dst = ei + N_EDGES;

    const size_t HN = (size_t)N_NODES * HID;          // 12.8M floats
    float* A      = (float*)d_ws;                     // hr (current)
    float* B      = A + HN;                           // accum = h + aggr
    float* aggr1  = B + HN;                           // [N][2]
    int*   deg    = (int*)(aggr1 + 2 * N_NODES);      // [N]
    int*   base   = deg + N_NODES;                    // [N+1]
    int*   cursor = base + N_NODES + 2;               // [N]
    int*   csr_src = cursor + N_NODES;                // [E]
    int*   csr_eid = csr_src + N_EDGES;               // [E]
    // total ≈ 117 MB

    // ---- CSR build (shared by both gather layers)
    hipMemsetAsync(deg, 0, (size_t)N_NODES * sizeof(int), stream);
    hipMemsetAsync(cursor, 0, (size_t)N_NODES * sizeof(int), stream);
    hist_kernel<<<(N_EDGES + 255) / 256, 256, 0, stream>>>(dst, deg);
    scan_kernel<<<1, 256, 0, stream>>>(deg, base);
    scatter_kernel<<<(N_EDGES + 255) / 256, 256, 0, stream>>>(src, dst, base, cursor,
                                                              csr_src, csr_eid);

    // ---- layer 1
    hipMemsetAsync(aggr1, 0, (size_t)N_NODES * 2 * sizeof(float), stream);
    edge1_kernel<<<(N_EDGES + 255) / 256, 256, 0, stream>>>(x, src, dst, ea, We1, be1, aggr1);
    node1_kernel<<<(N_NODES * 64 + 255) / 256, 256, 0, stream>>>(x, aggr1, W1, b1, A);

    // ---- layers 2 and 3 (shared weights)
    for (int l = 0; l < 2; ++l) {
        aggr2_kernel<<<(N_NODES + 3) / 4, 256, 0, stream>>>(A, csr_src, csr_eid, ea,
                                                            We2, be2, base, B);
        node2_kernel<<<(N_NODES + BN - 1) / BN, 256, 0, stream>>>(B, W2, b2, A);
    }

    // ---- head
    end_kernel<<<(N_NODES + 3) / 4, 256, 0, stream>>>(A, Wend, bend, out);
}

// Round 3
// 1097.180 us; speedup vs baseline: 10.1780x; 1.2015x over previous
//
#include <hip/hip_runtime.h>
#include <math.h>

#define N_NODES 50000
#define N_EDGES 1600000
#define HID 256
// eps = 0

// ---------------------------------------------------------------- CSR build ---
__global__ void hist_kernel(const int* __restrict__ dst, int* __restrict__ deg) {
    int e = blockIdx.x * blockDim.x + threadIdx.x;
    if (e < N_EDGES) atomicAdd(&deg[dst[e]], 1);
}

// single-block exclusive scan: 256 threads, each owns a contiguous chunk
__global__ __launch_bounds__(256) void scan_kernel(const int* __restrict__ deg,
                                                   int* __restrict__ base) {
    __shared__ int sums[256];
    const int CHUNK = (N_NODES + 255) / 256;  // 196
    const int t = threadIdx.x;
    const int start = t * CHUNK;
    int s = 0;
    for (int i = 0; i < CHUNK; ++i) {
        int idx = start + i;
        if (idx < N_NODES) s += deg[idx];
    }
    sums[t] = s;
    __syncthreads();
    for (int off = 1; off < 256; off <<= 1) {
        int v = (t >= off) ? sums[t - off] : 0;
        __syncthreads();
        sums[t] += v;
        __syncthreads();
    }
    int run = (t == 0) ? 0 : sums[t - 1];
    for (int i = 0; i < CHUNK; ++i) {
        int idx = start + i;
        if (idx < N_NODES) {
            base[idx] = run;
            run += deg[idx];
        }
    }
    if (t == 255) base[N_NODES] = run;
}

// build dst-sorted 32B records: {ea0..ea6, src_bits}
__global__ void scatter_rec_kernel(const int* __restrict__ src,
                                   const int* __restrict__ dst,
                                   const float* __restrict__ ea,
                                   const int* __restrict__ base,
                                   int* __restrict__ cursor,
                                   float* __restrict__ rec) {
    int e = blockIdx.x * blockDim.x + threadIdx.x;
    if (e >= N_EDGES) return;
    int d = dst[e];
    int pos = base[d] + atomicAdd(&cursor[d], 1);
    const float* ep = ea + (size_t)e * 7;
    float a0 = ep[0], a1 = ep[1], a2 = ep[2], a3 = ep[3];
    float a4 = ep[4], a5 = ep[5], a6 = ep[6];
    float* rp = rec + (size_t)pos * 8;
    *(float4*)rp       = make_float4(a0, a1, a2, a3);
    *(float4*)(rp + 4) = make_float4(a4, a5, a6, __int_as_float(src[e]));
}

// ---------------------------------------------------------------- layer 1 ---
// gather over records: one wave per node, lanes stride edges, 2 channels
__global__ __launch_bounds__(256) void aggr1_kernel(
        const float* __restrict__ x,     // [N][2]
        const float* __restrict__ rec,   // [E][8]
        const int* __restrict__ base,    // [N+1]
        const float* __restrict__ We1,   // [7][2]
        const float* __restrict__ be1,   // [2]
        float* __restrict__ aggr1) {     // [N][2]
    const int lane = threadIdx.x & 63;
    const int wid = threadIdx.x >> 6;
    const int n = blockIdx.x * 4 + wid;
    if (n >= N_NODES) return;
    float w00 = We1[0],  w01 = We1[1],  w10 = We1[2],  w11 = We1[3];
    float w20 = We1[4],  w21 = We1[5],  w30 = We1[6],  w31 = We1[7];
    float w40 = We1[8],  w41 = We1[9],  w50 = We1[10], w51 = We1[11];
    float w60 = We1[12], w61 = We1[13];
    float bb0 = be1[0], bb1 = be1[1];
    float m0 = 0.f, m1 = 0.f;
    const int s0 = base[n], s1 = base[n + 1];
    for (int pos = s0 + lane; pos < s1; pos += 64) {
        const float* p = rec + (size_t)pos * 8;
        float4 a = *(const float4*)p;
        float4 b = *(const float4*)(p + 4);
        int s = __float_as_int(b.w);
        float t0 = bb0, t1 = bb1;
        t0 = fmaf(a.x, w00, t0); t1 = fmaf(a.x, w01, t1);
        t0 = fmaf(a.y, w10, t0); t1 = fmaf(a.y, w11, t1);
        t0 = fmaf(a.z, w20, t0); t1 = fmaf(a.z, w21, t1);
        t0 = fmaf(a.w, w30, t0); t1 = fmaf(a.w, w31, t1);
        t0 = fmaf(b.x, w40, t0); t1 = fmaf(b.x, w41, t1);
        t0 = fmaf(b.y, w50, t0); t1 = fmaf(b.y, w51, t1);
        t0 = fmaf(b.z, w60, t0); t1 = fmaf(b.z, w61, t1);
        float2 xv = *(const float2*)&x[(size_t)s * 2];
        m0 += fmaxf(t0 + xv.x, 0.f);
        m1 += fmaxf(t1 + xv.y, 0.f);
    }
#pragma unroll
    for (int off = 32; off > 0; off >>= 1) {
        m0 += __shfl_down(m0, off);
        m1 += __shfl_down(m1, off);
    }
    if (lane == 0) {
        aggr1[n * 2 + 0] = m0;
        aggr1[n * 2 + 1] = m1;
    }
}

// h1r = relu((x + aggr1) @ W1 + b1)   [N][256]
__global__ void node1_kernel(const float* __restrict__ x,
                             const float* __restrict__ aggr1,
                             const float* __restrict__ W1,    // [2][256]
                             const float* __restrict__ b1,    // [256]
                             float* __restrict__ hr) {
    int idx = blockIdx.x * blockDim.x + threadIdx.x;
    int n = idx >> 6;
    if (n >= N_NODES) return;
    int c = (idx & 63) * 4;
    float t0 = x[n * 2 + 0] + aggr1[n * 2 + 0];
    float t1 = x[n * 2 + 1] + aggr1[n * 2 + 1];
    float4 w0 = *(const float4*)&W1[c];
    float4 w1 = *(const float4*)&W1[256 + c];
    float4 bb = *(const float4*)&b1[c];
    float4 r;
    r.x = fmaxf(fmaf(t0, w0.x, fmaf(t1, w1.x, bb.x)), 0.f);
    r.y = fmaxf(fmaf(t0, w0.y, fmaf(t1, w1.y, bb.y)), 0.f);
    r.z = fmaxf(fmaf(t0, w0.z, fmaf(t1, w1.z, bb.z)), 0.f);
    r.w = fmaxf(fmaf(t0, w0.w, fmaf(t1, w1.w, bb.w)), 0.f);
    *(float4*)&hr[n * HID + c] = r;
}

// ------------------------------------------------------------ layers 2..3 ---
// CSR gather over sorted records, software-pipelined: record 2-ahead, h 1-ahead.
__global__ __launch_bounds__(256) void aggr2_kernel(
        const float* __restrict__ hr,     // [N][256]
        const float* __restrict__ rec,    // [E][8] dst-sorted {ea0..6, src}
        const int* __restrict__ base,     // [N+1]
        const float* __restrict__ We2,    // [7][256]
        const float* __restrict__ be2,    // [256]
        float* __restrict__ accum) {      // [N][256] out
    const int lane = threadIdx.x & 63;
    const int wid = threadIdx.x >> 6;
    const int n = blockIdx.x * 4 + wid;
    if (n >= N_NODES) return;
    const int c4 = lane * 4;
    float4 w0 = *(const float4*)&We2[0 * HID + c4];
    float4 w1 = *(const float4*)&We2[1 * HID + c4];
    float4 w2 = *(const float4*)&We2[2 * HID + c4];
    float4 w3 = *(const float4*)&We2[3 * HID + c4];
    float4 w4 = *(const float4*)&We2[4 * HID + c4];
    float4 w5 = *(const float4*)&We2[5 * HID + c4];
    float4 w6 = *(const float4*)&We2[6 * HID + c4];
    const float4 bb = *(const float4*)&be2[c4];

    float4 acc = *(const float4*)&hr[(size_t)n * HID + c4];
    const int s0 = base[n];
    const int deg = base[n + 1] - s0;
    if (deg > 0) {
        const float* rp = rec + (size_t)s0 * 8;
        const int last = deg - 1;
        // clamped record fetch (uniform address; redundant re-loads hit cache)
        const float* p0 = rp;
        float4 ra = *(const float4*)p0, rb = *(const float4*)(p0 + 4);
        const float* p1 = rp + (size_t)((1 < last) ? 1 : last) * 8;
        float4 na = *(const float4*)p1, nb = *(const float4*)(p1 + 4);
        float4 h0 = *(const float4*)&hr[(size_t)__float_as_int(rb.w) * HID + c4];
        for (int i = 0; i < deg; ++i) {
            // issue next h row (depends only on nb, already resident)
            float4 h1 = *(const float4*)&hr[(size_t)__float_as_int(nb.w) * HID + c4];
            // prefetch record i+2 (clamped)
            int j = i + 2; j = (j < last) ? j : last;
            const float* p2 = rp + (size_t)j * 8;
            float4 ta = *(const float4*)p2, tb = *(const float4*)(p2 + 4);
            // compute with current record + current h row
            float4 m = bb;
            m.x = fmaf(ra.x, w0.x, m.x); m.y = fmaf(ra.x, w0.y, m.y);
            m.z = fmaf(ra.x, w0.z, m.z); m.w = fmaf(ra.x, w0.w, m.w);
            m.x = fmaf(ra.y, w1.x, m.x); m.y = fmaf(ra.y, w1.y, m.y);
            m.z = fmaf(ra.y, w1.z, m.z); m.w = fmaf(ra.y, w1.w, m.w);
            m.x = fmaf(ra.z, w2.x, m.x); m.y = fmaf(ra.z, w2.y, m.y);
            m.z = fmaf(ra.z, w2.z, m.z); m.w = fmaf(ra.z, w2.w, m.w);
            m.x = fmaf(ra.w, w3.x, m.x); m.y = fmaf(ra.w, w3.y, m.y);
            m.z = fmaf(ra.w, w3.z, m.z); m.w = fmaf(ra.w, w3.w, m.w);
            m.x = fmaf(rb.x, w4.x, m.x); m.y = fmaf(rb.x, w4.y, m.y);
            m.z = fmaf(rb.x, w4.z, m.z); m.w = fmaf(rb.x, w4.w, m.w);
            m.x = fmaf(rb.y, w5.x, m.x); m.y = fmaf(rb.y, w5.y, m.y);
            m.z = fmaf(rb.y, w5.z, m.z); m.w = fmaf(rb.y, w5.w, m.w);
            m.x = fmaf(rb.z, w6.x, m.x); m.y = fmaf(rb.z, w6.y, m.y);
            m.z = fmaf(rb.z, w6.z, m.z); m.w = fmaf(rb.z, w6.w, m.w);
            acc.x += fmaxf(m.x + h0.x, 0.f);
            acc.y += fmaxf(m.y + h0.y, 0.f);
            acc.z += fmaxf(m.z + h0.z, 0.f);
            acc.w += fmaxf(m.w + h0.w, 0.f);
            ra = na; rb = nb; na = ta; nb = tb; h0 = h1;
        }
    }
    *(float4*)&accum[(size_t)n * HID + c4] = acc;
}

// out = relu(T @ W2 + b2); optionally fused final head (sigmoid(relu·Wend+bend))
#define BN 64
#define BK 32
#define TPITCH 36
#define WPITCH 260
template <bool FUSE_END>
__global__ __launch_bounds__(256) void node2_kernel(
        const float* __restrict__ T,    // [N][256]
        const float* __restrict__ W,    // [256][256]
        const float* __restrict__ b,    // [256]
        const float* __restrict__ Wend, // [256] (FUSE_END)
        const float* __restrict__ bend, // [1]   (FUSE_END)
        float* __restrict__ out) {      // [N][256] or [N][1]
    __shared__ float Ts[BN * TPITCH];
    __shared__ float Ws[BK * WPITCH];
    const int t = threadIdx.x;
    const int n0 = blockIdx.x * BN;
    const int cc = t & 31;
    const int nn = t >> 5;
    float acc[8][8];
#pragma unroll
    for (int i = 0; i < 8; ++i)
#pragma unroll
        for (int j = 0; j < 8; ++j) acc[i][j] = 0.f;

    for (int k0 = 0; k0 < HID; k0 += BK) {
        __syncthreads();
        {   // stage T
            int row = t >> 2;
            int koff = (t & 3) * 8;
            int n = n0 + row;
            float4 v0 = make_float4(0.f, 0.f, 0.f, 0.f), v1 = v0;
            if (n < N_NODES) {
                v0 = *(const float4*)&T[(size_t)n * HID + k0 + koff];
                v1 = *(const float4*)&T[(size_t)n * HID + k0 + koff + 4];
            }
            *(float4*)&Ts[row * TPITCH + koff] = v0;
            *(float4*)&Ts[row * TPITCH + koff + 4] = v1;
        }
        {   // stage W
            int row = t >> 3;
            int cbase = (t & 7) * 4;
            const float* wg = &W[(size_t)(k0 + row) * HID];
            float* wl = &Ws[row * WPITCH];
#pragma unroll
            for (int i = 0; i < 8; ++i)
                *(float4*)&wl[cbase + i * 32] = *(const float4*)&wg[cbase + i * 32];
        }
        __syncthreads();
#pragma unroll
        for (int k = 0; k < BK; ++k) {
            float4 wa = *(const float4*)&Ws[k * WPITCH + cc * 8];
            float4 wb = *(const float4*)&Ws[k * WPITCH + cc * 8 + 4];
#pragma unroll
            for (int i = 0; i < 8; ++i) {
                float a = Ts[(nn * 8 + i) * TPITCH + k];
                acc[i][0] = fmaf(a, wa.x, acc[i][0]);
                acc[i][1] = fmaf(a, wa.y, acc[i][1]);
                acc[i][2] = fmaf(a, wa.z, acc[i][2]);
                acc[i][3] = fmaf(a, wa.w, acc[i][3]);
                acc[i][4] = fmaf(a, wb.x, acc[i][4]);
                acc[i][5] = fmaf(a, wb.y, acc[i][5]);
                acc[i][6] = fmaf(a, wb.z, acc[i][6]);
                acc[i][7] = fmaf(a, wb.w, acc[i][7]);
            }
        }
    }
    float4 b0 = *(const float4*)&b[cc * 8];
    float4 b1v = *(const float4*)&b[cc * 8 + 4];
    if (!FUSE_END) {
#pragma unroll
        for (int i = 0; i < 8; ++i) {
            int n = n0 + nn * 8 + i;
            if (n < N_NODES) {
                float4 r0, r1;
                r0.x = fmaxf(acc[i][0] + b0.x, 0.f);
                r0.y = fmaxf(acc[i][1] + b0.y, 0.f);
                r0.z = fmaxf(acc[i][2] + b0.z, 0.f);
                r0.w = fmaxf(acc[i][3] + b0.w, 0.f);
                r1.x = fmaxf(acc[i][4] + b1v.x, 0.f);
                r1.y = fmaxf(acc[i][5] + b1v.y, 0.f);
                r1.z = fmaxf(acc[i][6] + b1v.z, 0.f);
                r1.w = fmaxf(acc[i][7] + b1v.w, 0.f);
                *(float4*)&out[(size_t)n * HID + cc * 8] = r0;
                *(float4*)&out[(size_t)n * HID + cc * 8 + 4] = r1;
            }
        }
    } else {
        // per-thread partial dot of relu(row) with Wend, reduce in LDS
        float4 we0 = *(const float4*)&Wend[cc * 8];
        float4 we1 = *(const float4*)&Wend[cc * 8 + 4];
        __syncthreads();               // done reading Ts; reuse as reduce buf
        float* red = Ts;               // [64][33]
#pragma unroll
        for (int i = 0; i < 8; ++i) {
            float p = 0.f;
            p = fmaf(fmaxf(acc[i][0] + b0.x, 0.f), we0.x, p);
            p = fmaf(fmaxf(acc[i][1] + b0.y, 0.f), we0.y, p);
            p = fmaf(fmaxf(acc[i][2] + b0.z, 0.f), we0.z, p);
            p = fmaf(fmaxf(acc[i][3] + b0.w, 0.f), we0.w, p);
            p = fmaf(fmaxf(acc[i][4] + b1v.x, 0.f), we1.x, p);
            p = fmaf(fmaxf(acc[i][5] + b1v.y, 0.f), we1.y, p);
            p = fmaf(fmaxf(acc[i][6] + b1v.z, 0.f), we1.z, p);
            p = fmaf(fmaxf(acc[i][7] + b1v.w, 0.f), we1.w, p);
            red[(nn * 8 + i) * 33 + cc] = p;
        }
        __syncthreads();
        if (t < 64) {
            int n = n0 + t;
            if (n < N_NODES) {
                float s = 0.f;
#pragma unroll
                for (int j = 0; j < 32; ++j) s += red[t * 33 + j];
                out[n] = 1.f / (1.f + expf(-(s + bend[0])));
            }
        }
    }
}

// ------------------------------------------------------------------ launch ---
extern "C" void kernel_launch(void* const* d_in, const int* in_sizes, int n_in,
                              void* d_out, int out_size, void* d_ws, size_t ws_size,
                              hipStream_t stream) {
    const float* x    = (const float*)d_in[0];
    const int*   ei   = (const int*)d_in[1];
    const float* ea   = (const float*)d_in[2];
    const float* We1  = (const float*)d_in[3];
    const float* be1  = (const float*)d_in[4];
    const float* W1   = (const float*)d_in[5];
    const float* b1   = (const float*)d_in[6];
    const float* We2  = (const float*)d_in[7];
    const float* be2  = (const float*)d_in[8];
    const float* W2   = (const float*)d_in[9];
    const float* b2   = (const float*)d_in[10];
    const float* Wend = (const float*)d_in[11];
    const float* bend = (const float*)d_in[12];
    float* out = (float*)d_out;

    const int* src = ei;
    const int* dst = ei + N_EDGES;

    const size_t HN = (size_t)N_NODES * HID;          // 12.8M floats
    float* A      = (float*)d_ws;                     // [N][256]
    float* B      = A + HN;                           // [N][256]
    float* rec    = B + HN;                           // [E][8]
    float* aggr1  = rec + (size_t)N_EDGES * 8;        // [N][2]
    int*   deg    = (int*)(aggr1 + 2 * N_NODES);      // [N]
    int*   cursor = deg + N_NODES;                    // [N]
    int*   base   = cursor + N_NODES;                 // [N+1]
    // total ≈ 154 MB

    // ---- CSR build + record sort (shared by all 3 layers)
    hipMemsetAsync(deg, 0, (size_t)N_NODES * 2 * sizeof(int), stream);  // deg+cursor
    hist_kernel<<<(N_EDGES + 255) / 256, 256, 0, stream>>>(dst, deg);
    scan_kernel<<<1, 256, 0, stream>>>(deg, base);
    scatter_rec_kernel<<<(N_EDGES + 255) / 256, 256, 0, stream>>>(src, dst, ea, base,
                                                                  cursor, rec);

    // ---- layer 1
    aggr1_kernel<<<(N_NODES + 3) / 4, 256, 0, stream>>>(x, rec, base, We1, be1, aggr1);
    node1_kernel<<<(N_NODES * 64 + 255) / 256, 256, 0, stream>>>(x, aggr1, W1, b1, A);

    // ---- layer 2
    aggr2_kernel<<<(N_NODES + 3) / 4, 256, 0, stream>>>(A, rec, base, We2, be2, B);
    node2_kernel<false><<<(N_NODES + BN - 1) / BN, 256, 0, stream>>>(B, W2, b2,
                                                                     nullptr, nullptr, A);
    // ---- layer 3 + head (fused)
    aggr2_kernel<<<(N_NODES + 3) / 4, 256, 0, stream>>>(A, rec, base, We2, be2, B);
    node2_kernel<true><<<(N_NODES + BN - 1) / BN, 256, 0, stream>>>(B, W2, b2,
                                                                    Wend, bend, out);
}

// Round 4
// 966.022 us; speedup vs baseline: 11.5599x; 1.1358x over previous
//
#include <hip/hip_runtime.h>
#include <math.h>

#define N_NODES 50000
#define N_EDGES 1600000
#define HID 256
#define SCAN_B 196   // ceil(N_NODES/256)
// eps = 0

// ---------------------------------------------------------------- CSR build ---
__global__ void hist_kernel(const int* __restrict__ dst, int* __restrict__ deg) {
    int e = blockIdx.x * blockDim.x + threadIdx.x;
    if (e < N_EDGES) atomicAdd(&deg[dst[e]], 1);
}

// per-256-node-group sums
__global__ __launch_bounds__(256) void scan1_kernel(const int* __restrict__ deg,
                                                    int* __restrict__ bsum) {
    int idx = blockIdx.x * 256 + threadIdx.x;
    int v = (idx < N_NODES) ? deg[idx] : 0;
#pragma unroll
    for (int off = 32; off > 0; off >>= 1) v += __shfl_down(v, off);
    __shared__ int ws[4];
    if ((threadIdx.x & 63) == 0) ws[threadIdx.x >> 6] = v;
    __syncthreads();
    if (threadIdx.x == 0) bsum[blockIdx.x] = ws[0] + ws[1] + ws[2] + ws[3];
}

// exclusive scan of the group sums (single small block)
__global__ __launch_bounds__(256) void scan2_kernel(int* __restrict__ bsum) {
    __shared__ int s[256];
    int t = threadIdx.x;
    int v = (t < SCAN_B) ? bsum[t] : 0;
    s[t] = v;
    __syncthreads();
    for (int off = 1; off < 256; off <<= 1) {
        int u = (t >= off) ? s[t - off] : 0;
        __syncthreads();
        s[t] += u;
        __syncthreads();
    }
    if (t < SCAN_B) bsum[t] = s[t] - v;  // exclusive
}

// per-group local exclusive scan + group offset -> base
__global__ __launch_bounds__(256) void scan3_kernel(const int* __restrict__ deg,
                                                    const int* __restrict__ bsum,
                                                    int* __restrict__ base) {
    __shared__ int s[256];
    int t = threadIdx.x;
    int idx = blockIdx.x * 256 + t;
    int v = (idx < N_NODES) ? deg[idx] : 0;
    s[t] = v;
    __syncthreads();
    for (int off = 1; off < 256; off <<= 1) {
        int u = (t >= off) ? s[t - off] : 0;
        __syncthreads();
        s[t] += u;
        __syncthreads();
    }
    if (idx < N_NODES) base[idx] = bsum[blockIdx.x] + s[t] - v;
    if (idx == 0) base[N_NODES] = N_EDGES;
}

// build dst-sorted 32B records: {ea0..ea6, src_bits}
__global__ void scatter_rec_kernel(const int* __restrict__ src,
                                   const int* __restrict__ dst,
                                   const float* __restrict__ ea,
                                   const int* __restrict__ base,
                                   int* __restrict__ cursor,
                                   float* __restrict__ rec) {
    int e = blockIdx.x * blockDim.x + threadIdx.x;
    if (e >= N_EDGES) return;
    int d = dst[e];
    int pos = base[d] + atomicAdd(&cursor[d], 1);
    const float* ep = ea + (size_t)e * 7;
    float a0 = ep[0], a1 = ep[1], a2 = ep[2], a3 = ep[3];
    float a4 = ep[4], a5 = ep[5], a6 = ep[6];
    float* rp = rec + (size_t)pos * 8;
    *(float4*)rp       = make_float4(a0, a1, a2, a3);
    *(float4*)(rp + 4) = make_float4(a4, a5, a6, __int_as_float(src[e]));
}

// ---------------------------------------------------------------- layer 1 ---
// fused gather + node MLP: one wave per node.
__global__ __launch_bounds__(256) void layer1_kernel(
        const float* __restrict__ x,     // [N][2]
        const float* __restrict__ rec,   // [E][8]
        const int* __restrict__ base,    // [N+1]
        const float* __restrict__ We1,   // [7][2]
        const float* __restrict__ be1,   // [2]
        const float* __restrict__ W1,    // [2][256]
        const float* __restrict__ b1,    // [256]
        float* __restrict__ hr) {        // [N][256]
    const int lane = threadIdx.x & 63;
    const int wid = threadIdx.x >> 6;
    const int n = blockIdx.x * 4 + wid;
    if (n >= N_NODES) return;
    float w00 = We1[0],  w01 = We1[1],  w10 = We1[2],  w11 = We1[3];
    float w20 = We1[4],  w21 = We1[5],  w30 = We1[6],  w31 = We1[7];
    float w40 = We1[8],  w41 = We1[9],  w50 = We1[10], w51 = We1[11];
    float w60 = We1[12], w61 = We1[13];
    float bb0 = be1[0], bb1 = be1[1];
    float m0 = 0.f, m1 = 0.f;
    const int s0 = base[n], s1 = base[n + 1];
    for (int pos = s0 + lane; pos < s1; pos += 64) {
        const float* p = rec + (size_t)pos * 8;
        float4 a = *(const float4*)p;
        float4 b = *(const float4*)(p + 4);
        int s = __float_as_int(b.w);
        float t0 = bb0, t1 = bb1;
        t0 = fmaf(a.x, w00, t0); t1 = fmaf(a.x, w01, t1);
        t0 = fmaf(a.y, w10, t0); t1 = fmaf(a.y, w11, t1);
        t0 = fmaf(a.z, w20, t0); t1 = fmaf(a.z, w21, t1);
        t0 = fmaf(a.w, w30, t0); t1 = fmaf(a.w, w31, t1);
        t0 = fmaf(b.x, w40, t0); t1 = fmaf(b.x, w41, t1);
        t0 = fmaf(b.y, w50, t0); t1 = fmaf(b.y, w51, t1);
        t0 = fmaf(b.z, w60, t0); t1 = fmaf(b.z, w61, t1);
        float2 xv = *(const float2*)&x[(size_t)s * 2];
        m0 += fmaxf(t0 + xv.x, 0.f);
        m1 += fmaxf(t1 + xv.y, 0.f);
    }
#pragma unroll
    for (int off = 32; off > 0; off >>= 1) {
        m0 += __shfl_down(m0, off);
        m1 += __shfl_down(m1, off);
    }
    m0 = __shfl(m0, 0);
    m1 = __shfl(m1, 0);
    const float t0 = x[n * 2 + 0] + m0;
    const float t1 = x[n * 2 + 1] + m1;
    const int c = lane * 4;
    float4 wa = *(const float4*)&W1[c];
    float4 wb = *(const float4*)&W1[256 + c];
    float4 bv = *(const float4*)&b1[c];
    float4 r;
    r.x = fmaxf(fmaf(t0, wa.x, fmaf(t1, wb.x, bv.x)), 0.f);
    r.y = fmaxf(fmaf(t0, wa.y, fmaf(t1, wb.y, bv.y)), 0.f);
    r.z = fmaxf(fmaf(t0, wa.z, fmaf(t1, wb.z, bv.z)), 0.f);
    r.w = fmaxf(fmaf(t0, wa.w, fmaf(t1, wb.w, bv.w)), 0.f);
    *(float4*)&hr[(size_t)n * HID + c] = r;
}

// ------------------------------------------------------------ layers 2..3 ---
// CSR gather, 4-wide edge groups: 4 h-rows in flight + next group's records
// prefetched. One wave per node; lane owns 4 channels.
#define EDGE(RA, RB, HV)                                              \
    do {                                                              \
        float4 m = bb;                                                \
        m.x = fmaf(RA.x, w0.x, m.x); m.y = fmaf(RA.x, w0.y, m.y);     \
        m.z = fmaf(RA.x, w0.z, m.z); m.w = fmaf(RA.x, w0.w, m.w);     \
        m.x = fmaf(RA.y, w1.x, m.x); m.y = fmaf(RA.y, w1.y, m.y);     \
        m.z = fmaf(RA.y, w1.z, m.z); m.w = fmaf(RA.y, w1.w, m.w);     \
        m.x = fmaf(RA.z, w2.x, m.x); m.y = fmaf(RA.z, w2.y, m.y);     \
        m.z = fmaf(RA.z, w2.z, m.z); m.w = fmaf(RA.z, w2.w, m.w);     \
        m.x = fmaf(RA.w, w3.x, m.x); m.y = fmaf(RA.w, w3.y, m.y);     \
        m.z = fmaf(RA.w, w3.z, m.z); m.w = fmaf(RA.w, w3.w, m.w);     \
        m.x = fmaf(RB.x, w4.x, m.x); m.y = fmaf(RB.x, w4.y, m.y);     \
        m.z = fmaf(RB.x, w4.z, m.z); m.w = fmaf(RB.x, w4.w, m.w);     \
        m.x = fmaf(RB.y, w5.x, m.x); m.y = fmaf(RB.y, w5.y, m.y);     \
        m.z = fmaf(RB.y, w5.z, m.z); m.w = fmaf(RB.y, w5.w, m.w);     \
        m.x = fmaf(RB.z, w6.x, m.x); m.y = fmaf(RB.z, w6.y, m.y);     \
        m.z = fmaf(RB.z, w6.z, m.z); m.w = fmaf(RB.z, w6.w, m.w);     \
        acc.x += fmaxf(m.x + HV.x, 0.f);                              \
        acc.y += fmaxf(m.y + HV.y, 0.f);                              \
        acc.z += fmaxf(m.z + HV.z, 0.f);                              \
        acc.w += fmaxf(m.w + HV.w, 0.f);                              \
    } while (0)

__global__ __launch_bounds__(256) void aggr2_kernel(
        const float* __restrict__ hr,     // [N][256]
        const float* __restrict__ rec,    // [E][8] dst-sorted {ea0..6, src}
        const int* __restrict__ base,     // [N+1]
        const float* __restrict__ We2,    // [7][256]
        const float* __restrict__ be2,    // [256]
        float* __restrict__ accum) {      // [N][256] out
    const int lane = threadIdx.x & 63;
    const int wid = threadIdx.x >> 6;
    const int n = blockIdx.x * 4 + wid;
    if (n >= N_NODES) return;
    const int c4 = lane * 4;
    float4 w0 = *(const float4*)&We2[0 * HID + c4];
    float4 w1 = *(const float4*)&We2[1 * HID + c4];
    float4 w2 = *(const float4*)&We2[2 * HID + c4];
    float4 w3 = *(const float4*)&We2[3 * HID + c4];
    float4 w4 = *(const float4*)&We2[4 * HID + c4];
    float4 w5 = *(const float4*)&We2[5 * HID + c4];
    float4 w6 = *(const float4*)&We2[6 * HID + c4];
    const float4 bb = *(const float4*)&be2[c4];

    float4 acc = *(const float4*)&hr[(size_t)n * HID + c4];
    const int s0 = base[n];
    const int deg = base[n + 1] - s0;
    const float* rp = rec + (size_t)s0 * 8;
    const int ng = deg & ~3;

    if (ng > 0) {
        float4 ca0 = *(const float4*)(rp + 0),  cb0 = *(const float4*)(rp + 4);
        float4 ca1 = *(const float4*)(rp + 8),  cb1 = *(const float4*)(rp + 12);
        float4 ca2 = *(const float4*)(rp + 16), cb2 = *(const float4*)(rp + 20);
        float4 ca3 = *(const float4*)(rp + 24), cb3 = *(const float4*)(rp + 28);
        for (int g = 4; ; g += 4) {
            // 4 independent h-row loads for the current group
            float4 h0 = *(const float4*)&hr[(size_t)__float_as_int(cb0.w) * HID + c4];
            float4 h1 = *(const float4*)&hr[(size_t)__float_as_int(cb1.w) * HID + c4];
            float4 h2 = *(const float4*)&hr[(size_t)__float_as_int(cb2.w) * HID + c4];
            float4 h3 = *(const float4*)&hr[(size_t)__float_as_int(cb3.w) * HID + c4];
            // prefetch next group's records (clamped re-read of last group: L1-hit)
            const float* np = rp + (size_t)((g < ng) ? g : (g - 4)) * 8;
            float4 ta0 = *(const float4*)(np + 0),  tb0 = *(const float4*)(np + 4);
            float4 ta1 = *(const float4*)(np + 8),  tb1 = *(const float4*)(np + 12);
            float4 ta2 = *(const float4*)(np + 16), tb2 = *(const float4*)(np + 20);
            float4 ta3 = *(const float4*)(np + 24), tb3 = *(const float4*)(np + 28);
            EDGE(ca0, cb0, h0);
            EDGE(ca1, cb1, h1);
            EDGE(ca2, cb2, h2);
            EDGE(ca3, cb3, h3);
            if (g >= ng) break;
            ca0 = ta0; cb0 = tb0; ca1 = ta1; cb1 = tb1;
            ca2 = ta2; cb2 = tb2; ca3 = ta3; cb3 = tb3;
        }
    }
    for (int p = ng; p < deg; ++p) {  // remainder 0..3 edges
        const float* pp = rp + (size_t)p * 8;
        float4 ra = *(const float4*)pp, rb = *(const float4*)(pp + 4);
        float4 hv = *(const float4*)&hr[(size_t)__float_as_int(rb.w) * HID + c4];
        EDGE(ra, rb, hv);
    }
    *(float4*)&accum[(size_t)n * HID + c4] = acc;
}

// out = relu(T @ W2 + b2); optionally fused final head (sigmoid(relu·Wend+bend))
#define BN 64
#define BK 32
#define TPITCH 36
#define WPITCH 260
template <bool FUSE_END>
__global__ __launch_bounds__(256) void node2_kernel(
        const float* __restrict__ T,    // [N][256]
        const float* __restrict__ W,    // [256][256]
        const float* __restrict__ b,    // [256]
        const float* __restrict__ Wend, // [256] (FUSE_END)
        const float* __restrict__ bend, // [1]   (FUSE_END)
        float* __restrict__ out) {      // [N][256] or [N][1]
    __shared__ float Ts[BN * TPITCH];
    __shared__ float Ws[BK * WPITCH];
    const int t = threadIdx.x;
    const int n0 = blockIdx.x * BN;
    const int cc = t & 31;
    const int nn = t >> 5;
    float acc[8][8];
#pragma unroll
    for (int i = 0; i < 8; ++i)
#pragma unroll
        for (int j = 0; j < 8; ++j) acc[i][j] = 0.f;

    for (int k0 = 0; k0 < HID; k0 += BK) {
        __syncthreads();
        {   // stage T
            int row = t >> 2;
            int koff = (t & 3) * 8;
            int n = n0 + row;
            float4 v0 = make_float4(0.f, 0.f, 0.f, 0.f), v1 = v0;
            if (n < N_NODES) {
                v0 = *(const float4*)&T[(size_t)n * HID + k0 + koff];
                v1 = *(const float4*)&T[(size_t)n * HID + k0 + koff + 4];
            }
            *(float4*)&Ts[row * TPITCH + koff] = v0;
            *(float4*)&Ts[row * TPITCH + koff + 4] = v1;
        }
        {   // stage W
            int row = t >> 3;
            int cbase = (t & 7) * 4;
            const float* wg = &W[(size_t)(k0 + row) * HID];
            float* wl = &Ws[row * WPITCH];
#pragma unroll
            for (int i = 0; i < 8; ++i)
                *(float4*)&wl[cbase + i * 32] = *(const float4*)&wg[cbase + i * 32];
        }
        __syncthreads();
#pragma unroll
        for (int k = 0; k < BK; ++k) {
            float4 wa = *(const float4*)&Ws[k * WPITCH + cc * 8];
            float4 wb = *(const float4*)&Ws[k * WPITCH + cc * 8 + 4];
#pragma unroll
            for (int i = 0; i < 8; ++i) {
                float a = Ts[(nn * 8 + i) * TPITCH + k];
                acc[i][0] = fmaf(a, wa.x, acc[i][0]);
                acc[i][1] = fmaf(a, wa.y, acc[i][1]);
                acc[i][2] = fmaf(a, wa.z, acc[i][2]);
                acc[i][3] = fmaf(a, wa.w, acc[i][3]);
                acc[i][4] = fmaf(a, wb.x, acc[i][4]);
                acc[i][5] = fmaf(a, wb.y, acc[i][5]);
                acc[i][6] = fmaf(a, wb.z, acc[i][6]);
                acc[i][7] = fmaf(a, wb.w, acc[i][7]);
            }
        }
    }
    float4 b0 = *(const float4*)&b[cc * 8];
    float4 b1v = *(const float4*)&b[cc * 8 + 4];
    if (!FUSE_END) {
#pragma unroll
        for (int i = 0; i < 8; ++i) {
            int n = n0 + nn * 8 + i;
            if (n < N_NODES) {
                float4 r0, r1;
                r0.x = fmaxf(acc[i][0] + b0.x, 0.f);
                r0.y = fmaxf(acc[i][1] + b0.y, 0.f);
                r0.z = fmaxf(acc[i][2] + b0.z, 0.f);
                r0.w = fmaxf(acc[i][3] + b0.w, 0.f);
                r1.x = fmaxf(acc[i][4] + b1v.x, 0.f);
                r1.y = fmaxf(acc[i][5] + b1v.y, 0.f);
                r1.z = fmaxf(acc[i][6] + b1v.z, 0.f);
                r1.w = fmaxf(acc[i][7] + b1v.w, 0.f);
                *(float4*)&out[(size_t)n * HID + cc * 8] = r0;
                *(float4*)&out[(size_t)n * HID + cc * 8 + 4] = r1;
            }
        }
    } else {
        float4 we0 = *(const float4*)&Wend[cc * 8];
        float4 we1 = *(const float4*)&Wend[cc * 8 + 4];
        __syncthreads();               // done reading Ts; reuse as reduce buf
        float* red = Ts;               // [64][33]
#pragma unroll
        for (int i = 0; i < 8; ++i) {
            float p = 0.f;
            p = fmaf(fmaxf(acc[i][0] + b0.x, 0.f), we0.x, p);
            p = fmaf(fmaxf(acc[i][1] + b0.y, 0.f), we0.y, p);
            p = fmaf(fmaxf(acc[i][2] + b0.z, 0.f), we0.z, p);
            p = fmaf(fmaxf(acc[i][3] + b0.w, 0.f), we0.w, p);
            p = fmaf(fmaxf(acc[i][4] + b1v.x, 0.f), we1.x, p);
            p = fmaf(fmaxf(acc[i][5] + b1v.y, 0.f), we1.y, p);
            p = fmaf(fmaxf(acc[i][6] + b1v.z, 0.f), we1.z, p);
            p = fmaf(fmaxf(acc[i][7] + b1v.w, 0.f), we1.w, p);
            red[(nn * 8 + i) * 33 + cc] = p;
        }
        __syncthreads();
        if (t < 64) {
            int n = n0 + t;
            if (n < N_NODES) {
                float s = 0.f;
#pragma unroll
                for (int j = 0; j < 32; ++j) s += red[t * 33 + j];
                out[n] = 1.f / (1.f + expf(-(s + bend[0])));
            }
        }
    }
}

// ------------------------------------------------------------------ launch ---
extern "C" void kernel_launch(void* const* d_in, const int* in_sizes, int n_in,
                              void* d_out, int out_size, void* d_ws, size_t ws_size,
                              hipStream_t stream) {
    const float* x    = (const float*)d_in[0];
    const int*   ei   = (const int*)d_in[1];
    const float* ea   = (const float*)d_in[2];
    const float* We1  = (const float*)d_in[3];
    const float* be1  = (const float*)d_in[4];
    const float* W1   = (const float*)d_in[5];
    const float* b1   = (const float*)d_in[6];
    const float* We2  = (const float*)d_in[7];
    const float* be2  = (const float*)d_in[8];
    const float* W2   = (const float*)d_in[9];
    const float* b2   = (const float*)d_in[10];
    const float* Wend = (const float*)d_in[11];
    const float* bend = (const float*)d_in[12];
    float* out = (float*)d_out;

    const int* src = ei;
    const int* dst = ei + N_EDGES;

    const size_t HN = (size_t)N_NODES * HID;          // 12.8M floats
    float* A      = (float*)d_ws;                     // [N][256]
    float* B      = A + HN;                           // [N][256]
    float* rec    = B + HN;                           // [E][8]
    int*   deg    = (int*)(rec + (size_t)N_EDGES * 8);// [N]
    int*   cursor = deg + N_NODES;                    // [N]
    int*   base   = cursor + N_NODES;                 // [N+2]
    int*   bsum   = base + N_NODES + 2;               // [256]
    // total ≈ 154 MB

    // ---- CSR build + record sort (shared by all 3 layers)
    hipMemsetAsync(deg, 0, (size_t)N_NODES * 2 * sizeof(int), stream);  // deg+cursor
    hist_kernel<<<(N_EDGES + 255) / 256, 256, 0, stream>>>(dst, deg);
    scan1_kernel<<<SCAN_B, 256, 0, stream>>>(deg, bsum);
    scan2_kernel<<<1, 256, 0, stream>>>(bsum);
    scan3_kernel<<<SCAN_B, 256, 0, stream>>>(deg, bsum, base);
    scatter_rec_kernel<<<(N_EDGES + 255) / 256, 256, 0, stream>>>(src, dst, ea, base,
                                                                  cursor, rec);

    // ---- layer 1 (fused gather + MLP)
    layer1_kernel<<<(N_NODES + 3) / 4, 256, 0, stream>>>(x, rec, base, We1, be1,
                                                         W1, b1, A);

    // ---- layer 2
    aggr2_kernel<<<(N_NODES + 3) / 4, 256, 0, stream>>>(A, rec, base, We2, be2, B);
    node2_kernel<false><<<(N_NODES + BN - 1) / BN, 256, 0, stream>>>(B, W2, b2,
                                                                     nullptr, nullptr, A);
    // ---- layer 3 + head (fused)
    aggr2_kernel<<<(N_NODES + 3) / 4, 256, 0, stream>>>(A, rec, base, We2, be2, B);
    node2_kernel<true><<<(N_NODES + BN - 1) / BN, 256, 0, stream>>>(B, W2, b2,
                                                                    Wend, bend, out);
}

// Round 5
// 964.676 us; speedup vs baseline: 11.5760x; 1.0014x over previous
//
#include <hip/hip_runtime.h>
#include <math.h>

#define N_NODES 50000
#define N_EDGES 1600000
#define HID 256
#define SCAN_B 196   // ceil(N_NODES/256)
// eps = 0

// ---------------------------------------------------------------- CSR build ---
__global__ void hist_kernel(const int* __restrict__ dst, int* __restrict__ deg) {
    int e = blockIdx.x * blockDim.x + threadIdx.x;
    if (e < N_EDGES) atomicAdd(&deg[dst[e]], 1);
}

// per-256-node-group sums
__global__ __launch_bounds__(256) void scan1_kernel(const int* __restrict__ deg,
                                                    int* __restrict__ bsum) {
    int idx = blockIdx.x * 256 + threadIdx.x;
    int v = (idx < N_NODES) ? deg[idx] : 0;
#pragma unroll
    for (int off = 32; off > 0; off >>= 1) v += __shfl_down(v, off);
    __shared__ int ws[4];
    if ((threadIdx.x & 63) == 0) ws[threadIdx.x >> 6] = v;
    __syncthreads();
    if (threadIdx.x == 0) bsum[blockIdx.x] = ws[0] + ws[1] + ws[2] + ws[3];
}

// exclusive scan of the group sums (single small block)
__global__ __launch_bounds__(256) void scan2_kernel(int* __restrict__ bsum) {
    __shared__ int s[256];
    int t = threadIdx.x;
    int v = (t < SCAN_B) ? bsum[t] : 0;
    s[t] = v;
    __syncthreads();
    for (int off = 1; off < 256; off <<= 1) {
        int u = (t >= off) ? s[t - off] : 0;
        __syncthreads();
        s[t] += u;
        __syncthreads();
    }
    if (t < SCAN_B) bsum[t] = s[t] - v;  // exclusive
}

// per-group local exclusive scan + group offset -> base
__global__ __launch_bounds__(256) void scan3_kernel(const int* __restrict__ deg,
                                                    const int* __restrict__ bsum,
                                                    int* __restrict__ base) {
    __shared__ int s[256];
    int t = threadIdx.x;
    int idx = blockIdx.x * 256 + t;
    int v = (idx < N_NODES) ? deg[idx] : 0;
    s[t] = v;
    __syncthreads();
    for (int off = 1; off < 256; off <<= 1) {
        int u = (t >= off) ? s[t - off] : 0;
        __syncthreads();
        s[t] += u;
        __syncthreads();
    }
    if (idx < N_NODES) base[idx] = bsum[blockIdx.x] + s[t] - v;
    if (idx == 0) base[N_NODES] = N_EDGES;
}

// build dst-sorted 32B records: {ea0..ea6, src_bits}
__global__ void scatter_rec_kernel(const int* __restrict__ src,
                                   const int* __restrict__ dst,
                                   const float* __restrict__ ea,
                                   const int* __restrict__ base,
                                   int* __restrict__ cursor,
                                   float* __restrict__ rec) {
    int e = blockIdx.x * blockDim.x + threadIdx.x;
    if (e >= N_EDGES) return;
    int d = dst[e];
    int pos = base[d] + atomicAdd(&cursor[d], 1);
    const float* ep = ea + (size_t)e * 7;
    float a0 = ep[0], a1 = ep[1], a2 = ep[2], a3 = ep[3];
    float a4 = ep[4], a5 = ep[5], a6 = ep[6];
    float* rp = rec + (size_t)pos * 8;
    *(float4*)rp       = make_float4(a0, a1, a2, a3);
    *(float4*)(rp + 4) = make_float4(a4, a5, a6, __int_as_float(src[e]));
}

// ---------------------------------------------------------------- layer 1 ---
// fused gather + node MLP: one wave per node.
__global__ __launch_bounds__(256) void layer1_kernel(
        const float* __restrict__ x,     // [N][2]
        const float* __restrict__ rec,   // [E][8]
        const int* __restrict__ base,    // [N+1]
        const float* __restrict__ We1,   // [7][2]
        const float* __restrict__ be1,   // [2]
        const float* __restrict__ W1,    // [2][256]
        const float* __restrict__ b1,    // [256]
        float* __restrict__ hr) {        // [N][256]
    const int lane = threadIdx.x & 63;
    const int wid = threadIdx.x >> 6;
    const int n = blockIdx.x * 4 + wid;
    if (n >= N_NODES) return;
    float w00 = We1[0],  w01 = We1[1],  w10 = We1[2],  w11 = We1[3];
    float w20 = We1[4],  w21 = We1[5],  w30 = We1[6],  w31 = We1[7];
    float w40 = We1[8],  w41 = We1[9],  w50 = We1[10], w51 = We1[11];
    float w60 = We1[12], w61 = We1[13];
    float bb0 = be1[0], bb1 = be1[1];
    float m0 = 0.f, m1 = 0.f;
    const int s0 = base[n], s1 = base[n + 1];
    for (int pos = s0 + lane; pos < s1; pos += 64) {
        const float* p = rec + (size_t)pos * 8;
        float4 a = *(const float4*)p;
        float4 b = *(const float4*)(p + 4);
        int s = __float_as_int(b.w);
        float t0 = bb0, t1 = bb1;
        t0 = fmaf(a.x, w00, t0); t1 = fmaf(a.x, w01, t1);
        t0 = fmaf(a.y, w10, t0); t1 = fmaf(a.y, w11, t1);
        t0 = fmaf(a.z, w20, t0); t1 = fmaf(a.z, w21, t1);
        t0 = fmaf(a.w, w30, t0); t1 = fmaf(a.w, w31, t1);
        t0 = fmaf(b.x, w40, t0); t1 = fmaf(b.x, w41, t1);
        t0 = fmaf(b.y, w50, t0); t1 = fmaf(b.y, w51, t1);
        t0 = fmaf(b.z, w60, t0); t1 = fmaf(b.z, w61, t1);
        float2 xv = *(const float2*)&x[(size_t)s * 2];
        m0 += fmaxf(t0 + xv.x, 0.f);
        m1 += fmaxf(t1 + xv.y, 0.f);
    }
#pragma unroll
    for (int off = 32; off > 0; off >>= 1) {
        m0 += __shfl_down(m0, off);
        m1 += __shfl_down(m1, off);
    }
    m0 = __shfl(m0, 0);
    m1 = __shfl(m1, 0);
    const float t0 = x[n * 2 + 0] + m0;
    const float t1 = x[n * 2 + 1] + m1;
    const int c = lane * 4;
    float4 wa = *(const float4*)&W1[c];
    float4 wb = *(const float4*)&W1[256 + c];
    float4 bv = *(const float4*)&b1[c];
    float4 r;
    r.x = fmaxf(fmaf(t0, wa.x, fmaf(t1, wb.x, bv.x)), 0.f);
    r.y = fmaxf(fmaf(t0, wa.y, fmaf(t1, wb.y, bv.y)), 0.f);
    r.z = fmaxf(fmaf(t0, wa.z, fmaf(t1, wb.z, bv.z)), 0.f);
    r.w = fmaxf(fmaf(t0, wa.w, fmaf(t1, wb.w, bv.w)), 0.f);
    *(float4*)&hr[(size_t)n * HID + c] = r;
}

// ------------------------------------------------------------ layers 2..3 ---
// Scalarized CSR gather, channel-split (128 cols/pass): one wave per node,
// records + src index + h base all wave-uniform (SGPR); lane owns 2 channels.
#define EDGE2(RA, RB, HV)                                             \
    do {                                                              \
        float2 m = bb;                                                \
        m.x = fmaf(RA.x, w0.x, m.x); m.y = fmaf(RA.x, w0.y, m.y);     \
        m.x = fmaf(RA.y, w1.x, m.x); m.y = fmaf(RA.y, w1.y, m.y);     \
        m.x = fmaf(RA.z, w2.x, m.x); m.y = fmaf(RA.z, w2.y, m.y);     \
        m.x = fmaf(RA.w, w3.x, m.x); m.y = fmaf(RA.w, w3.y, m.y);     \
        m.x = fmaf(RB.x, w4.x, m.x); m.y = fmaf(RB.x, w4.y, m.y);     \
        m.x = fmaf(RB.y, w5.x, m.x); m.y = fmaf(RB.y, w5.y, m.y);     \
        m.x = fmaf(RB.z, w6.x, m.x); m.y = fmaf(RB.z, w6.y, m.y);     \
        acc.x += fmaxf(m.x + HV.x, 0.f);                              \
        acc.y += fmaxf(m.y + HV.y, 0.f);                              \
    } while (0)

__global__ __launch_bounds__(128, 4) void aggr2_kernel(
        const float* __restrict__ hr,     // [N][256]
        const float* __restrict__ rec,    // [E][8] dst-sorted {ea0..6, src}
        const int* __restrict__ base,     // [N+1]
        const float* __restrict__ We2,    // [7][256]
        const float* __restrict__ be2,    // [256]
        float* __restrict__ accum,        // [N][256] out (this pass: 128 cols)
        int coff) {                       // 0 or 128
    const int lane = threadIdx.x & 63;
    // n is wave-uniform by construction; readfirstlane forces SGPR so all
    // node-level values (base, record pointer, record loads, h base) scalarize.
    const int n = __builtin_amdgcn_readfirstlane(blockIdx.x * 2 + (threadIdx.x >> 6));
    if (n >= N_NODES) return;
    const int c2 = coff + lane * 2;
    float2 w0 = *(const float2*)&We2[0 * HID + c2];
    float2 w1 = *(const float2*)&We2[1 * HID + c2];
    float2 w2 = *(const float2*)&We2[2 * HID + c2];
    float2 w3 = *(const float2*)&We2[3 * HID + c2];
    float2 w4 = *(const float2*)&We2[4 * HID + c2];
    float2 w5 = *(const float2*)&We2[5 * HID + c2];
    float2 w6 = *(const float2*)&We2[6 * HID + c2];
    const float2 bb = *(const float2*)&be2[c2];

    float2 acc = *(const float2*)&hr[(size_t)n * HID + c2];
    const int s0 = base[n];
    const int deg = base[n + 1] - s0;
    const float* rp = rec + (size_t)s0 * 8;

    int i = 0;
    for (; i + 4 <= deg; i += 4) {
        const float* p = rp + (size_t)i * 8;
        float4 r0a = *(const float4*)(p + 0),  r0b = *(const float4*)(p + 4);
        float4 r1a = *(const float4*)(p + 8),  r1b = *(const float4*)(p + 12);
        float4 r2a = *(const float4*)(p + 16), r2b = *(const float4*)(p + 20);
        float4 r3a = *(const float4*)(p + 24), r3b = *(const float4*)(p + 28);
        // 4 independent gathers, SGPR row base + lane offset
        const float2 h0 = *(const float2*)&hr[(size_t)__float_as_int(r0b.w) * HID + c2];
        const float2 h1 = *(const float2*)&hr[(size_t)__float_as_int(r1b.w) * HID + c2];
        const float2 h2 = *(const float2*)&hr[(size_t)__float_as_int(r2b.w) * HID + c2];
        const float2 h3 = *(const float2*)&hr[(size_t)__float_as_int(r3b.w) * HID + c2];
        EDGE2(r0a, r0b, h0);
        EDGE2(r1a, r1b, h1);
        EDGE2(r2a, r2b, h2);
        EDGE2(r3a, r3b, h3);
    }
    for (; i < deg; ++i) {
        const float* p = rp + (size_t)i * 8;
        float4 ra = *(const float4*)p, rb = *(const float4*)(p + 4);
        const float2 hv = *(const float2*)&hr[(size_t)__float_as_int(rb.w) * HID + c2];
        EDGE2(ra, rb, hv);
    }
    *(float2*)&accum[(size_t)n * HID + c2] = acc;
}

// out = relu(T @ W2 + b2); optionally fused final head (sigmoid(relu·Wend+bend))
#define BN 64
#define BK 32
#define TPITCH 36
#define WPITCH 260
template <bool FUSE_END>
__global__ __launch_bounds__(256) void node2_kernel(
        const float* __restrict__ T,    // [N][256]
        const float* __restrict__ W,    // [256][256]
        const float* __restrict__ b,    // [256]
        const float* __restrict__ Wend, // [256] (FUSE_END)
        const float* __restrict__ bend, // [1]   (FUSE_END)
        float* __restrict__ out) {      // [N][256] or [N][1]
    __shared__ float Ts[BN * TPITCH];
    __shared__ float Ws[BK * WPITCH];
    const int t = threadIdx.x;
    const int n0 = blockIdx.x * BN;
    const int cc = t & 31;
    const int nn = t >> 5;
    float acc[8][8];
#pragma unroll
    for (int i = 0; i < 8; ++i)
#pragma unroll
        for (int j = 0; j < 8; ++j) acc[i][j] = 0.f;

    for (int k0 = 0; k0 < HID; k0 += BK) {
        __syncthreads();
        {   // stage T
            int row = t >> 2;
            int koff = (t & 3) * 8;
            int n = n0 + row;
            float4 v0 = make_float4(0.f, 0.f, 0.f, 0.f), v1 = v0;
            if (n < N_NODES) {
                v0 = *(const float4*)&T[(size_t)n * HID + k0 + koff];
                v1 = *(const float4*)&T[(size_t)n * HID + k0 + koff + 4];
            }
            *(float4*)&Ts[row * TPITCH + koff] = v0;
            *(float4*)&Ts[row * TPITCH + koff + 4] = v1;
        }
        {   // stage W
            int row = t >> 3;
            int cbase = (t & 7) * 4;
            const float* wg = &W[(size_t)(k0 + row) * HID];
            float* wl = &Ws[row * WPITCH];
#pragma unroll
            for (int i = 0; i < 8; ++i)
                *(float4*)&wl[cbase + i * 32] = *(const float4*)&wg[cbase + i * 32];
        }
        __syncthreads();
#pragma unroll
        for (int k = 0; k < BK; ++k) {
            float4 wa = *(const float4*)&Ws[k * WPITCH + cc * 8];
            float4 wb = *(const float4*)&Ws[k * WPITCH + cc * 8 + 4];
#pragma unroll
            for (int i = 0; i < 8; ++i) {
                float a = Ts[(nn * 8 + i) * TPITCH + k];
                acc[i][0] = fmaf(a, wa.x, acc[i][0]);
                acc[i][1] = fmaf(a, wa.y, acc[i][1]);
                acc[i][2] = fmaf(a, wa.z, acc[i][2]);
                acc[i][3] = fmaf(a, wa.w, acc[i][3]);
                acc[i][4] = fmaf(a, wb.x, acc[i][4]);
                acc[i][5] = fmaf(a, wb.y, acc[i][5]);
                acc[i][6] = fmaf(a, wb.z, acc[i][6]);
                acc[i][7] = fmaf(a, wb.w, acc[i][7]);
            }
        }
    }
    float4 b0 = *(const float4*)&b[cc * 8];
    float4 b1v = *(const float4*)&b[cc * 8 + 4];
    if (!FUSE_END) {
#pragma unroll
        for (int i = 0; i < 8; ++i) {
            int n = n0 + nn * 8 + i;
            if (n < N_NODES) {
                float4 r0, r1;
                r0.x = fmaxf(acc[i][0] + b0.x, 0.f);
                r0.y = fmaxf(acc[i][1] + b0.y, 0.f);
                r0.z = fmaxf(acc[i][2] + b0.z, 0.f);
                r0.w = fmaxf(acc[i][3] + b0.w, 0.f);
                r1.x = fmaxf(acc[i][4] + b1v.x, 0.f);
                r1.y = fmaxf(acc[i][5] + b1v.y, 0.f);
                r1.z = fmaxf(acc[i][6] + b1v.z, 0.f);
                r1.w = fmaxf(acc[i][7] + b1v.w, 0.f);
                *(float4*)&out[(size_t)n * HID + cc * 8] = r0;
                *(float4*)&out[(size_t)n * HID + cc * 8 + 4] = r1;
            }
        }
    } else {
        float4 we0 = *(const float4*)&Wend[cc * 8];
        float4 we1 = *(const float4*)&Wend[cc * 8 + 4];
        __syncthreads();               // done reading Ts; reuse as reduce buf
        float* red = Ts;               // [64][33]
#pragma unroll
        for (int i = 0; i < 8; ++i) {
            float p = 0.f;
            p = fmaf(fmaxf(acc[i][0] + b0.x, 0.f), we0.x, p);
            p = fmaf(fmaxf(acc[i][1] + b0.y, 0.f), we0.y, p);
            p = fmaf(fmaxf(acc[i][2] + b0.z, 0.f), we0.z, p);
            p = fmaf(fmaxf(acc[i][3] + b0.w, 0.f), we0.w, p);
            p = fmaf(fmaxf(acc[i][4] + b1v.x, 0.f), we1.x, p);
            p = fmaf(fmaxf(acc[i][5] + b1v.y, 0.f), we1.y, p);
            p = fmaf(fmaxf(acc[i][6] + b1v.z, 0.f), we1.z, p);
            p = fmaf(fmaxf(acc[i][7] + b1v.w, 0.f), we1.w, p);
            red[(nn * 8 + i) * 33 + cc] = p;
        }
        __syncthreads();
        if (t < 64) {
            int n = n0 + t;
            if (n < N_NODES) {
                float s = 0.f;
#pragma unroll
                for (int j = 0; j < 32; ++j) s += red[t * 33 + j];
                out[n] = 1.f / (1.f + expf(-(s + bend[0])));
            }
        }
    }
}

// ------------------------------------------------------------------ launch ---
extern "C" void kernel_launch(void* const* d_in, const int* in_sizes, int n_in,
                              void* d_out, int out_size, void* d_ws, size_t ws_size,
                              hipStream_t stream) {
    const float* x    = (const float*)d_in[0];
    const int*   ei   = (const int*)d_in[1];
    const float* ea   = (const float*)d_in[2];
    const float* We1  = (const float*)d_in[3];
    const float* be1  = (const float*)d_in[4];
    const float* W1   = (const float*)d_in[5];
    const float* b1   = (const float*)d_in[6];
    const float* We2  = (const float*)d_in[7];
    const float* be2  = (const float*)d_in[8];
    const float* W2   = (const float*)d_in[9];
    const float* b2   = (const float*)d_in[10];
    const float* Wend = (const float*)d_in[11];
    const float* bend = (const float*)d_in[12];
    float* out = (float*)d_out;

    const int* src = ei;
    const int* dst = ei + N_EDGES;

    const size_t HN = (size_t)N_NODES * HID;          // 12.8M floats
    float* A      = (float*)d_ws;                     // [N][256]
    float* B      = A + HN;                           // [N][256]
    float* rec    = B + HN;                           // [E][8]
    int*   deg    = (int*)(rec + (size_t)N_EDGES * 8);// [N]
    int*   cursor = deg + N_NODES;                    // [N]
    int*   base   = cursor + N_NODES;                 // [N+2]
    int*   bsum   = base + N_NODES + 2;               // [256]
    // total ≈ 154 MB

    // ---- CSR build + record sort (shared by all 3 layers)
    hipMemsetAsync(deg, 0, (size_t)N_NODES * 2 * sizeof(int), stream);  // deg+cursor
    hist_kernel<<<(N_EDGES + 255) / 256, 256, 0, stream>>>(dst, deg);
    scan1_kernel<<<SCAN_B, 256, 0, stream>>>(deg, bsum);
    scan2_kernel<<<1, 256, 0, stream>>>(bsum);
    scan3_kernel<<<SCAN_B, 256, 0, stream>>>(deg, bsum, base);
    scatter_rec_kernel<<<(N_EDGES + 255) / 256, 256, 0, stream>>>(src, dst, ea, base,
                                                                  cursor, rec);

    // ---- layer 1 (fused gather + MLP)
    layer1_kernel<<<(N_NODES + 3) / 4, 256, 0, stream>>>(x, rec, base, We1, be1,
                                                         W1, b1, A);

    const int AGG_B = (N_NODES + 1) / 2;  // 2 nodes (2 waves) per block
    // ---- layer 2
    aggr2_kernel<<<AGG_B, 128, 0, stream>>>(A, rec, base, We2, be2, B, 0);
    aggr2_kernel<<<AGG_B, 128, 0, stream>>>(A, rec, base, We2, be2, B, 128);
    node2_kernel<false><<<(N_NODES + BN - 1) / BN, 256, 0, stream>>>(B, W2, b2,
                                                                     nullptr, nullptr, A);
    // ---- layer 3 + head (fused)
    aggr2_kernel<<<AGG_B, 128, 0, stream>>>(A, rec, base, We2, be2, B, 0);
    aggr2_kernel<<<AGG_B, 128, 0, stream>>>(A, rec, base, We2, be2, B, 128);
    node2_kernel<true><<<(N_NODES + BN - 1) / BN, 256, 0, stream>>>(B, W2, b2,
                                                                    Wend, bend, out);
}

// Round 6
// 953.119 us; speedup vs baseline: 11.7164x; 1.0121x over previous
//
#include <hip/hip_runtime.h>
#include <math.h>

#define N_NODES 50000
#define N_EDGES 1600000
#define HID 256
#define SCAN_B 196   // ceil(N_NODES/256)
// eps = 0

// ---------------------------------------------------------------- CSR build ---
__global__ void hist_kernel(const int* __restrict__ dst, int* __restrict__ deg) {
    int e = blockIdx.x * blockDim.x + threadIdx.x;
    if (e < N_EDGES) atomicAdd(&deg[dst[e]], 1);
}

__global__ __launch_bounds__(256) void scan1_kernel(const int* __restrict__ deg,
                                                    int* __restrict__ bsum) {
    int idx = blockIdx.x * 256 + threadIdx.x;
    int v = (idx < N_NODES) ? deg[idx] : 0;
#pragma unroll
    for (int off = 32; off > 0; off >>= 1) v += __shfl_down(v, off);
    __shared__ int ws[4];
    if ((threadIdx.x & 63) == 0) ws[threadIdx.x >> 6] = v;
    __syncthreads();
    if (threadIdx.x == 0) bsum[blockIdx.x] = ws[0] + ws[1] + ws[2] + ws[3];
}

__global__ __launch_bounds__(256) void scan2_kernel(int* __restrict__ bsum) {
    __shared__ int s[256];
    int t = threadIdx.x;
    int v = (t < SCAN_B) ? bsum[t] : 0;
    s[t] = v;
    __syncthreads();
    for (int off = 1; off < 256; off <<= 1) {
        int u = (t >= off) ? s[t - off] : 0;
        __syncthreads();
        s[t] += u;
        __syncthreads();
    }
    if (t < SCAN_B) bsum[t] = s[t] - v;  // exclusive
}

__global__ __launch_bounds__(256) void scan3_kernel(const int* __restrict__ deg,
                                                    const int* __restrict__ bsum,
                                                    int* __restrict__ base) {
    __shared__ int s[256];
    int t = threadIdx.x;
    int idx = blockIdx.x * 256 + t;
    int v = (idx < N_NODES) ? deg[idx] : 0;
    s[t] = v;
    __syncthreads();
    for (int off = 1; off < 256; off <<= 1) {
        int u = (t >= off) ? s[t - off] : 0;
        __syncthreads();
        s[t] += u;
        __syncthreads();
    }
    if (idx < N_NODES) base[idx] = bsum[blockIdx.x] + s[t] - v;
    if (idx == 0) base[N_NODES] = N_EDGES;
}

// build dst-sorted 32B records: {ea0..ea6, src_bits}
__global__ void scatter_rec_kernel(const int* __restrict__ src,
                                   const int* __restrict__ dst,
                                   const float* __restrict__ ea,
                                   const int* __restrict__ base,
                                   int* __restrict__ cursor,
                                   float* __restrict__ rec) {
    int e = blockIdx.x * blockDim.x + threadIdx.x;
    if (e >= N_EDGES) return;
    int d = dst[e];
    int pos = base[d] + atomicAdd(&cursor[d], 1);
    const float* ep = ea + (size_t)e * 7;
    float a0 = ep[0], a1 = ep[1], a2 = ep[2], a3 = ep[3];
    float a4 = ep[4], a5 = ep[5], a6 = ep[6];
    float* rp = rec + (size_t)pos * 8;
    *(float4*)rp       = make_float4(a0, a1, a2, a3);
    *(float4*)(rp + 4) = make_float4(a4, a5, a6, __int_as_float(src[e]));
}

// ---------------------------------------------------------------- layer 1 ---
__global__ __launch_bounds__(256) void layer1_kernel(
        const float* __restrict__ x,     // [N][2]
        const float* __restrict__ rec,   // [E][8]
        const int* __restrict__ base,    // [N+1]
        const float* __restrict__ We1,   // [7][2]
        const float* __restrict__ be1,   // [2]
        const float* __restrict__ W1,    // [2][256]
        const float* __restrict__ b1,    // [256]
        float* __restrict__ hr) {        // [N][256]
    const int lane = threadIdx.x & 63;
    const int wid = threadIdx.x >> 6;
    const int n = blockIdx.x * 4 + wid;
    if (n >= N_NODES) return;
    float w00 = We1[0],  w01 = We1[1],  w10 = We1[2],  w11 = We1[3];
    float w20 = We1[4],  w21 = We1[5],  w30 = We1[6],  w31 = We1[7];
    float w40 = We1[8],  w41 = We1[9],  w50 = We1[10], w51 = We1[11];
    float w60 = We1[12], w61 = We1[13];
    float bb0 = be1[0], bb1 = be1[1];
    float m0 = 0.f, m1 = 0.f;
    const int s0 = base[n], s1 = base[n + 1];
    for (int pos = s0 + lane; pos < s1; pos += 64) {
        const float* p = rec + (size_t)pos * 8;
        float4 a = *(const float4*)p;
        float4 b = *(const float4*)(p + 4);
        int s = __float_as_int(b.w);
        float t0 = bb0, t1 = bb1;
        t0 = fmaf(a.x, w00, t0); t1 = fmaf(a.x, w01, t1);
        t0 = fmaf(a.y, w10, t0); t1 = fmaf(a.y, w11, t1);
        t0 = fmaf(a.z, w20, t0); t1 = fmaf(a.z, w21, t1);
        t0 = fmaf(a.w, w30, t0); t1 = fmaf(a.w, w31, t1);
        t0 = fmaf(b.x, w40, t0); t1 = fmaf(b.x, w41, t1);
        t0 = fmaf(b.y, w50, t0); t1 = fmaf(b.y, w51, t1);
        t0 = fmaf(b.z, w60, t0); t1 = fmaf(b.z, w61, t1);
        float2 xv = *(const float2*)&x[(size_t)s * 2];
        m0 += fmaxf(t0 + xv.x, 0.f);
        m1 += fmaxf(t1 + xv.y, 0.f);
    }
#pragma unroll
    for (int off = 32; off > 0; off >>= 1) {
        m0 += __shfl_down(m0, off);
        m1 += __shfl_down(m1, off);
    }
    m0 = __shfl(m0, 0);
    m1 = __shfl(m1, 0);
    const float t0 = x[n * 2 + 0] + m0;
    const float t1 = x[n * 2 + 1] + m1;
    const int c = lane * 4;
    float4 wa = *(const float4*)&W1[c];
    float4 wb = *(const float4*)&W1[256 + c];
    float4 bv = *(const float4*)&b1[c];
    float4 r;
    r.x = fmaxf(fmaf(t0, wa.x, fmaf(t1, wb.x, bv.x)), 0.f);
    r.y = fmaxf(fmaf(t0, wa.y, fmaf(t1, wb.y, bv.y)), 0.f);
    r.z = fmaxf(fmaf(t0, wa.z, fmaf(t1, wb.z, bv.z)), 0.f);
    r.w = fmaxf(fmaf(t0, wa.w, fmaf(t1, wb.w, bv.w)), 0.f);
    *(float4*)&hr[(size_t)n * HID + c] = r;
}

// ------------------------------------------------------------ layers 2..3 ---
// CSR gather, one wave per node, full 256-col row per instruction.
// Pipeline: records AND h-rows double-buffered one 4-edge group ahead
// (8 h-row loads in flight per wave). h-row base scalar via readfirstlane.
#define EDGE(RA, RB, HV)                                              \
    do {                                                              \
        float4 m = bb;                                                \
        m.x = fmaf(RA.x, w0.x, m.x); m.y = fmaf(RA.x, w0.y, m.y);     \
        m.z = fmaf(RA.x, w0.z, m.z); m.w = fmaf(RA.x, w0.w, m.w);     \
        m.x = fmaf(RA.y, w1.x, m.x); m.y = fmaf(RA.y, w1.y, m.y);     \
        m.z = fmaf(RA.y, w1.z, m.z); m.w = fmaf(RA.y, w1.w, m.w);     \
        m.x = fmaf(RA.z, w2.x, m.x); m.y = fmaf(RA.z, w2.y, m.y);     \
        m.z = fmaf(RA.z, w2.z, m.z); m.w = fmaf(RA.z, w2.w, m.w);     \
        m.x = fmaf(RA.w, w3.x, m.x); m.y = fmaf(RA.w, w3.y, m.y);     \
        m.z = fmaf(RA.w, w3.z, m.z); m.w = fmaf(RA.w, w3.w, m.w);     \
        m.x = fmaf(RB.x, w4.x, m.x); m.y = fmaf(RB.x, w4.y, m.y);     \
        m.z = fmaf(RB.x, w4.z, m.z); m.w = fmaf(RB.x, w4.w, m.w);     \
        m.x = fmaf(RB.y, w5.x, m.x); m.y = fmaf(RB.y, w5.y, m.y);     \
        m.z = fmaf(RB.y, w5.z, m.z); m.w = fmaf(RB.y, w5.w, m.w);     \
        m.x = fmaf(RB.z, w6.x, m.x); m.y = fmaf(RB.z, w6.y, m.y);     \
        m.z = fmaf(RB.z, w6.z, m.z); m.w = fmaf(RB.z, w6.w, m.w);     \
        acc.x += fmaxf(m.x + HV.x, 0.f);                              \
        acc.y += fmaxf(m.y + HV.y, 0.f);                              \
        acc.z += fmaxf(m.z + HV.z, 0.f);                              \
        acc.w += fmaxf(m.w + HV.w, 0.f);                              \
    } while (0)

#define HROW(RB) (*(const float4*)&hr[(size_t)__builtin_amdgcn_readfirstlane( \
                       __float_as_int(RB.w)) * HID + c4])

__global__ __launch_bounds__(256) void aggr2_kernel(
        const float* __restrict__ hr,     // [N][256]
        const float* __restrict__ rec,    // [E][8] dst-sorted {ea0..6, src}
        const int* __restrict__ base,     // [N+1]
        const float* __restrict__ We2,    // [7][256]
        const float* __restrict__ be2,    // [256]
        float* __restrict__ accum) {      // [N][256] out
    const int lane = threadIdx.x & 63;
    const int n = blockIdx.x * 4 + (threadIdx.x >> 6);
    if (n >= N_NODES) return;
    const int c4 = lane * 4;
    float4 w0 = *(const float4*)&We2[0 * HID + c4];
    float4 w1 = *(const float4*)&We2[1 * HID + c4];
    float4 w2 = *(const float4*)&We2[2 * HID + c4];
    float4 w3 = *(const float4*)&We2[3 * HID + c4];
    float4 w4 = *(const float4*)&We2[4 * HID + c4];
    float4 w5 = *(const float4*)&We2[5 * HID + c4];
    float4 w6 = *(const float4*)&We2[6 * HID + c4];
    const float4 bb = *(const float4*)&be2[c4];

    float4 acc = *(const float4*)&hr[(size_t)n * HID + c4];
    const int s0 = base[n];
    const int deg = base[n + 1] - s0;
    const float4* rp = (const float4*)rec + (size_t)s0 * 2;
    const int ng = deg >> 2;

    if (ng > 0) {
        // group 0 records (wave-uniform addresses -> broadcast loads)
        float4 r0a = rp[0], r0b = rp[1], r1a = rp[2], r1b = rp[3];
        float4 r2a = rp[4], r2b = rp[5], r3a = rp[6], r3b = rp[7];
        // group 0 h-rows
        float4 h0 = HROW(r0b);
        float4 h1 = HROW(r1b);
        float4 h2 = HROW(r2b);
        float4 h3 = HROW(r3b);
        for (int g = 1; g < ng; ++g) {
            const float4* np = rp + (size_t)g * 8;
            // next group's records
            float4 t0a = np[0], t0b = np[1], t1a = np[2], t1b = np[3];
            float4 t2a = np[4], t2b = np[5], t3a = np[6], t3b = np[7];
            // next group's h-rows (now 8 h-loads in flight)
            float4 g0 = HROW(t0b);
            float4 g1 = HROW(t1b);
            float4 g2 = HROW(t2b);
            float4 g3 = HROW(t3b);
            // consume current group
            EDGE(r0a, r0b, h0);
            EDGE(r1a, r1b, h1);
            EDGE(r2a, r2b, h2);
            EDGE(r3a, r3b, h3);
            r0a = t0a; r0b = t0b; r1a = t1a; r1b = t1b;
            r2a = t2a; r2b = t2b; r3a = t3a; r3b = t3b;
            h0 = g0; h1 = g1; h2 = g2; h3 = g3;
        }
        EDGE(r0a, r0b, h0);
        EDGE(r1a, r1b, h1);
        EDGE(r2a, r2b, h2);
        EDGE(r3a, r3b, h3);
    }
    for (int i = ng * 4; i < deg; ++i) {
        float4 ra = rp[(size_t)i * 2], rb = rp[(size_t)i * 2 + 1];
        float4 hv = HROW(rb);
        EDGE(ra, rb, hv);
    }
    *(float4*)&accum[(size_t)n * HID + c4] = acc;
}

// ---------------------------------------------------------------- node MLP ---
// out = relu(T @ W2 + b2). Block: 64 nodes x 128-col slab; thread: 8 nodes x
// 4 cols strided by 32 (conflict-free b32 Ws reads at bank==cc).
#define BN 64
#define BK 32
#define TS_P 36
#define WS_P 132
__global__ __launch_bounds__(256) void node2_kernel(
        const float* __restrict__ T,    // [N][256]
        const float* __restrict__ W,    // [256][256]
        const float* __restrict__ b,    // [256]
        float* __restrict__ out) {      // [N][256] (relu'd)
    __shared__ float Ts[BN * TS_P];     // [node][k]
    __shared__ float Ws[BK * WS_P];     // [k][col in slab]
    const int t = threadIdx.x;
    const int n0 = (blockIdx.x >> 1) * BN;
    const int coff = (blockIdx.x & 1) * 128;
    const int cc = t & 31;
    const int nn = t >> 5;
    float acc[8][4];
#pragma unroll
    for (int i = 0; i < 8; ++i)
#pragma unroll
        for (int j = 0; j < 4; ++j) acc[i][j] = 0.f;

    for (int k0 = 0; k0 < HID; k0 += BK) {
        __syncthreads();
        {   // stage T: row = t>>2, koff = (t&3)*8
            int row = t >> 2;
            int koff = (t & 3) * 8;
            int n = n0 + row;
            float4 v0 = make_float4(0.f, 0.f, 0.f, 0.f), v1 = v0;
            if (n < N_NODES) {
                v0 = *(const float4*)&T[(size_t)n * HID + k0 + koff];
                v1 = *(const float4*)&T[(size_t)n * HID + k0 + koff + 4];
            }
            *(float4*)&Ts[row * TS_P + koff] = v0;
            *(float4*)&Ts[row * TS_P + koff + 4] = v1;
        }
        {   // stage W slab: row = t>>3 (0..31), cols (t&7)*16 .. +15
            int row = t >> 3;
            int cb = (t & 7) * 16;
            const float* wg = &W[(size_t)(k0 + row) * HID + coff + cb];
            float* wl = &Ws[row * WS_P + cb];
            *(float4*)(wl + 0)  = *(const float4*)(wg + 0);
            *(float4*)(wl + 4)  = *(const float4*)(wg + 4);
            *(float4*)(wl + 8)  = *(const float4*)(wg + 8);
            *(float4*)(wl + 12) = *(const float4*)(wg + 12);
        }
        __syncthreads();
#pragma unroll
        for (int k = 0; k < BK; k += 2) {
            float wa0 = Ws[k * WS_P + cc];
            float wa1 = Ws[k * WS_P + cc + 32];
            float wa2 = Ws[k * WS_P + cc + 64];
            float wa3 = Ws[k * WS_P + cc + 96];
            float wb0 = Ws[(k + 1) * WS_P + cc];
            float wb1 = Ws[(k + 1) * WS_P + cc + 32];
            float wb2 = Ws[(k + 1) * WS_P + cc + 64];
            float wb3 = Ws[(k + 1) * WS_P + cc + 96];
#pragma unroll
            for (int i = 0; i < 8; ++i) {
                float2 a = *(const float2*)&Ts[(nn * 8 + i) * TS_P + k];
                acc[i][0] = fmaf(a.x, wa0, acc[i][0]);
                acc[i][1] = fmaf(a.x, wa1, acc[i][1]);
                acc[i][2] = fmaf(a.x, wa2, acc[i][2]);
                acc[i][3] = fmaf(a.x, wa3, acc[i][3]);
                acc[i][0] = fmaf(a.y, wb0, acc[i][0]);
                acc[i][1] = fmaf(a.y, wb1, acc[i][1]);
                acc[i][2] = fmaf(a.y, wb2, acc[i][2]);
                acc[i][3] = fmaf(a.y, wb3, acc[i][3]);
            }
        }
    }
    const float bv0 = b[coff + cc];
    const float bv1 = b[coff + cc + 32];
    const float bv2 = b[coff + cc + 64];
    const float bv3 = b[coff + cc + 96];
#pragma unroll
    for (int i = 0; i < 8; ++i) {
        int n = n0 + nn * 8 + i;
        if (n < N_NODES) {
            float* op = &out[(size_t)n * HID + coff + cc];
            op[0]  = fmaxf(acc[i][0] + bv0, 0.f);
            op[32] = fmaxf(acc[i][1] + bv1, 0.f);
            op[64] = fmaxf(acc[i][2] + bv2, 0.f);
            op[96] = fmaxf(acc[i][3] + bv3, 0.f);
        }
    }
}

// ------------------------------------------------------------------ final ---
__global__ void end_kernel(const float* __restrict__ hr,
                           const float* __restrict__ Wend,  // [256]
                           const float* __restrict__ bend,  // [1]
                           float* __restrict__ out) {
    int n = blockIdx.x * 4 + (threadIdx.x >> 6);
    if (n >= N_NODES) return;
    int lane = threadIdx.x & 63;
    float4 h4 = *(const float4*)&hr[(size_t)n * HID + lane * 4];
    float4 w4 = *(const float4*)&Wend[lane * 4];
    float s = h4.x * w4.x + h4.y * w4.y + h4.z * w4.z + h4.w * w4.w;
#pragma unroll
    for (int off = 32; off > 0; off >>= 1) s += __shfl_down(s, off);
    if (lane == 0) out[n] = 1.f / (1.f + expf(-(s + bend[0])));
}

// ------------------------------------------------------------------ launch ---
extern "C" void kernel_launch(void* const* d_in, const int* in_sizes, int n_in,
                              void* d_out, int out_size, void* d_ws, size_t ws_size,
                              hipStream_t stream) {
    const float* x    = (const float*)d_in[0];
    const int*   ei   = (const int*)d_in[1];
    const float* ea   = (const float*)d_in[2];
    const float* We1  = (const float*)d_in[3];
    const float* be1  = (const float*)d_in[4];
    const float* W1   = (const float*)d_in[5];
    const float* b1   = (const float*)d_in[6];
    const float* We2  = (const float*)d_in[7];
    const float* be2  = (const float*)d_in[8];
    const float* W2   = (const float*)d_in[9];
    const float* b2   = (const float*)d_in[10];
    const float* Wend = (const float*)d_in[11];
    const float* bend = (const float*)d_in[12];
    float* out = (float*)d_out;

    const int* src = ei;
    const int* dst = ei + N_EDGES;

    const size_t HN = (size_t)N_NODES * HID;          // 12.8M floats
    float* A      = (float*)d_ws;                     // [N][256]
    float* B      = A + HN;                           // [N][256]
    float* rec    = B + HN;                           // [E][8]
    int*   deg    = (int*)(rec + (size_t)N_EDGES * 8);// [N]
    int*   cursor = deg + N_NODES;                    // [N]
    int*   base   = cursor + N_NODES;                 // [N+2]
    int*   bsum   = base + N_NODES + 2;               // [256]
    // total ≈ 154 MB

    // ---- CSR build + record sort (shared by all 3 layers)
    hipMemsetAsync(deg, 0, (size_t)N_NODES * 2 * sizeof(int), stream);  // deg+cursor
    hist_kernel<<<(N_EDGES + 255) / 256, 256, 0, stream>>>(dst, deg);
    scan1_kernel<<<SCAN_B, 256, 0, stream>>>(deg, bsum);
    scan2_kernel<<<1, 256, 0, stream>>>(bsum);
    scan3_kernel<<<SCAN_B, 256, 0, stream>>>(deg, bsum, base);
    scatter_rec_kernel<<<(N_EDGES + 255) / 256, 256, 0, stream>>>(src, dst, ea, base,
                                                                  cursor, rec);

    // ---- layer 1 (fused gather + MLP)
    layer1_kernel<<<(N_NODES + 3) / 4, 256, 0, stream>>>(x, rec, base, We1, be1,
                                                         W1, b1, A);

    const int N2_B = ((N_NODES + BN - 1) / BN) * 2;   // col-slab split
    // ---- layer 2
    aggr2_kernel<<<(N_NODES + 3) / 4, 256, 0, stream>>>(A, rec, base, We2, be2, B);
    node2_kernel<<<N2_B, 256, 0, stream>>>(B, W2, b2, A);
    // ---- layer 3
    aggr2_kernel<<<(N_NODES + 3) / 4, 256, 0, stream>>>(A, rec, base, We2, be2, B);
    node2_kernel<<<N2_B, 256, 0, stream>>>(B, W2, b2, A);
    // ---- head
    end_kernel<<<(N_NODES + 3) / 4, 256, 0, stream>>>(A, Wend, bend, out);
}

// Round 7
// 755.799 us; speedup vs baseline: 14.7752x; 1.2611x over previous
//
#include <hip/hip_runtime.h>
#include <hip/hip_fp16.h>
#include <math.h>

#define N_NODES 50000
#define N_EDGES 1600000
#define HID 256
#define SCAN_B 196   // ceil(N_NODES/256)
// eps = 0

// ---------------------------------------------------------------- CSR build ---
__global__ void hist_kernel(const int* __restrict__ dst, int* __restrict__ deg) {
    int e = blockIdx.x * blockDim.x + threadIdx.x;
    if (e < N_EDGES) atomicAdd(&deg[dst[e]], 1);
}

__global__ __launch_bounds__(256) void scan1_kernel(const int* __restrict__ deg,
                                                    int* __restrict__ bsum) {
    int idx = blockIdx.x * 256 + threadIdx.x;
    int v = (idx < N_NODES) ? deg[idx] : 0;
#pragma unroll
    for (int off = 32; off > 0; off >>= 1) v += __shfl_down(v, off);
    __shared__ int ws[4];
    if ((threadIdx.x & 63) == 0) ws[threadIdx.x >> 6] = v;
    __syncthreads();
    if (threadIdx.x == 0) bsum[blockIdx.x] = ws[0] + ws[1] + ws[2] + ws[3];
}

__global__ __launch_bounds__(256) void scan2_kernel(int* __restrict__ bsum) {
    __shared__ int s[256];
    int t = threadIdx.x;
    int v = (t < SCAN_B) ? bsum[t] : 0;
    s[t] = v;
    __syncthreads();
    for (int off = 1; off < 256; off <<= 1) {
        int u = (t >= off) ? s[t - off] : 0;
        __syncthreads();
        s[t] += u;
        __syncthreads();
    }
    if (t < SCAN_B) bsum[t] = s[t] - v;  // exclusive
}

__global__ __launch_bounds__(256) void scan3_kernel(const int* __restrict__ deg,
                                                    const int* __restrict__ bsum,
                                                    int* __restrict__ base) {
    __shared__ int s[256];
    int t = threadIdx.x;
    int idx = blockIdx.x * 256 + t;
    int v = (idx < N_NODES) ? deg[idx] : 0;
    s[t] = v;
    __syncthreads();
    for (int off = 1; off < 256; off <<= 1) {
        int u = (t >= off) ? s[t - off] : 0;
        __syncthreads();
        s[t] += u;
        __syncthreads();
    }
    if (idx < N_NODES) base[idx] = bsum[blockIdx.x] + s[t] - v;
    if (idx == 0) base[N_NODES] = N_EDGES;
}

// build dst-sorted 32B records: {ea0..ea6, src_bits}
__global__ void scatter_rec_kernel(const int* __restrict__ src,
                                   const int* __restrict__ dst,
                                   const float* __restrict__ ea,
                                   const int* __restrict__ base,
                                   int* __restrict__ cursor,
                                   float* __restrict__ rec) {
    int e = blockIdx.x * blockDim.x + threadIdx.x;
    if (e >= N_EDGES) return;
    int d = dst[e];
    int pos = base[d] + atomicAdd(&cursor[d], 1);
    const float* ep = ea + (size_t)e * 7;
    float a0 = ep[0], a1 = ep[1], a2 = ep[2], a3 = ep[3];
    float a4 = ep[4], a5 = ep[5], a6 = ep[6];
    float* rp = rec + (size_t)pos * 8;
    *(float4*)rp       = make_float4(a0, a1, a2, a3);
    *(float4*)(rp + 4) = make_float4(a4, a5, a6, __int_as_float(src[e]));
}

// ---------------------------------------------------------------- layer 1 ---
// fused gather + node MLP; writes h as fp16
__global__ __launch_bounds__(256) void layer1_kernel(
        const float* __restrict__ x,     // [N][2]
        const float* __restrict__ rec,   // [E][8]
        const int* __restrict__ base,    // [N+1]
        const float* __restrict__ We1,   // [7][2]
        const float* __restrict__ be1,   // [2]
        const float* __restrict__ W1,    // [2][256]
        const float* __restrict__ b1,    // [256]
        __half* __restrict__ hh) {       // [N][256] fp16
    const int lane = threadIdx.x & 63;
    const int wid = threadIdx.x >> 6;
    const int n = blockIdx.x * 4 + wid;
    if (n >= N_NODES) return;
    float w00 = We1[0],  w01 = We1[1],  w10 = We1[2],  w11 = We1[3];
    float w20 = We1[4],  w21 = We1[5],  w30 = We1[6],  w31 = We1[7];
    float w40 = We1[8],  w41 = We1[9],  w50 = We1[10], w51 = We1[11];
    float w60 = We1[12], w61 = We1[13];
    float bb0 = be1[0], bb1 = be1[1];
    float m0 = 0.f, m1 = 0.f;
    const int s0 = base[n], s1 = base[n + 1];
    for (int pos = s0 + lane; pos < s1; pos += 64) {
        const float* p = rec + (size_t)pos * 8;
        float4 a = *(const float4*)p;
        float4 b = *(const float4*)(p + 4);
        int s = __float_as_int(b.w);
        float t0 = bb0, t1 = bb1;
        t0 = fmaf(a.x, w00, t0); t1 = fmaf(a.x, w01, t1);
        t0 = fmaf(a.y, w10, t0); t1 = fmaf(a.y, w11, t1);
        t0 = fmaf(a.z, w20, t0); t1 = fmaf(a.z, w21, t1);
        t0 = fmaf(a.w, w30, t0); t1 = fmaf(a.w, w31, t1);
        t0 = fmaf(b.x, w40, t0); t1 = fmaf(b.x, w41, t1);
        t0 = fmaf(b.y, w50, t0); t1 = fmaf(b.y, w51, t1);
        t0 = fmaf(b.z, w60, t0); t1 = fmaf(b.z, w61, t1);
        float2 xv = *(const float2*)&x[(size_t)s * 2];
        m0 += fmaxf(t0 + xv.x, 0.f);
        m1 += fmaxf(t1 + xv.y, 0.f);
    }
#pragma unroll
    for (int off = 32; off > 0; off >>= 1) {
        m0 += __shfl_down(m0, off);
        m1 += __shfl_down(m1, off);
    }
    m0 = __shfl(m0, 0);
    m1 = __shfl(m1, 0);
    const float t0 = x[n * 2 + 0] + m0;
    const float t1 = x[n * 2 + 1] + m1;
    const int c = lane * 4;
    float4 wa = *(const float4*)&W1[c];
    float4 wb = *(const float4*)&W1[256 + c];
    float4 bv = *(const float4*)&b1[c];
    float4 r;
    r.x = fmaxf(fmaf(t0, wa.x, fmaf(t1, wb.x, bv.x)), 0.f);
    r.y = fmaxf(fmaf(t0, wa.y, fmaf(t1, wb.y, bv.y)), 0.f);
    r.z = fmaxf(fmaf(t0, wa.z, fmaf(t1, wb.z, bv.z)), 0.f);
    r.w = fmaxf(fmaf(t0, wa.w, fmaf(t1, wb.w, bv.w)), 0.f);
    union { float2 f; __half2 h[2]; } u;
    u.h[0] = __float22half2_rn(make_float2(r.x, r.y));
    u.h[1] = __float22half2_rn(make_float2(r.z, r.w));
    *(float2*)&hh[(size_t)n * HID + c] = u.f;
}

// ------------------------------------------------------------ layers 2..3 ---
// CSR gather from fp16 h. One wave/node; records scalarized (s_load);
// ping-pong pipeline, 4 edges per group, 8 h-loads in flight.
#define EDGEH(RA, RB, HRAW)                                           \
    do {                                                              \
        float4 m = bb;                                                \
        m.x = fmaf(RA.x, w0.x, m.x); m.y = fmaf(RA.x, w0.y, m.y);     \
        m.z = fmaf(RA.x, w0.z, m.z); m.w = fmaf(RA.x, w0.w, m.w);     \
        m.x = fmaf(RA.y, w1.x, m.x); m.y = fmaf(RA.y, w1.y, m.y);     \
        m.z = fmaf(RA.y, w1.z, m.z); m.w = fmaf(RA.y, w1.w, m.w);     \
        m.x = fmaf(RA.z, w2.x, m.x); m.y = fmaf(RA.z, w2.y, m.y);     \
        m.z = fmaf(RA.z, w2.z, m.z); m.w = fmaf(RA.z, w2.w, m.w);     \
        m.x = fmaf(RA.w, w3.x, m.x); m.y = fmaf(RA.w, w3.y, m.y);     \
        m.z = fmaf(RA.w, w3.z, m.z); m.w = fmaf(RA.w, w3.w, m.w);     \
        m.x = fmaf(RB.x, w4.x, m.x); m.y = fmaf(RB.x, w4.y, m.y);     \
        m.z = fmaf(RB.x, w4.z, m.z); m.w = fmaf(RB.x, w4.w, m.w);     \
        m.x = fmaf(RB.y, w5.x, m.x); m.y = fmaf(RB.y, w5.y, m.y);     \
        m.z = fmaf(RB.y, w5.z, m.z); m.w = fmaf(RB.y, w5.w, m.w);     \
        m.x = fmaf(RB.z, w6.x, m.x); m.y = fmaf(RB.z, w6.y, m.y);     \
        m.z = fmaf(RB.z, w6.z, m.z); m.w = fmaf(RB.z, w6.w, m.w);     \
        __half2 _p0 = *(__half2*)&HRAW.x;                             \
        __half2 _p1 = *(__half2*)&HRAW.y;                             \
        float2 _f0 = __half22float2(_p0);                             \
        float2 _f1 = __half22float2(_p1);                             \
        acc.x += fmaxf(m.x + _f0.x, 0.f);                             \
        acc.y += fmaxf(m.y + _f0.y, 0.f);                             \
        acc.z += fmaxf(m.z + _f1.x, 0.f);                             \
        acc.w += fmaxf(m.w + _f1.y, 0.f);                             \
    } while (0)

#define HLOAD(RB) (*(const float2*)(hh +                              \
        (size_t)__builtin_amdgcn_readfirstlane(__float_as_int(RB.w)) * HID + c4))

#define LOADG(A0, B0, A1, B1, A2, B2, A3, B3, H0, H1, H2, H3, G)      \
    do {                                                              \
        const float4* _rp = rp + (size_t)(G) * 8;                     \
        A0 = _rp[0]; B0 = _rp[1]; A1 = _rp[2]; B1 = _rp[3];           \
        A2 = _rp[4]; B2 = _rp[5]; A3 = _rp[6]; B3 = _rp[7];           \
        H0 = HLOAD(B0); H1 = HLOAD(B1);                               \
        H2 = HLOAD(B2); H3 = HLOAD(B3);                               \
    } while (0)

#define CONS4(A0, B0, A1, B1, A2, B2, A3, B3, H0, H1, H2, H3)         \
    do {                                                              \
        EDGEH(A0, B0, H0); EDGEH(A1, B1, H1);                         \
        EDGEH(A2, B2, H2); EDGEH(A3, B3, H3);                         \
    } while (0)

__global__ __launch_bounds__(256) void aggr2_kernel(
        const __half* __restrict__ hh,    // [N][256] fp16
        const float* __restrict__ rec,    // [E][8] dst-sorted {ea0..6, src}
        const int* __restrict__ base,     // [N+1]
        const float* __restrict__ We2,    // [7][256]
        const float* __restrict__ be2,    // [256]
        float* __restrict__ accum) {      // [N][256] fp32 out
    const int lane = threadIdx.x & 63;
    const int n = blockIdx.x * 4 + (threadIdx.x >> 6);
    if (n >= N_NODES) return;
    const int c4 = lane * 4;
    float4 w0 = *(const float4*)&We2[0 * HID + c4];
    float4 w1 = *(const float4*)&We2[1 * HID + c4];
    float4 w2 = *(const float4*)&We2[2 * HID + c4];
    float4 w3 = *(const float4*)&We2[3 * HID + c4];
    float4 w4 = *(const float4*)&We2[4 * HID + c4];
    float4 w5 = *(const float4*)&We2[5 * HID + c4];
    float4 w6 = *(const float4*)&We2[6 * HID + c4];
    const float4 bb = *(const float4*)&be2[c4];

    // acc init = h[n] (fp16 -> fp32)
    float4 acc;
    {
        float2 raw = *(const float2*)(hh + (size_t)n * HID + c4);
        __half2 p0 = *(__half2*)&raw.x;
        __half2 p1 = *(__half2*)&raw.y;
        float2 f0 = __half22float2(p0), f1 = __half22float2(p1);
        acc = make_float4(f0.x, f0.y, f1.x, f1.y);
    }
    // scalarize the per-node CSR window
    const int s0 = __builtin_amdgcn_readfirstlane(base[n]);
    const int deg = __builtin_amdgcn_readfirstlane(base[n + 1]) - s0;
    const float4* rp = (const float4*)rec + (size_t)s0 * 2;
    const int ng = deg >> 2;

    float4 r0a, r0b, r1a, r1b, r2a, r2b, r3a, r3b;
    float2 rh0, rh1, rh2, rh3;
    float4 t0a, t0b, t1a, t1b, t2a, t2b, t3a, t3b;
    float2 th0, th1, th2, th3;

    if (ng > 0) {
        LOADG(r0a, r0b, r1a, r1b, r2a, r2b, r3a, r3b, rh0, rh1, rh2, rh3, 0);
        int g = 1;
        for (; g + 1 < ng; g += 2) {
            LOADG(t0a, t0b, t1a, t1b, t2a, t2b, t3a, t3b, th0, th1, th2, th3, g);
            CONS4(r0a, r0b, r1a, r1b, r2a, r2b, r3a, r3b, rh0, rh1, rh2, rh3);
            LOADG(r0a, r0b, r1a, r1b, r2a, r2b, r3a, r3b, rh0, rh1, rh2, rh3, g + 1);
            CONS4(t0a, t0b, t1a, t1b, t2a, t2b, t3a, t3b, th0, th1, th2, th3);
        }
        if (g < ng) {
            LOADG(t0a, t0b, t1a, t1b, t2a, t2b, t3a, t3b, th0, th1, th2, th3, g);
            CONS4(r0a, r0b, r1a, r1b, r2a, r2b, r3a, r3b, rh0, rh1, rh2, rh3);
            CONS4(t0a, t0b, t1a, t1b, t2a, t2b, t3a, t3b, th0, th1, th2, th3);
        } else {
            CONS4(r0a, r0b, r1a, r1b, r2a, r2b, r3a, r3b, rh0, rh1, rh2, rh3);
        }
    }
    for (int i = ng * 4; i < deg; ++i) {   // remainder 0..3 edges
        float4 ra = rp[(size_t)i * 2], rbv = rp[(size_t)i * 2 + 1];
        float2 hv = HLOAD(rbv);
        EDGEH(ra, rbv, hv);
    }
    *(float4*)&accum[(size_t)n * HID + c4] = acc;
}

// ---------------------------------------------------------------- node MLP ---
// out = relu(T @ W2 + b2) written as fp16. Block: 64 nodes x 128-col slab;
// thread: 8 nodes x 4 cols strided by 32 (conflict-free b32 Ws reads).
#define BN 64
#define BK 32
#define TS_P 36
#define WS_P 132
__global__ __launch_bounds__(256) void node2_kernel(
        const float* __restrict__ T,    // [N][256] fp32
        const float* __restrict__ W,    // [256][256]
        const float* __restrict__ b,    // [256]
        __half* __restrict__ outh) {    // [N][256] fp16 (relu'd)
    __shared__ float Ts[BN * TS_P];     // [node][k]
    __shared__ float Ws[BK * WS_P];     // [k][col in slab]
    const int t = threadIdx.x;
    const int n0 = (blockIdx.x >> 1) * BN;
    const int coff = (blockIdx.x & 1) * 128;
    const int cc = t & 31;
    const int nn = t >> 5;
    float acc[8][4];
#pragma unroll
    for (int i = 0; i < 8; ++i)
#pragma unroll
        for (int j = 0; j < 4; ++j) acc[i][j] = 0.f;

    for (int k0 = 0; k0 < HID; k0 += BK) {
        __syncthreads();
        {   // stage T
            int row = t >> 2;
            int koff = (t & 3) * 8;
            int n = n0 + row;
            float4 v0 = make_float4(0.f, 0.f, 0.f, 0.f), v1 = v0;
            if (n < N_NODES) {
                v0 = *(const float4*)&T[(size_t)n * HID + k0 + koff];
                v1 = *(const float4*)&T[(size_t)n * HID + k0 + koff + 4];
            }
            *(float4*)&Ts[row * TS_P + koff] = v0;
            *(float4*)&Ts[row * TS_P + koff + 4] = v1;
        }
        {   // stage W slab
            int row = t >> 3;
            int cb = (t & 7) * 16;
            const float* wg = &W[(size_t)(k0 + row) * HID + coff + cb];
            float* wl = &Ws[row * WS_P + cb];
            *(float4*)(wl + 0)  = *(const float4*)(wg + 0);
            *(float4*)(wl + 4)  = *(const float4*)(wg + 4);
            *(float4*)(wl + 8)  = *(const float4*)(wg + 8);
            *(float4*)(wl + 12) = *(const float4*)(wg + 12);
        }
        __syncthreads();
#pragma unroll
        for (int k = 0; k < BK; k += 2) {
            float wa0 = Ws[k * WS_P + cc];
            float wa1 = Ws[k * WS_P + cc + 32];
            float wa2 = Ws[k * WS_P + cc + 64];
            float wa3 = Ws[k * WS_P + cc + 96];
            float wb0 = Ws[(k + 1) * WS_P + cc];
            float wb1 = Ws[(k + 1) * WS_P + cc + 32];
            float wb2 = Ws[(k + 1) * WS_P + cc + 64];
            float wb3 = Ws[(k + 1) * WS_P + cc + 96];
#pragma unroll
            for (int i = 0; i < 8; ++i) {
                float2 a = *(const float2*)&Ts[(nn * 8 + i) * TS_P + k];
                acc[i][0] = fmaf(a.x, wa0, acc[i][0]);
                acc[i][1] = fmaf(a.x, wa1, acc[i][1]);
                acc[i][2] = fmaf(a.x, wa2, acc[i][2]);
                acc[i][3] = fmaf(a.x, wa3, acc[i][3]);
                acc[i][0] = fmaf(a.y, wb0, acc[i][0]);
                acc[i][1] = fmaf(a.y, wb1, acc[i][1]);
                acc[i][2] = fmaf(a.y, wb2, acc[i][2]);
                acc[i][3] = fmaf(a.y, wb3, acc[i][3]);
            }
        }
    }
    const float bv0 = b[coff + cc];
    const float bv1 = b[coff + cc + 32];
    const float bv2 = b[coff + cc + 64];
    const float bv3 = b[coff + cc + 96];
#pragma unroll
    for (int i = 0; i < 8; ++i) {
        int n = n0 + nn * 8 + i;
        if (n < N_NODES) {
            __half* op = &outh[(size_t)n * HID + coff + cc];
            op[0]  = __float2half(fmaxf(acc[i][0] + bv0, 0.f));
            op[32] = __float2half(fmaxf(acc[i][1] + bv1, 0.f));
            op[64] = __float2half(fmaxf(acc[i][2] + bv2, 0.f));
            op[96] = __float2half(fmaxf(acc[i][3] + bv3, 0.f));
        }
    }
}

// ------------------------------------------------------------------ final ---
__global__ void end_kernel(const __half* __restrict__ hh,
                           const float* __restrict__ Wend,  // [256]
                           const float* __restrict__ bend,  // [1]
                           float* __restrict__ out) {
    int n = blockIdx.x * 4 + (threadIdx.x >> 6);
    if (n >= N_NODES) return;
    int lane = threadIdx.x & 63;
    float2 raw = *(const float2*)(hh + (size_t)n * HID + lane * 4);
    __half2 p0 = *(__half2*)&raw.x;
    __half2 p1 = *(__half2*)&raw.y;
    float2 f0 = __half22float2(p0), f1 = __half22float2(p1);
    float4 w4 = *(const float4*)&Wend[lane * 4];
    float s = f0.x * w4.x + f0.y * w4.y + f1.x * w4.z + f1.y * w4.w;
#pragma unroll
    for (int off = 32; off > 0; off >>= 1) s += __shfl_down(s, off);
    if (lane == 0) out[n] = 1.f / (1.f + expf(-(s + bend[0])));
}

// ------------------------------------------------------------------ launch ---
extern "C" void kernel_launch(void* const* d_in, const int* in_sizes, int n_in,
                              void* d_out, int out_size, void* d_ws, size_t ws_size,
                              hipStream_t stream) {
    const float* x    = (const float*)d_in[0];
    const int*   ei   = (const int*)d_in[1];
    const float* ea   = (const float*)d_in[2];
    const float* We1  = (const float*)d_in[3];
    const float* be1  = (const float*)d_in[4];
    const float* W1   = (const float*)d_in[5];
    const float* b1   = (const float*)d_in[6];
    const float* We2  = (const float*)d_in[7];
    const float* be2  = (const float*)d_in[8];
    const float* W2   = (const float*)d_in[9];
    const float* b2   = (const float*)d_in[10];
    const float* Wend = (const float*)d_in[11];
    const float* bend = (const float*)d_in[12];
    float* out = (float*)d_out;

    const int* src = ei;
    const int* dst = ei + N_EDGES;

    const size_t HN = (size_t)N_NODES * HID;          // 12.8M elements
    float*  B     = (float*)d_ws;                     // [N][256] fp32 accum
    __half* Ah    = (__half*)(B + HN);                // [N][256] fp16 h
    float*  rec   = (float*)(Ah + HN);                // [E][8]
    int*   deg    = (int*)(rec + (size_t)N_EDGES * 8);// [N]
    int*   cursor = deg + N_NODES;                    // [N]
    int*   base   = cursor + N_NODES;                 // [N+2]
    int*   bsum   = base + N_NODES + 2;               // [256]
    // total ≈ 129 MB

    // ---- CSR build + record sort (shared by all 3 layers)
    hipMemsetAsync(deg, 0, (size_t)N_NODES * 2 * sizeof(int), stream);  // deg+cursor
    hist_kernel<<<(N_EDGES + 255) / 256, 256, 0, stream>>>(dst, deg);
    scan1_kernel<<<SCAN_B, 256, 0, stream>>>(deg, bsum);
    scan2_kernel<<<1, 256, 0, stream>>>(bsum);
    scan3_kernel<<<SCAN_B, 256, 0, stream>>>(deg, bsum, base);
    scatter_rec_kernel<<<(N_EDGES + 255) / 256, 256, 0, stream>>>(src, dst, ea, base,
                                                                  cursor, rec);

    // ---- layer 1 (fused gather + MLP) -> Ah (fp16)
    layer1_kernel<<<(N_NODES + 3) / 4, 256, 0, stream>>>(x, rec, base, We1, be1,
                                                         W1, b1, Ah);

    const int N2_B = ((N_NODES + BN - 1) / BN) * 2;   // col-slab split
    // ---- layer 2
    aggr2_kernel<<<(N_NODES + 3) / 4, 256, 0, stream>>>(Ah, rec, base, We2, be2, B);
    node2_kernel<<<N2_B, 256, 0, stream>>>(B, W2, b2, Ah);
    // ---- layer 3
    aggr2_kernel<<<(N_NODES + 3) / 4, 256, 0, stream>>>(Ah, rec, base, We2, be2, B);
    node2_kernel<<<N2_B, 256, 0, stream>>>(B, W2, b2, Ah);
    // ---- head
    end_kernel<<<(N_NODES + 3) / 4, 256, 0, stream>>>(Ah, Wend, bend, out);
}

// Round 9
// 595.877 us; speedup vs baseline: 18.7406x; 1.2684x over previous
//
#include <hip/hip_runtime.h>
#include <hip/hip_fp16.h>
#include <math.h>

#define N_NODES 50000
#define N_EDGES 1600000
#define HID 256
#define SCAN_B 196   // ceil(N_NODES/256)
// eps = 0

typedef _Float16 f16x8 __attribute__((ext_vector_type(8)));
typedef float f32x4 __attribute__((ext_vector_type(4)));

// ROCm 7.2 has no __hmax2 — emit v_pk_max_f16 directly.
static __device__ __forceinline__ __half2 pk_max2(__half2 a, __half2 b) {
    unsigned au = *reinterpret_cast<unsigned*>(&a);
    unsigned bu = *reinterpret_cast<unsigned*>(&b);
    unsigned r;
    asm("v_pk_max_f16 %0, %1, %2" : "=v"(r) : "v"(au), "v"(bu));
    return *reinterpret_cast<__half2*>(&r);
}

// ---------------------------------------------------------------- CSR build ---
__global__ void hist_kernel(const int* __restrict__ dst, int* __restrict__ deg) {
    int e = blockIdx.x * blockDim.x + threadIdx.x;
    if (e < N_EDGES) atomicAdd(&deg[dst[e]], 1);
}

__global__ __launch_bounds__(256) void scan1_kernel(const int* __restrict__ deg,
                                                    int* __restrict__ bsum) {
    int idx = blockIdx.x * 256 + threadIdx.x;
    int v = (idx < N_NODES) ? deg[idx] : 0;
#pragma unroll
    for (int off = 32; off > 0; off >>= 1) v += __shfl_down(v, off);
    __shared__ int ws[4];
    if ((threadIdx.x & 63) == 0) ws[threadIdx.x >> 6] = v;
    __syncthreads();
    if (threadIdx.x == 0) bsum[blockIdx.x] = ws[0] + ws[1] + ws[2] + ws[3];
}

__global__ __launch_bounds__(256) void scan2_kernel(int* __restrict__ bsum) {
    __shared__ int s[256];
    int t = threadIdx.x;
    int v = (t < SCAN_B) ? bsum[t] : 0;
    s[t] = v;
    __syncthreads();
    for (int off = 1; off < 256; off <<= 1) {
        int u = (t >= off) ? s[t - off] : 0;
        __syncthreads();
        s[t] += u;
        __syncthreads();
    }
    if (t < SCAN_B) bsum[t] = s[t] - v;  // exclusive
}

__global__ __launch_bounds__(256) void scan3_kernel(const int* __restrict__ deg,
                                                    const int* __restrict__ bsum,
                                                    int* __restrict__ base) {
    __shared__ int s[256];
    int t = threadIdx.x;
    int idx = blockIdx.x * 256 + t;
    int v = (idx < N_NODES) ? deg[idx] : 0;
    s[t] = v;
    __syncthreads();
    for (int off = 1; off < 256; off <<= 1) {
        int u = (t >= off) ? s[t - off] : 0;
        __syncthreads();
        s[t] += u;
        __syncthreads();
    }
    if (idx < N_NODES) base[idx] = bsum[blockIdx.x] + s[t] - v;
    if (idx == 0) base[N_NODES] = N_EDGES;
}

// build dst-sorted 32B records: {half2(a0,a0)..half2(a6,a6), src_bits}
__global__ void scatter_rec_kernel(const int* __restrict__ src,
                                   const int* __restrict__ dst,
                                   const float* __restrict__ ea,
                                   const int* __restrict__ base,
                                   int* __restrict__ cursor,
                                   float* __restrict__ rec) {
    int e = blockIdx.x * blockDim.x + threadIdx.x;
    if (e >= N_EDGES) return;
    int d = dst[e];
    int pos = base[d] + atomicAdd(&cursor[d], 1);
    const float* ep = ea + (size_t)e * 7;
    float4 v0, v1;
    *(__half2*)&v0.x = __floats2half2_rn(ep[0], ep[0]);
    *(__half2*)&v0.y = __floats2half2_rn(ep[1], ep[1]);
    *(__half2*)&v0.z = __floats2half2_rn(ep[2], ep[2]);
    *(__half2*)&v0.w = __floats2half2_rn(ep[3], ep[3]);
    *(__half2*)&v1.x = __floats2half2_rn(ep[4], ep[4]);
    *(__half2*)&v1.y = __floats2half2_rn(ep[5], ep[5]);
    *(__half2*)&v1.z = __floats2half2_rn(ep[6], ep[6]);
    v1.w = __int_as_float(src[e]);
    float* rp = rec + (size_t)pos * 8;
    *(float4*)rp       = v0;
    *(float4*)(rp + 4) = v1;
}

// ---------------------------------------------------------------- layer 1 ---
// fused gather + node MLP; writes h as fp16
__global__ __launch_bounds__(256) void layer1_kernel(
        const float* __restrict__ x,     // [N][2]
        const float* __restrict__ rec,   // [E][8] (ea as dup'd half2)
        const int* __restrict__ base,    // [N+1]
        const float* __restrict__ We1,   // [7][2]
        const float* __restrict__ be1,   // [2]
        const float* __restrict__ W1,    // [2][256]
        const float* __restrict__ b1,    // [256]
        __half* __restrict__ hh) {       // [N][256] fp16
    const int lane = threadIdx.x & 63;
    const int wid = threadIdx.x >> 6;
    const int n = blockIdx.x * 4 + wid;
    if (n >= N_NODES) return;
    float w00 = We1[0],  w01 = We1[1],  w10 = We1[2],  w11 = We1[3];
    float w20 = We1[4],  w21 = We1[5],  w30 = We1[6],  w31 = We1[7];
    float w40 = We1[8],  w41 = We1[9],  w50 = We1[10], w51 = We1[11];
    float w60 = We1[12], w61 = We1[13];
    float bb0 = be1[0], bb1 = be1[1];
    float m0 = 0.f, m1 = 0.f;
    const int s0 = base[n], s1 = base[n + 1];
    for (int pos = s0 + lane; pos < s1; pos += 64) {
        const float* p = rec + (size_t)pos * 8;
        float4 a = *(const float4*)p;
        float4 b = *(const float4*)(p + 4);
        int s = __float_as_int(b.w);
        float a0 = __low2float(*(__half2*)&a.x);
        float a1 = __low2float(*(__half2*)&a.y);
        float a2 = __low2float(*(__half2*)&a.z);
        float a3 = __low2float(*(__half2*)&a.w);
        float a4 = __low2float(*(__half2*)&b.x);
        float a5 = __low2float(*(__half2*)&b.y);
        float a6 = __low2float(*(__half2*)&b.z);
        float t0 = bb0, t1 = bb1;
        t0 = fmaf(a0, w00, t0); t1 = fmaf(a0, w01, t1);
        t0 = fmaf(a1, w10, t0); t1 = fmaf(a1, w11, t1);
        t0 = fmaf(a2, w20, t0); t1 = fmaf(a2, w21, t1);
        t0 = fmaf(a3, w30, t0); t1 = fmaf(a3, w31, t1);
        t0 = fmaf(a4, w40, t0); t1 = fmaf(a4, w41, t1);
        t0 = fmaf(a5, w50, t0); t1 = fmaf(a5, w51, t1);
        t0 = fmaf(a6, w60, t0); t1 = fmaf(a6, w61, t1);
        float2 xv = *(const float2*)&x[(size_t)s * 2];
        m0 += fmaxf(t0 + xv.x, 0.f);
        m1 += fmaxf(t1 + xv.y, 0.f);
    }
#pragma unroll
    for (int off = 32; off > 0; off >>= 1) {
        m0 += __shfl_down(m0, off);
        m1 += __shfl_down(m1, off);
    }
    m0 = __shfl(m0, 0);
    m1 = __shfl(m1, 0);
    const float t0 = x[n * 2 + 0] + m0;
    const float t1 = x[n * 2 + 1] + m1;
    const int c = lane * 4;
    float4 wa = *(const float4*)&W1[c];
    float4 wb = *(const float4*)&W1[256 + c];
    float4 bv = *(const float4*)&b1[c];
    float4 r;
    r.x = fmaxf(fmaf(t0, wa.x, fmaf(t1, wb.x, bv.x)), 0.f);
    r.y = fmaxf(fmaf(t0, wa.y, fmaf(t1, wb.y, bv.y)), 0.f);
    r.z = fmaxf(fmaf(t0, wa.z, fmaf(t1, wb.z, bv.z)), 0.f);
    r.w = fmaxf(fmaf(t0, wa.w, fmaf(t1, wb.w, bv.w)), 0.f);
    union { float2 f; __half2 h[2]; } u;
    u.h[0] = __float22half2_rn(make_float2(r.x, r.y));
    u.h[1] = __float22half2_rn(make_float2(r.z, r.w));
    *(float2*)&hh[(size_t)n * HID + c] = u.f;
}

// ------------------------------------------------------------ layers 2..3 ---
// CSR gather from fp16 h, packed-fp16 edge MLP (14 pk_fma), fp32 accumulate.
// One wave/node; ping-pong pipeline, 4 edges/group, 8 h-loads in flight.
#define EDGEH(RA, RB, HV)                                              \
    do {                                                               \
        __half2 _a0 = *(__half2*)&RA.x, _a1 = *(__half2*)&RA.y;        \
        __half2 _a2 = *(__half2*)&RA.z, _a3 = *(__half2*)&RA.w;        \
        __half2 _a4 = *(__half2*)&RB.x, _a5 = *(__half2*)&RB.y;        \
        __half2 _a6 = *(__half2*)&RB.z;                                \
        __half2 _m0 = bb01, _m1 = bb23;                                \
        _m0 = __hfma2(_a0, w0a, _m0); _m1 = __hfma2(_a0, w0b, _m1);    \
        _m0 = __hfma2(_a1, w1a, _m0); _m1 = __hfma2(_a1, w1b, _m1);    \
        _m0 = __hfma2(_a2, w2a, _m0); _m1 = __hfma2(_a2, w2b, _m1);    \
        _m0 = __hfma2(_a3, w3a, _m0); _m1 = __hfma2(_a3, w3b, _m1);    \
        _m0 = __hfma2(_a4, w4a, _m0); _m1 = __hfma2(_a4, w4b, _m1);    \
        _m0 = __hfma2(_a5, w5a, _m0); _m1 = __hfma2(_a5, w5b, _m1);    \
        _m0 = __hfma2(_a6, w6a, _m0); _m1 = __hfma2(_a6, w6b, _m1);    \
        __half2 _h0 = *(__half2*)&HV.x, _h1 = *(__half2*)&HV.y;        \
        _m0 = pk_max2(__hadd2(_m0, _h0), z2);                          \
        _m1 = pk_max2(__hadd2(_m1, _h1), z2);                          \
        acc.x += __low2float(_m0); acc.y += __high2float(_m0);         \
        acc.z += __low2float(_m1); acc.w += __high2float(_m1);         \
    } while (0)

#define HLOAD(RB) (*(const float2*)(hh +                               \
        (size_t)__builtin_amdgcn_readfirstlane(__float_as_int(RB.w)) * HID + c4))

#define LOADG(A0, B0, A1, B1, A2, B2, A3, B3, H0, H1, H2, H3, G)       \
    do {                                                               \
        const float4* _rp = rp + (size_t)(G) * 8;                      \
        A0 = _rp[0]; B0 = _rp[1]; A1 = _rp[2]; B1 = _rp[3];            \
        A2 = _rp[4]; B2 = _rp[5]; A3 = _rp[6]; B3 = _rp[7];            \
        H0 = HLOAD(B0); H1 = HLOAD(B1);                                \
        H2 = HLOAD(B2); H3 = HLOAD(B3);                                \
    } while (0)

#define CONS4(A0, B0, A1, B1, A2, B2, A3, B3, H0, H1, H2, H3)          \
    do {                                                               \
        EDGEH(A0, B0, H0); EDGEH(A1, B1, H1);                          \
        EDGEH(A2, B2, H2); EDGEH(A3, B3, H3);                          \
    } while (0)

__global__ __launch_bounds__(256) void aggr2_kernel(
        const __half* __restrict__ hh,    // [N][256] fp16
        const float* __restrict__ rec,    // [E][8] dst-sorted packed records
        const int* __restrict__ base,     // [N+1]
        const float* __restrict__ We2,    // [7][256] fp32
        const float* __restrict__ be2,    // [256] fp32
        __half* __restrict__ accum) {     // [N][256] fp16 out
    const int lane = threadIdx.x & 63;
    const int n = blockIdx.x * 4 + (threadIdx.x >> 6);
    if (n >= N_NODES) return;
    const int c4 = lane * 4;
    // lane's 4 columns of We2 as half2 pairs
    __half2 w0a = __floats2half2_rn(We2[0 * HID + c4], We2[0 * HID + c4 + 1]);
    __half2 w0b = __floats2half2_rn(We2[0 * HID + c4 + 2], We2[0 * HID + c4 + 3]);
    __half2 w1a = __floats2half2_rn(We2[1 * HID + c4], We2[1 * HID + c4 + 1]);
    __half2 w1b = __floats2half2_rn(We2[1 * HID + c4 + 2], We2[1 * HID + c4 + 3]);
    __half2 w2a = __floats2half2_rn(We2[2 * HID + c4], We2[2 * HID + c4 + 1]);
    __half2 w2b = __floats2half2_rn(We2[2 * HID + c4 + 2], We2[2 * HID + c4 + 3]);
    __half2 w3a = __floats2half2_rn(We2[3 * HID + c4], We2[3 * HID + c4 + 1]);
    __half2 w3b = __floats2half2_rn(We2[3 * HID + c4 + 2], We2[3 * HID + c4 + 3]);
    __half2 w4a = __floats2half2_rn(We2[4 * HID + c4], We2[4 * HID + c4 + 1]);
    __half2 w4b = __floats2half2_rn(We2[4 * HID + c4 + 2], We2[4 * HID + c4 + 3]);
    __half2 w5a = __floats2half2_rn(We2[5 * HID + c4], We2[5 * HID + c4 + 1]);
    __half2 w5b = __floats2half2_rn(We2[5 * HID + c4 + 2], We2[5 * HID + c4 + 3]);
    __half2 w6a = __floats2half2_rn(We2[6 * HID + c4], We2[6 * HID + c4 + 1]);
    __half2 w6b = __floats2half2_rn(We2[6 * HID + c4 + 2], We2[6 * HID + c4 + 3]);
    __half2 bb01 = __floats2half2_rn(be2[c4], be2[c4 + 1]);
    __half2 bb23 = __floats2half2_rn(be2[c4 + 2], be2[c4 + 3]);
    const __half2 z2 = __float2half2_rn(0.f);

    // acc init = h[n] (fp16 -> fp32)
    float4 acc;
    {
        float2 raw = *(const float2*)(hh + (size_t)n * HID + c4);
        __half2 p0 = *(__half2*)&raw.x;
        __half2 p1 = *(__half2*)&raw.y;
        float2 f0 = __half22float2(p0), f1 = __half22float2(p1);
        acc = make_float4(f0.x, f0.y, f1.x, f1.y);
    }
    const int s0 = __builtin_amdgcn_readfirstlane(base[n]);
    const int deg = __builtin_amdgcn_readfirstlane(base[n + 1]) - s0;
    const float4* rp = (const float4*)rec + (size_t)s0 * 2;
    const int ng = deg >> 2;

    float4 r0a, r0b, r1a, r1b, r2a, r2b, r3a, r3b;
    float2 rh0, rh1, rh2, rh3;
    float4 t0a, t0b, t1a, t1b, t2a, t2b, t3a, t3b;
    float2 th0, th1, th2, th3;

    if (ng > 0) {
        LOADG(r0a, r0b, r1a, r1b, r2a, r2b, r3a, r3b, rh0, rh1, rh2, rh3, 0);
        int g = 1;
        for (; g + 1 < ng; g += 2) {
            LOADG(t0a, t0b, t1a, t1b, t2a, t2b, t3a, t3b, th0, th1, th2, th3, g);
            CONS4(r0a, r0b, r1a, r1b, r2a, r2b, r3a, r3b, rh0, rh1, rh2, rh3);
            LOADG(r0a, r0b, r1a, r1b, r2a, r2b, r3a, r3b, rh0, rh1, rh2, rh3, g + 1);
            CONS4(t0a, t0b, t1a, t1b, t2a, t2b, t3a, t3b, th0, th1, th2, th3);
        }
        if (g < ng) {
            LOADG(t0a, t0b, t1a, t1b, t2a, t2b, t3a, t3b, th0, th1, th2, th3, g);
            CONS4(r0a, r0b, r1a, r1b, r2a, r2b, r3a, r3b, rh0, rh1, rh2, rh3);
            CONS4(t0a, t0b, t1a, t1b, t2a, t2b, t3a, t3b, th0, th1, th2, th3);
        } else {
            CONS4(r0a, r0b, r1a, r1b, r2a, r2b, r3a, r3b, rh0, rh1, rh2, rh3);
        }
    }
    for (int i = ng * 4; i < deg; ++i) {   // remainder 0..3 edges
        float4 ra = rp[(size_t)i * 2], rbv = rp[(size_t)i * 2 + 1];
        float2 hv = HLOAD(rbv);
        EDGEH(ra, rbv, hv);
    }
    // store fp16
    float2 of;
    *(__half2*)&of.x = __floats2half2_rn(acc.x, acc.y);
    *(__half2*)&of.y = __floats2half2_rn(acc.z, acc.w);
    *(float2*)&accum[(size_t)n * HID + c4] = of;
}

// ------------------------------------------------- W2 -> fp16 B-frag swizzle ---
// W2s[((ct*8+kc)*64+lane)*8 + j] = W2[kc*32 + (lane>>4)*8 + j][ct*16 + (lane&15)]
__global__ __launch_bounds__(256) void w2_swizzle_kernel(const float* __restrict__ W,
                                                         __half* __restrict__ W2s) {
    int t = blockIdx.x * 256 + threadIdx.x;   // 16*8*64 = 8192
    if (t >= 16 * 8 * 64) return;
    int lane = t & 63;
    int kc = (t >> 6) & 7;
    int ct = t >> 9;
    int k0 = kc * 32 + (lane >> 4) * 8;
    int col = ct * 16 + (lane & 15);
#pragma unroll
    for (int j = 0; j < 8; ++j)
        W2s[(size_t)t * 8 + j] = __float2half(W[(size_t)(k0 + j) * HID + col]);
}

// ---------------------------------------------------------------- node MLP ---
// out = relu(A @ W2 + b2) via mfma_f32_16x16x32_f16.
// Block = 4 waves x 16 nodes; wave covers 16 nodes x 256 cols, K=256.
__global__ __launch_bounds__(256) void node2_mfma_kernel(
        const __half* __restrict__ A,     // [N][256] fp16 (accum)
        const __half* __restrict__ W2s,   // swizzled B-frags
        const float* __restrict__ b,      // [256]
        __half* __restrict__ outh) {      // [N][256] fp16 (relu'd)
    const int lane = threadIdx.x & 63;
    const int wv = threadIdx.x >> 6;
    const int n_base = blockIdx.x * 64 + wv * 16;
    if (n_base >= N_NODES) return;
    const int quad = lane >> 4;
    const int mrow = lane & 15;
    // A-frags for all 8 k-chunks: A[m=lane&15][k=quad*8+j]
    f16x8 af[8];
    const __half* ap = A + (size_t)(n_base + mrow) * HID + quad * 8;
#pragma unroll
    for (int kc = 0; kc < 8; ++kc)
        af[kc] = *(const f16x8*)(ap + kc * 32);
#pragma unroll
    for (int ct = 0; ct < 16; ++ct) {
        f32x4 c = {0.f, 0.f, 0.f, 0.f};
        const f16x8* bp = (const f16x8*)W2s + (size_t)(ct * 8) * 64 + lane;
#pragma unroll
        for (int kc = 0; kc < 8; ++kc)
            c = __builtin_amdgcn_mfma_f32_16x16x32_f16(af[kc], bp[(size_t)kc * 64],
                                                       c, 0, 0, 0);
        const int col = ct * 16 + mrow;            // D col = lane&15
        const float bias = b[col];
#pragma unroll
        for (int r = 0; r < 4; ++r) {              // D row = quad*4 + r
            int n = n_base + quad * 4 + r;
            if (n < N_NODES)
                outh[(size_t)n * HID + col] = __float2half(fmaxf(c[r] + bias, 0.f));
        }
    }
}

// ------------------------------------------------------------------ final ---
__global__ void end_kernel(const __half* __restrict__ hh,
                           const float* __restrict__ Wend,  // [256]
                           const float* __restrict__ bend,  // [1]
                           float* __restrict__ out) {
    int n = blockIdx.x * 4 + (threadIdx.x >> 6);
    if (n >= N_NODES) return;
    int lane = threadIdx.x & 63;
    float2 raw = *(const float2*)(hh + (size_t)n * HID + lane * 4);
    __half2 p0 = *(__half2*)&raw.x;
    __half2 p1 = *(__half2*)&raw.y;
    float2 f0 = __half22float2(p0), f1 = __half22float2(p1);
    float4 w4 = *(const float4*)&Wend[lane * 4];
    float s = f0.x * w4.x + f0.y * w4.y + f1.x * w4.z + f1.y * w4.w;
#pragma unroll
    for (int off = 32; off > 0; off >>= 1) s += __shfl_down(s, off);
    if (lane == 0) out[n] = 1.f / (1.f + expf(-(s + bend[0])));
}

// ------------------------------------------------------------------ launch ---
extern "C" void kernel_launch(void* const* d_in, const int* in_sizes, int n_in,
                              void* d_out, int out_size, void* d_ws, size_t ws_size,
                              hipStream_t stream) {
    const float* x    = (const float*)d_in[0];
    const int*   ei   = (const int*)d_in[1];
    const float* ea   = (const float*)d_in[2];
    const float* We1  = (const float*)d_in[3];
    const float* be1  = (const float*)d_in[4];
    const float* W1   = (const float*)d_in[5];
    const float* b1   = (const float*)d_in[6];
    const float* We2  = (const float*)d_in[7];
    const float* be2  = (const float*)d_in[8];
    const float* W2   = (const float*)d_in[9];
    const float* b2   = (const float*)d_in[10];
    const float* Wend = (const float*)d_in[11];
    const float* bend = (const float*)d_in[12];
    float* out = (float*)d_out;

    const int* src = ei;
    const int* dst = ei + N_EDGES;

    const size_t HN = (size_t)N_NODES * HID;           // 12.8M elements
    __half* Bh    = (__half*)d_ws;                     // [N][256] fp16 accum
    __half* Ah    = Bh + HN;                           // [N][256] fp16 h
    float*  rec   = (float*)(Ah + HN);                 // [E][8]
    __half* W2s   = (__half*)(rec + (size_t)N_EDGES * 8);  // 64K halves
    int*   deg    = (int*)(W2s + 16 * 8 * 64 * 8);     // [N]
    int*   cursor = deg + N_NODES;                     // [N]
    int*   base   = cursor + N_NODES;                  // [N+2]
    int*   bsum   = base + N_NODES + 2;                // [256]
    // total ≈ 103 MB

    // ---- CSR build + record sort (shared by all 3 layers)
    hipMemsetAsync(deg, 0, (size_t)N_NODES * 2 * sizeof(int), stream);  // deg+cursor
    hist_kernel<<<(N_EDGES + 255) / 256, 256, 0, stream>>>(dst, deg);
    scan1_kernel<<<SCAN_B, 256, 0, stream>>>(deg, bsum);
    scan2_kernel<<<1, 256, 0, stream>>>(bsum);
    scan3_kernel<<<SCAN_B, 256, 0, stream>>>(deg, bsum, base);
    scatter_rec_kernel<<<(N_EDGES + 255) / 256, 256, 0, stream>>>(src, dst, ea, base,
                                                                  cursor, rec);
    w2_swizzle_kernel<<<32, 256, 0, stream>>>(W2, W2s);

    // ---- layer 1 (fused gather + MLP) -> Ah (fp16)
    layer1_kernel<<<(N_NODES + 3) / 4, 256, 0, stream>>>(x, rec, base, We1, be1,
                                                         W1, b1, Ah);

    const int N2_B = (N_NODES + 63) / 64;
    // ---- layer 2
    aggr2_kernel<<<(N_NODES + 3) / 4, 256, 0, stream>>>(Ah, rec, base, We2, be2, Bh);
    node2_mfma_kernel<<<N2_B, 256, 0, stream>>>(Bh, W2s, b2, Ah);
    // ---- layer 3
    aggr2_kernel<<<(N_NODES + 3) / 4, 256, 0, stream>>>(Ah, rec, base, We2, be2, Bh);
    node2_mfma_kernel<<<N2_B, 256, 0, stream>>>(Bh, W2s, b2, Ah);
    // ---- head
    end_kernel<<<(N_NODES + 3) / 4, 256, 0, stream>>>(Ah, Wend, bend, out);
}

// Round 10
// 543.318 us; speedup vs baseline: 20.5535x; 1.0967x over previous
//
#include <hip/hip_runtime.h>
#include <hip/hip_fp16.h>
#include <math.h>

#define N_NODES 50000
#define N_EDGES 1600000
#define HID 256
#define SCAN_B 196   // ceil(N_NODES/256)
// eps = 0

typedef _Float16 f16x8 __attribute__((ext_vector_type(8)));
typedef float f32x4 __attribute__((ext_vector_type(4)));
typedef float v2f __attribute__((ext_vector_type(2)));

// ROCm 7.2 has no __hmax2 — emit v_pk_max_f16 directly.
static __device__ __forceinline__ __half2 pk_max2(__half2 a, __half2 b) {
    unsigned au = *reinterpret_cast<unsigned*>(&a);
    unsigned bu = *reinterpret_cast<unsigned*>(&b);
    unsigned r;
    asm("v_pk_max_f16 %0, %1, %2" : "=v"(r) : "v"(au), "v"(bu));
    return *reinterpret_cast<__half2*>(&r);
}

// 4 floats -> 4 fp8 (e4m3) packed in one dword
static __device__ __forceinline__ unsigned pack4_fp8(float a, float b, float c, float d) {
    int v = __builtin_amdgcn_cvt_pk_fp8_f32(a, b, 0, false);
    v = __builtin_amdgcn_cvt_pk_fp8_f32(c, d, v, true);
    return (unsigned)v;
}

// ---------------------------------------------------------------- CSR build ---
__global__ void hist_kernel(const int* __restrict__ dst, int* __restrict__ deg) {
    int e = blockIdx.x * blockDim.x + threadIdx.x;
    if (e < N_EDGES) atomicAdd(&deg[dst[e]], 1);
}

__global__ __launch_bounds__(256) void scan1_kernel(const int* __restrict__ deg,
                                                    int* __restrict__ bsum) {
    int idx = blockIdx.x * 256 + threadIdx.x;
    int v = (idx < N_NODES) ? deg[idx] : 0;
#pragma unroll
    for (int off = 32; off > 0; off >>= 1) v += __shfl_down(v, off);
    __shared__ int ws[4];
    if ((threadIdx.x & 63) == 0) ws[threadIdx.x >> 6] = v;
    __syncthreads();
    if (threadIdx.x == 0) bsum[blockIdx.x] = ws[0] + ws[1] + ws[2] + ws[3];
}

__global__ __launch_bounds__(256) void scan2_kernel(int* __restrict__ bsum) {
    __shared__ int s[256];
    int t = threadIdx.x;
    int v = (t < SCAN_B) ? bsum[t] : 0;
    s[t] = v;
    __syncthreads();
    for (int off = 1; off < 256; off <<= 1) {
        int u = (t >= off) ? s[t - off] : 0;
        __syncthreads();
        s[t] += u;
        __syncthreads();
    }
    if (t < SCAN_B) bsum[t] = s[t] - v;  // exclusive
}

__global__ __launch_bounds__(256) void scan3_kernel(const int* __restrict__ deg,
                                                    const int* __restrict__ bsum,
                                                    int* __restrict__ base) {
    __shared__ int s[256];
    int t = threadIdx.x;
    int idx = blockIdx.x * 256 + t;
    int v = (idx < N_NODES) ? deg[idx] : 0;
    s[t] = v;
    __syncthreads();
    for (int off = 1; off < 256; off <<= 1) {
        int u = (t >= off) ? s[t - off] : 0;
        __syncthreads();
        s[t] += u;
        __syncthreads();
    }
    if (idx < N_NODES) base[idx] = bsum[blockIdx.x] + s[t] - v;
    if (idx == 0) base[N_NODES] = N_EDGES;
}

// build dst-sorted 32B records: {half2(a0,a0)..half2(a6,a6), src_bits}
__global__ void scatter_rec_kernel(const int* __restrict__ src,
                                   const int* __restrict__ dst,
                                   const float* __restrict__ ea,
                                   const int* __restrict__ base,
                                   int* __restrict__ cursor,
                                   float* __restrict__ rec) {
    int e = blockIdx.x * blockDim.x + threadIdx.x;
    if (e >= N_EDGES) return;
    int d = dst[e];
    int pos = base[d] + atomicAdd(&cursor[d], 1);
    const float* ep = ea + (size_t)e * 7;
    float4 v0, v1;
    *(__half2*)&v0.x = __floats2half2_rn(ep[0], ep[0]);
    *(__half2*)&v0.y = __floats2half2_rn(ep[1], ep[1]);
    *(__half2*)&v0.z = __floats2half2_rn(ep[2], ep[2]);
    *(__half2*)&v0.w = __floats2half2_rn(ep[3], ep[3]);
    *(__half2*)&v1.x = __floats2half2_rn(ep[4], ep[4]);
    *(__half2*)&v1.y = __floats2half2_rn(ep[5], ep[5]);
    *(__half2*)&v1.z = __floats2half2_rn(ep[6], ep[6]);
    v1.w = __int_as_float(src[e]);
    float* rp = rec + (size_t)pos * 8;
    *(float4*)rp       = v0;
    *(float4*)(rp + 4) = v1;
}

// ---------------------------------------------------------------- layer 1 ---
// fused gather + node MLP; writes h as fp8 (one dword = lane's 4 channels)
__global__ __launch_bounds__(256) void layer1_kernel(
        const float* __restrict__ x,     // [N][2]
        const float* __restrict__ rec,   // [E][8] (ea as dup'd half2)
        const int* __restrict__ base,    // [N+1]
        const float* __restrict__ We1,   // [7][2]
        const float* __restrict__ be1,   // [2]
        const float* __restrict__ W1,    // [2][256]
        const float* __restrict__ b1,    // [256]
        unsigned* __restrict__ h8) {     // [N][64] dwords (fp8 x4)
    const int lane = threadIdx.x & 63;
    const int wid = threadIdx.x >> 6;
    const int n = blockIdx.x * 4 + wid;
    if (n >= N_NODES) return;
    float w00 = We1[0],  w01 = We1[1],  w10 = We1[2],  w11 = We1[3];
    float w20 = We1[4],  w21 = We1[5],  w30 = We1[6],  w31 = We1[7];
    float w40 = We1[8],  w41 = We1[9],  w50 = We1[10], w51 = We1[11];
    float w60 = We1[12], w61 = We1[13];
    float bb0 = be1[0], bb1 = be1[1];
    float m0 = 0.f, m1 = 0.f;
    const int s0 = base[n], s1 = base[n + 1];
    for (int pos = s0 + lane; pos < s1; pos += 64) {
        const float* p = rec + (size_t)pos * 8;
        float4 a = *(const float4*)p;
        float4 b = *(const float4*)(p + 4);
        int s = __float_as_int(b.w);
        float a0 = __low2float(*(__half2*)&a.x);
        float a1 = __low2float(*(__half2*)&a.y);
        float a2 = __low2float(*(__half2*)&a.z);
        float a3 = __low2float(*(__half2*)&a.w);
        float a4 = __low2float(*(__half2*)&b.x);
        float a5 = __low2float(*(__half2*)&b.y);
        float a6 = __low2float(*(__half2*)&b.z);
        float t0 = bb0, t1 = bb1;
        t0 = fmaf(a0, w00, t0); t1 = fmaf(a0, w01, t1);
        t0 = fmaf(a1, w10, t0); t1 = fmaf(a1, w11, t1);
        t0 = fmaf(a2, w20, t0); t1 = fmaf(a2, w21, t1);
        t0 = fmaf(a3, w30, t0); t1 = fmaf(a3, w31, t1);
        t0 = fmaf(a4, w40, t0); t1 = fmaf(a4, w41, t1);
        t0 = fmaf(a5, w50, t0); t1 = fmaf(a5, w51, t1);
        t0 = fmaf(a6, w60, t0); t1 = fmaf(a6, w61, t1);
        float2 xv = *(const float2*)&x[(size_t)s * 2];
        m0 += fmaxf(t0 + xv.x, 0.f);
        m1 += fmaxf(t1 + xv.y, 0.f);
    }
#pragma unroll
    for (int off = 32; off > 0; off >>= 1) {
        m0 += __shfl_down(m0, off);
        m1 += __shfl_down(m1, off);
    }
    m0 = __shfl(m0, 0);
    m1 = __shfl(m1, 0);
    const float t0 = x[n * 2 + 0] + m0;
    const float t1 = x[n * 2 + 1] + m1;
    const int c = lane * 4;
    float4 wa = *(const float4*)&W1[c];
    float4 wb = *(const float4*)&W1[256 + c];
    float4 bv = *(const float4*)&b1[c];
    float4 r;
    r.x = fmaxf(fmaf(t0, wa.x, fmaf(t1, wb.x, bv.x)), 0.f);
    r.y = fmaxf(fmaf(t0, wa.y, fmaf(t1, wb.y, bv.y)), 0.f);
    r.z = fmaxf(fmaf(t0, wa.z, fmaf(t1, wb.z, bv.z)), 0.f);
    r.w = fmaxf(fmaf(t0, wa.w, fmaf(t1, wb.w, bv.w)), 0.f);
    h8[(size_t)n * 64 + lane] = pack4_fp8(r.x, r.y, r.z, r.w);
}

// ------------------------------------------------------------ layers 2..3 ---
// CSR gather from fp8 h (1 dword = 4 channels/lane), packed-fp16 edge MLP,
// fp16 accumulate. One wave/node; ping-pong, 4 edges/group, 8 h-loads in flight.
#define EDGEH(RA, RB, HU)                                              \
    do {                                                               \
        __half2 _a0 = *(__half2*)&RA.x, _a1 = *(__half2*)&RA.y;        \
        __half2 _a2 = *(__half2*)&RA.z, _a3 = *(__half2*)&RA.w;        \
        __half2 _a4 = *(__half2*)&RB.x, _a5 = *(__half2*)&RB.y;        \
        __half2 _a6 = *(__half2*)&RB.z;                                \
        __half2 _m0 = bb01, _m1 = bb23;                                \
        _m0 = __hfma2(_a0, w0a, _m0); _m1 = __hfma2(_a0, w0b, _m1);    \
        _m0 = __hfma2(_a1, w1a, _m0); _m1 = __hfma2(_a1, w1b, _m1);    \
        _m0 = __hfma2(_a2, w2a, _m0); _m1 = __hfma2(_a2, w2b, _m1);    \
        _m0 = __hfma2(_a3, w3a, _m0); _m1 = __hfma2(_a3, w3b, _m1);    \
        _m0 = __hfma2(_a4, w4a, _m0); _m1 = __hfma2(_a4, w4b, _m1);    \
        _m0 = __hfma2(_a5, w5a, _m0); _m1 = __hfma2(_a5, w5b, _m1);    \
        _m0 = __hfma2(_a6, w6a, _m0); _m1 = __hfma2(_a6, w6b, _m1);    \
        v2f _hf0 = __builtin_amdgcn_cvt_pk_f32_fp8((int)(HU), false);  \
        v2f _hf1 = __builtin_amdgcn_cvt_pk_f32_fp8((int)(HU), true);   \
        __half2 _h0 = __float22half2_rn(make_float2(_hf0.x, _hf0.y));  \
        __half2 _h1 = __float22half2_rn(make_float2(_hf1.x, _hf1.y));  \
        _m0 = pk_max2(__hadd2(_m0, _h0), z2);                          \
        _m1 = pk_max2(__hadd2(_m1, _h1), z2);                          \
        acc0 = __hadd2(acc0, _m0);                                     \
        acc1 = __hadd2(acc1, _m1);                                     \
    } while (0)

#define HLOAD(RB) (h8[(size_t)__builtin_amdgcn_readfirstlane(          \
                       __float_as_int(RB.w)) * 64 + lane])

#define LOADG(A0, B0, A1, B1, A2, B2, A3, B3, H0, H1, H2, H3, G)       \
    do {                                                               \
        const float4* _rp = rp + (size_t)(G) * 8;                      \
        A0 = _rp[0]; B0 = _rp[1]; A1 = _rp[2]; B1 = _rp[3];            \
        A2 = _rp[4]; B2 = _rp[5]; A3 = _rp[6]; B3 = _rp[7];            \
        H0 = HLOAD(B0); H1 = HLOAD(B1);                                \
        H2 = HLOAD(B2); H3 = HLOAD(B3);                                \
    } while (0)

#define CONS4(A0, B0, A1, B1, A2, B2, A3, B3, H0, H1, H2, H3)          \
    do {                                                               \
        EDGEH(A0, B0, H0); EDGEH(A1, B1, H1);                          \
        EDGEH(A2, B2, H2); EDGEH(A3, B3, H3);                          \
    } while (0)

__global__ __launch_bounds__(256) void aggr2_kernel(
        const unsigned* __restrict__ h8,  // [N][64] dwords (fp8 x4)
        const float* __restrict__ rec,    // [E][8] dst-sorted packed records
        const int* __restrict__ base,     // [N+1]
        const float* __restrict__ We2,    // [7][256] fp32
        const float* __restrict__ be2,    // [256] fp32
        __half* __restrict__ accum) {     // [N][256] fp16 out
    const int lane = threadIdx.x & 63;
    const int n = blockIdx.x * 4 + (threadIdx.x >> 6);
    if (n >= N_NODES) return;
    const int c4 = lane * 4;
    __half2 w0a = __floats2half2_rn(We2[0 * HID + c4], We2[0 * HID + c4 + 1]);
    __half2 w0b = __floats2half2_rn(We2[0 * HID + c4 + 2], We2[0 * HID + c4 + 3]);
    __half2 w1a = __floats2half2_rn(We2[1 * HID + c4], We2[1 * HID + c4 + 1]);
    __half2 w1b = __floats2half2_rn(We2[1 * HID + c4 + 2], We2[1 * HID + c4 + 3]);
    __half2 w2a = __floats2half2_rn(We2[2 * HID + c4], We2[2 * HID + c4 + 1]);
    __half2 w2b = __floats2half2_rn(We2[2 * HID + c4 + 2], We2[2 * HID + c4 + 3]);
    __half2 w3a = __floats2half2_rn(We2[3 * HID + c4], We2[3 * HID + c4 + 1]);
    __half2 w3b = __floats2half2_rn(We2[3 * HID + c4 + 2], We2[3 * HID + c4 + 3]);
    __half2 w4a = __floats2half2_rn(We2[4 * HID + c4], We2[4 * HID + c4 + 1]);
    __half2 w4b = __floats2half2_rn(We2[4 * HID + c4 + 2], We2[4 * HID + c4 + 3]);
    __half2 w5a = __floats2half2_rn(We2[5 * HID + c4], We2[5 * HID + c4 + 1]);
    __half2 w5b = __floats2half2_rn(We2[5 * HID + c4 + 2], We2[5 * HID + c4 + 3]);
    __half2 w6a = __floats2half2_rn(We2[6 * HID + c4], We2[6 * HID + c4 + 1]);
    __half2 w6b = __floats2half2_rn(We2[6 * HID + c4 + 2], We2[6 * HID + c4 + 3]);
    __half2 bb01 = __floats2half2_rn(be2[c4], be2[c4 + 1]);
    __half2 bb23 = __floats2half2_rn(be2[c4 + 2], be2[c4 + 3]);
    const __half2 z2 = __float2half2_rn(0.f);

    // acc init = h[n] (fp8 -> fp16)
    __half2 acc0, acc1;
    {
        unsigned hv = h8[(size_t)n * 64 + lane];
        v2f f0 = __builtin_amdgcn_cvt_pk_f32_fp8((int)hv, false);
        v2f f1 = __builtin_amdgcn_cvt_pk_f32_fp8((int)hv, true);
        acc0 = __float22half2_rn(make_float2(f0.x, f0.y));
        acc1 = __float22half2_rn(make_float2(f1.x, f1.y));
    }
    const int s0 = __builtin_amdgcn_readfirstlane(base[n]);
    const int deg = __builtin_amdgcn_readfirstlane(base[n + 1]) - s0;
    const float4* rp = (const float4*)rec + (size_t)s0 * 2;
    const int ng = deg >> 2;

    float4 r0a, r0b, r1a, r1b, r2a, r2b, r3a, r3b;
    unsigned rh0, rh1, rh2, rh3;
    float4 t0a, t0b, t1a, t1b, t2a, t2b, t3a, t3b;
    unsigned th0, th1, th2, th3;

    if (ng > 0) {
        LOADG(r0a, r0b, r1a, r1b, r2a, r2b, r3a, r3b, rh0, rh1, rh2, rh3, 0);
        int g = 1;
        for (; g + 1 < ng; g += 2) {
            LOADG(t0a, t0b, t1a, t1b, t2a, t2b, t3a, t3b, th0, th1, th2, th3, g);
            CONS4(r0a, r0b, r1a, r1b, r2a, r2b, r3a, r3b, rh0, rh1, rh2, rh3);
            LOADG(r0a, r0b, r1a, r1b, r2a, r2b, r3a, r3b, rh0, rh1, rh2, rh3, g + 1);
            CONS4(t0a, t0b, t1a, t1b, t2a, t2b, t3a, t3b, th0, th1, th2, th3);
        }
        if (g < ng) {
            LOADG(t0a, t0b, t1a, t1b, t2a, t2b, t3a, t3b, th0, th1, th2, th3, g);
            CONS4(r0a, r0b, r1a, r1b, r2a, r2b, r3a, r3b, rh0, rh1, rh2, rh3);
            CONS4(t0a, t0b, t1a, t1b, t2a, t2b, t3a, t3b, th0, th1, th2, th3);
        } else {
            CONS4(r0a, r0b, r1a, r1b, r2a, r2b, r3a, r3b, rh0, rh1, rh2, rh3);
        }
    }
    for (int i = ng * 4; i < deg; ++i) {   // remainder 0..3 edges
        float4 ra = rp[(size_t)i * 2], rbv = rp[(size_t)i * 2 + 1];
        unsigned hv = HLOAD(rbv);
        EDGEH(ra, rbv, hv);
    }
    float2 of;
    *(__half2*)&of.x = acc0;
    *(__half2*)&of.y = acc1;
    *(float2*)&accum[(size_t)n * HID + c4] = of;
}

// ------------------------------------------------- W2 -> fp16 B-frag swizzle ---
// W2s[((ct*8+kc)*64+lane)*8 + j] = W2[kc*32 + (lane>>4)*8 + j][ct*16 + (lane&15)]
__global__ __launch_bounds__(256) void w2_swizzle_kernel(const float* __restrict__ W,
                                                         __half* __restrict__ W2s) {
    int t = blockIdx.x * 256 + threadIdx.x;   // 16*8*64 = 8192
    if (t >= 16 * 8 * 64) return;
    int lane = t & 63;
    int kc = (t >> 6) & 7;
    int ct = t >> 9;
    int k0 = kc * 32 + (lane >> 4) * 8;
    int col = ct * 16 + (lane & 15);
#pragma unroll
    for (int j = 0; j < 8; ++j)
        W2s[(size_t)t * 8 + j] = __float2half(W[(size_t)(k0 + j) * HID + col]);
}

// ---------------------------------------------------------------- node MLP ---
// relu(A @ W2 + b2) via mfma_f32_16x16x32_f16.
// FUSE_END=false: write h as fp8. FUSE_END=true: fuse the sigmoid head.
template <bool FUSE_END>
__global__ __launch_bounds__(256) void node2_mfma_kernel(
        const __half* __restrict__ A,     // [N][256] fp16 (accum)
        const __half* __restrict__ W2s,   // swizzled B-frags
        const float* __restrict__ b,      // [256]
        unsigned char* __restrict__ h8,   // [N][256] fp8 out (!FUSE_END)
        const float* __restrict__ Wend,   // [256] (FUSE_END)
        const float* __restrict__ bend,   // [1]   (FUSE_END)
        float* __restrict__ out) {        // [N] (FUSE_END)
    const int lane = threadIdx.x & 63;
    const int wv = threadIdx.x >> 6;
    const int n_base = blockIdx.x * 64 + wv * 16;
    if (n_base >= N_NODES) return;
    const int quad = lane >> 4;
    const int mrow = lane & 15;
    // A-frags for all 8 k-chunks: A[m=lane&15][k=quad*8+j]
    f16x8 af[8];
    const __half* ap = A + (size_t)(n_base + mrow) * HID + quad * 8;
#pragma unroll
    for (int kc = 0; kc < 8; ++kc)
        af[kc] = *(const f16x8*)(ap + kc * 32);
    float p0 = 0.f, p1 = 0.f, p2 = 0.f, p3 = 0.f;   // head partials (FUSE_END)
#pragma unroll
    for (int ct = 0; ct < 16; ++ct) {
        f32x4 c = {0.f, 0.f, 0.f, 0.f};
        const f16x8* bp = (const f16x8*)W2s + (size_t)(ct * 8) * 64 + lane;
#pragma unroll
        for (int kc = 0; kc < 8; ++kc)
            c = __builtin_amdgcn_mfma_f32_16x16x32_f16(af[kc], bp[(size_t)kc * 64],
                                                       c, 0, 0, 0);
        const int col = ct * 16 + mrow;            // D col = lane&15
        const float bias = b[col];
        if (!FUSE_END) {
#pragma unroll
            for (int r = 0; r < 4; ++r) {          // D row = quad*4 + r
                int n = n_base + quad * 4 + r;
                float v = fmaxf(c[r] + bias, 0.f);
                int pk = __builtin_amdgcn_cvt_pk_fp8_f32(v, v, 0, false);
                if (n < N_NODES)
                    h8[(size_t)n * HID + col] = (unsigned char)(pk & 0xff);
            }
        } else {
            const float we = Wend[col];
            p0 = fmaf(fmaxf(c[0] + bias, 0.f), we, p0);
            p1 = fmaf(fmaxf(c[1] + bias, 0.f), we, p1);
            p2 = fmaf(fmaxf(c[2] + bias, 0.f), we, p2);
            p3 = fmaf(fmaxf(c[3] + bias, 0.f), we, p3);
        }
    }
    if (FUSE_END) {
        // reduce over the 16 mrow lanes of each quad group
#pragma unroll
        for (int mask = 1; mask < 16; mask <<= 1) {
            p0 += __shfl_xor(p0, mask);
            p1 += __shfl_xor(p1, mask);
            p2 += __shfl_xor(p2, mask);
            p3 += __shfl_xor(p3, mask);
        }
        if (mrow == 0) {
            const float bd = bend[0];
            int n = n_base + quad * 4;
            if (n + 0 < N_NODES) out[n + 0] = 1.f / (1.f + expf(-(p0 + bd)));
            if (n + 1 < N_NODES) out[n + 1] = 1.f / (1.f + expf(-(p1 + bd)));
            if (n + 2 < N_NODES) out[n + 2] = 1.f / (1.f + expf(-(p2 + bd)));
            if (n + 3 < N_NODES) out[n + 3] = 1.f / (1.f + expf(-(p3 + bd)));
        }
    }
}

// ------------------------------------------------------------------ launch ---
extern "C" void kernel_launch(void* const* d_in, const int* in_sizes, int n_in,
                              void* d_out, int out_size, void* d_ws, size_t ws_size,
                              hipStream_t stream) {
    const float* x    = (const float*)d_in[0];
    const int*   ei   = (const int*)d_in[1];
    const float* ea   = (const float*)d_in[2];
    const float* We1  = (const float*)d_in[3];
    const float* be1  = (const float*)d_in[4];
    const float* W1   = (const float*)d_in[5];
    const float* b1   = (const float*)d_in[6];
    const float* We2  = (const float*)d_in[7];
    const float* be2  = (const float*)d_in[8];
    const float* W2   = (const float*)d_in[9];
    const float* b2   = (const float*)d_in[10];
    const float* Wend = (const float*)d_in[11];
    const float* bend = (const float*)d_in[12];
    float* out = (float*)d_out;

    const int* src = ei;
    const int* dst = ei + N_EDGES;

    const size_t HN = (size_t)N_NODES * HID;           // 12.8M elements
    __half*   Bh   = (__half*)d_ws;                    // [N][256] fp16 accum
    unsigned* Ah   = (unsigned*)(Bh + HN);             // [N][64] fp8x4 h
    float*    rec  = (float*)(Ah + (size_t)N_NODES * 64); // [E][8]
    __half*   W2s  = (__half*)(rec + (size_t)N_EDGES * 8);
    int*   deg    = (int*)(W2s + 16 * 8 * 64 * 8);     // [N]
    int*   cursor = deg + N_NODES;                     // [N]
    int*   base   = cursor + N_NODES;                  // [N+2]
    int*   bsum   = base + N_NODES + 2;                // [256]
    // total ≈ 90 MB

    // ---- CSR build + record sort (shared by all 3 layers)
    hipMemsetAsync(deg, 0, (size_t)N_NODES * 2 * sizeof(int), stream);  // deg+cursor
    hist_kernel<<<(N_EDGES + 255) / 256, 256, 0, stream>>>(dst, deg);
    scan1_kernel<<<SCAN_B, 256, 0, stream>>>(deg, bsum);
    scan2_kernel<<<1, 256, 0, stream>>>(bsum);
    scan3_kernel<<<SCAN_B, 256, 0, stream>>>(deg, bsum, base);
    scatter_rec_kernel<<<(N_EDGES + 255) / 256, 256, 0, stream>>>(src, dst, ea, base,
                                                                  cursor, rec);
    w2_swizzle_kernel<<<32, 256, 0, stream>>>(W2, W2s);

    // ---- layer 1 (fused gather + MLP) -> Ah (fp8)
    layer1_kernel<<<(N_NODES + 3) / 4, 256, 0, stream>>>(x, rec, base, We1, be1,
                                                         W1, b1, Ah);

    const int N2_B = (N_NODES + 63) / 64;
    // ---- layer 2
    aggr2_kernel<<<(N_NODES + 3) / 4, 256, 0, stream>>>(Ah, rec, base, We2, be2, Bh);
    node2_mfma_kernel<false><<<N2_B, 256, 0, stream>>>(Bh, W2s, b2,
                                                       (unsigned char*)Ah,
                                                       nullptr, nullptr, nullptr);
    // ---- layer 3 + fused head
    aggr2_kernel<<<(N_NODES + 3) / 4, 256, 0, stream>>>(Ah, rec, base, We2, be2, Bh);
    node2_mfma_kernel<true><<<N2_B, 256, 0, stream>>>(Bh, W2s, b2, nullptr,
                                                      Wend, bend, out);
}

// Round 11
// 536.143 us; speedup vs baseline: 20.8286x; 1.0134x over previous
//
#include <hip/hip_runtime.h>
#include <hip/hip_fp16.h>
#include <math.h>

#define N_NODES 50000
#define N_EDGES 1600000
#define HID 256
#define SCAN_B 196   // ceil(N_NODES/256)
// eps = 0

typedef _Float16 f16x8 __attribute__((ext_vector_type(8)));
typedef float f32x4 __attribute__((ext_vector_type(4)));
typedef float v2f __attribute__((ext_vector_type(2)));

// ROCm 7.2 has no __hmax2 — emit v_pk_max_f16 directly.
static __device__ __forceinline__ __half2 pk_max2(__half2 a, __half2 b) {
    unsigned au = *reinterpret_cast<unsigned*>(&a);
    unsigned bu = *reinterpret_cast<unsigned*>(&b);
    unsigned r;
    asm("v_pk_max_f16 %0, %1, %2" : "=v"(r) : "v"(au), "v"(bu));
    return *reinterpret_cast<__half2*>(&r);
}

// 4 floats -> 4 fp8 (e4m3) packed in one dword
static __device__ __forceinline__ unsigned pack4_fp8(float a, float b, float c, float d) {
    int v = __builtin_amdgcn_cvt_pk_fp8_f32(a, b, 0, false);
    v = __builtin_amdgcn_cvt_pk_fp8_f32(c, d, v, true);
    return (unsigned)v;
}

// ---------------------------------------------------------------- CSR build ---
// 4 edges per thread (strided) — keeps 4 independent memory chains in flight.
__global__ __launch_bounds__(256) void hist_kernel(const int* __restrict__ dst,
                                                   int* __restrict__ deg) {
    const int T = gridDim.x * 256;
    const int t = blockIdx.x * 256 + threadIdx.x;
#pragma unroll
    for (int i = 0; i < 4; ++i) {
        int e = t + i * T;
        if (e < N_EDGES) atomicAdd(&deg[dst[e]], 1);   // no return use: fire&forget
    }
}

__global__ __launch_bounds__(256) void scan1_kernel(const int* __restrict__ deg,
                                                    int* __restrict__ bsum) {
    int idx = blockIdx.x * 256 + threadIdx.x;
    int v = (idx < N_NODES) ? deg[idx] : 0;
#pragma unroll
    for (int off = 32; off > 0; off >>= 1) v += __shfl_down(v, off);
    __shared__ int ws[4];
    if ((threadIdx.x & 63) == 0) ws[threadIdx.x >> 6] = v;
    __syncthreads();
    if (threadIdx.x == 0) bsum[blockIdx.x] = ws[0] + ws[1] + ws[2] + ws[3];
}

__global__ __launch_bounds__(256) void scan2_kernel(int* __restrict__ bsum) {
    __shared__ int s[256];
    int t = threadIdx.x;
    int v = (t < SCAN_B) ? bsum[t] : 0;
    s[t] = v;
    __syncthreads();
    for (int off = 1; off < 256; off <<= 1) {
        int u = (t >= off) ? s[t - off] : 0;
        __syncthreads();
        s[t] += u;
        __syncthreads();
    }
    if (t < SCAN_B) bsum[t] = s[t] - v;  // exclusive
}

__global__ __launch_bounds__(256) void scan3_kernel(const int* __restrict__ deg,
                                                    const int* __restrict__ bsum,
                                                    int* __restrict__ base) {
    __shared__ int s[256];
    int t = threadIdx.x;
    int idx = blockIdx.x * 256 + t;
    int v = (idx < N_NODES) ? deg[idx] : 0;
    s[t] = v;
    __syncthreads();
    for (int off = 1; off < 256; off <<= 1) {
        int u = (t >= off) ? s[t - off] : 0;
        __syncthreads();
        s[t] += u;
        __syncthreads();
    }
    if (idx < N_NODES) base[idx] = bsum[blockIdx.x] + s[t] - v;
    if (idx == 0) base[N_NODES] = N_EDGES;
}

// build one dst-sorted 32B record {half2(a0,a0)..half2(a6,a6), src_bits}
static __device__ __forceinline__ void write_rec(float* __restrict__ rec, int pos,
                                                 const float* __restrict__ ep, int s) {
    float4 v0, v1;
    *(__half2*)&v0.x = __floats2half2_rn(ep[0], ep[0]);
    *(__half2*)&v0.y = __floats2half2_rn(ep[1], ep[1]);
    *(__half2*)&v0.z = __floats2half2_rn(ep[2], ep[2]);
    *(__half2*)&v0.w = __floats2half2_rn(ep[3], ep[3]);
    *(__half2*)&v1.x = __floats2half2_rn(ep[4], ep[4]);
    *(__half2*)&v1.y = __floats2half2_rn(ep[5], ep[5]);
    *(__half2*)&v1.z = __floats2half2_rn(ep[6], ep[6]);
    v1.w = __int_as_float(s);
    float* rp = rec + (size_t)pos * 8;
    *(float4*)rp       = v0;
    *(float4*)(rp + 4) = v1;
}

// 4 edges per thread (strided): 4 independent atomic round-trips + 4 record
// stores in flight. e0..e2 always valid at this grid size; e3 guarded.
__global__ __launch_bounds__(256) void scatter_rec_kernel(
        const int* __restrict__ src,
        const int* __restrict__ dst,
        const float* __restrict__ ea,
        const int* __restrict__ base,
        int* __restrict__ cursor,
        float* __restrict__ rec) {
    const int T = gridDim.x * 256;
    const int t = blockIdx.x * 256 + threadIdx.x;
    const int e0 = t, e1 = t + T, e2 = t + 2 * T, e3 = t + 3 * T;
    const bool v3 = (e3 < N_EDGES);
    int d0 = dst[e0], d1 = dst[e1], d2 = dst[e2];
    int s0 = src[e0], s1 = src[e1], s2 = src[e2];
    int d3 = v3 ? dst[e3] : 0;
    int s3 = v3 ? src[e3] : 0;
    int p0 = base[d0] + atomicAdd(&cursor[d0], 1);
    int p1 = base[d1] + atomicAdd(&cursor[d1], 1);
    int p2 = base[d2] + atomicAdd(&cursor[d2], 1);
    int p3 = v3 ? (base[d3] + atomicAdd(&cursor[d3], 1)) : 0;
    write_rec(rec, p0, ea + (size_t)e0 * 7, s0);
    write_rec(rec, p1, ea + (size_t)e1 * 7, s1);
    write_rec(rec, p2, ea + (size_t)e2 * 7, s2);
    if (v3) write_rec(rec, p3, ea + (size_t)e3 * 7, s3);
}

// ---------------------------------------------------------------- layer 1 ---
// fused gather + node MLP; writes h as fp8 (one dword = lane's 4 channels)
__global__ __launch_bounds__(256) void layer1_kernel(
        const float* __restrict__ x,     // [N][2]
        const float* __restrict__ rec,   // [E][8] (ea as dup'd half2)
        const int* __restrict__ base,    // [N+1]
        const float* __restrict__ We1,   // [7][2]
        const float* __restrict__ be1,   // [2]
        const float* __restrict__ W1,    // [2][256]
        const float* __restrict__ b1,    // [256]
        unsigned* __restrict__ h8) {     // [N][64] dwords (fp8 x4)
    const int lane = threadIdx.x & 63;
    const int wid = threadIdx.x >> 6;
    const int n = blockIdx.x * 4 + wid;
    if (n >= N_NODES) return;
    float w00 = We1[0],  w01 = We1[1],  w10 = We1[2],  w11 = We1[3];
    float w20 = We1[4],  w21 = We1[5],  w30 = We1[6],  w31 = We1[7];
    float w40 = We1[8],  w41 = We1[9],  w50 = We1[10], w51 = We1[11];
    float w60 = We1[12], w61 = We1[13];
    float bb0 = be1[0], bb1 = be1[1];
    float m0 = 0.f, m1 = 0.f;
    const int s0 = base[n], s1 = base[n + 1];
    for (int pos = s0 + lane; pos < s1; pos += 64) {
        const float* p = rec + (size_t)pos * 8;
        float4 a = *(const float4*)p;
        float4 b = *(const float4*)(p + 4);
        int s = __float_as_int(b.w);
        float a0 = __low2float(*(__half2*)&a.x);
        float a1 = __low2float(*(__half2*)&a.y);
        float a2 = __low2float(*(__half2*)&a.z);
        float a3 = __low2float(*(__half2*)&a.w);
        float a4 = __low2float(*(__half2*)&b.x);
        float a5 = __low2float(*(__half2*)&b.y);
        float a6 = __low2float(*(__half2*)&b.z);
        float t0 = bb0, t1 = bb1;
        t0 = fmaf(a0, w00, t0); t1 = fmaf(a0, w01, t1);
        t0 = fmaf(a1, w10, t0); t1 = fmaf(a1, w11, t1);
        t0 = fmaf(a2, w20, t0); t1 = fmaf(a2, w21, t1);
        t0 = fmaf(a3, w30, t0); t1 = fmaf(a3, w31, t1);
        t0 = fmaf(a4, w40, t0); t1 = fmaf(a4, w41, t1);
        t0 = fmaf(a5, w50, t0); t1 = fmaf(a5, w51, t1);
        t0 = fmaf(a6, w60, t0); t1 = fmaf(a6, w61, t1);
        float2 xv = *(const float2*)&x[(size_t)s * 2];
        m0 += fmaxf(t0 + xv.x, 0.f);
        m1 += fmaxf(t1 + xv.y, 0.f);
    }
#pragma unroll
    for (int off = 32; off > 0; off >>= 1) {
        m0 += __shfl_down(m0, off);
        m1 += __shfl_down(m1, off);
    }
    m0 = __shfl(m0, 0);
    m1 = __shfl(m1, 0);
    const float t0 = x[n * 2 + 0] + m0;
    const float t1 = x[n * 2 + 1] + m1;
    const int c = lane * 4;
    float4 wa = *(const float4*)&W1[c];
    float4 wb = *(const float4*)&W1[256 + c];
    float4 bv = *(const float4*)&b1[c];
    float4 r;
    r.x = fmaxf(fmaf(t0, wa.x, fmaf(t1, wb.x, bv.x)), 0.f);
    r.y = fmaxf(fmaf(t0, wa.y, fmaf(t1, wb.y, bv.y)), 0.f);
    r.z = fmaxf(fmaf(t0, wa.z, fmaf(t1, wb.z, bv.z)), 0.f);
    r.w = fmaxf(fmaf(t0, wa.w, fmaf(t1, wb.w, bv.w)), 0.f);
    h8[(size_t)n * 64 + lane] = pack4_fp8(r.x, r.y, r.z, r.w);
}

// ------------------------------------------------------------ layers 2..3 ---
// CSR gather from fp8 h (1 dword = 4 channels/lane), packed-fp16 edge MLP,
// fp16 accumulate. One wave/node; ping-pong, 4 edges/group, 8 h-loads in flight.
#define EDGEH(RA, RB, HU)                                              \
    do {                                                               \
        __half2 _a0 = *(__half2*)&RA.x, _a1 = *(__half2*)&RA.y;        \
        __half2 _a2 = *(__half2*)&RA.z, _a3 = *(__half2*)&RA.w;        \
        __half2 _a4 = *(__half2*)&RB.x, _a5 = *(__half2*)&RB.y;        \
        __half2 _a6 = *(__half2*)&RB.z;                                \
        __half2 _m0 = bb01, _m1 = bb23;                                \
        _m0 = __hfma2(_a0, w0a, _m0); _m1 = __hfma2(_a0, w0b, _m1);    \
        _m0 = __hfma2(_a1, w1a, _m0); _m1 = __hfma2(_a1, w1b, _m1);    \
        _m0 = __hfma2(_a2, w2a, _m0); _m1 = __hfma2(_a2, w2b, _m1);    \
        _m0 = __hfma2(_a3, w3a, _m0); _m1 = __hfma2(_a3, w3b, _m1);    \
        _m0 = __hfma2(_a4, w4a, _m0); _m1 = __hfma2(_a4, w4b, _m1);    \
        _m0 = __hfma2(_a5, w5a, _m0); _m1 = __hfma2(_a5, w5b, _m1);    \
        _m0 = __hfma2(_a6, w6a, _m0); _m1 = __hfma2(_a6, w6b, _m1);    \
        v2f _hf0 = __builtin_amdgcn_cvt_pk_f32_fp8((int)(HU), false);  \
        v2f _hf1 = __builtin_amdgcn_cvt_pk_f32_fp8((int)(HU), true);   \
        __half2 _h0 = __float22half2_rn(make_float2(_hf0.x, _hf0.y));  \
        __half2 _h1 = __float22half2_rn(make_float2(_hf1.x, _hf1.y));  \
        _m0 = pk_max2(__hadd2(_m0, _h0), z2);                          \
        _m1 = pk_max2(__hadd2(_m1, _h1), z2);                          \
        acc0 = __hadd2(acc0, _m0);                                     \
        acc1 = __hadd2(acc1, _m1);                                     \
    } while (0)

#define HLOAD(RB) (h8[(size_t)__builtin_amdgcn_readfirstlane(          \
                       __float_as_int(RB.w)) * 64 + lane])

#define LOADG(A0, B0, A1, B1, A2, B2, A3, B3, H0, H1, H2, H3, G)       \
    do {                                                               \
        const float4* _rp = rp + (size_t)(G) * 8;                      \
        A0 = _rp[0]; B0 = _rp[1]; A1 = _rp[2]; B1 = _rp[3];            \
        A2 = _rp[4]; B2 = _rp[5]; A3 = _rp[6]; B3 = _rp[7];            \
        H0 = HLOAD(B0); H1 = HLOAD(B1);                                \
        H2 = HLOAD(B2); H3 = HLOAD(B3);                                \
    } while (0)

#define CONS4(A0, B0, A1, B1, A2, B2, A3, B3, H0, H1, H2, H3)          \
    do {                                                               \
        EDGEH(A0, B0, H0); EDGEH(A1, B1, H1);                          \
        EDGEH(A2, B2, H2); EDGEH(A3, B3, H3);                          \
    } while (0)

__global__ __launch_bounds__(256) void aggr2_kernel(
        const unsigned* __restrict__ h8,  // [N][64] dwords (fp8 x4)
        const float* __restrict__ rec,    // [E][8] dst-sorted packed records
        const int* __restrict__ base,     // [N+1]
        const float* __restrict__ We2,    // [7][256] fp32
        const float* __restrict__ be2,    // [256] fp32
        __half* __restrict__ accum) {     // [N][256] fp16 out
    const int lane = threadIdx.x & 63;
    const int n = blockIdx.x * 4 + (threadIdx.x >> 6);
    if (n >= N_NODES) return;
    const int c4 = lane * 4;
    __half2 w0a = __floats2half2_rn(We2[0 * HID + c4], We2[0 * HID + c4 + 1]);
    __half2 w0b = __floats2half2_rn(We2[0 * HID + c4 + 2], We2[0 * HID + c4 + 3]);
    __half2 w1a = __floats2half2_rn(We2[1 * HID + c4], We2[1 * HID + c4 + 1]);
    __half2 w1b = __floats2half2_rn(We2[1 * HID + c4 + 2], We2[1 * HID + c4 + 3]);
    __half2 w2a = __floats2half2_rn(We2[2 * HID + c4], We2[2 * HID + c4 + 1]);
    __half2 w2b = __floats2half2_rn(We2[2 * HID + c4 + 2], We2[2 * HID + c4 + 3]);
    __half2 w3a = __floats2half2_rn(We2[3 * HID + c4], We2[3 * HID + c4 + 1]);
    __half2 w3b = __floats2half2_rn(We2[3 * HID + c4 + 2], We2[3 * HID + c4 + 3]);
    __half2 w4a = __floats2half2_rn(We2[4 * HID + c4], We2[4 * HID + c4 + 1]);
    __half2 w4b = __floats2half2_rn(We2[4 * HID + c4 + 2], We2[4 * HID + c4 + 3]);
    __half2 w5a = __floats2half2_rn(We2[5 * HID + c4], We2[5 * HID + c4 + 1]);
    __half2 w5b = __floats2half2_rn(We2[5 * HID + c4 + 2], We2[5 * HID + c4 + 3]);
    __half2 w6a = __floats2half2_rn(We2[6 * HID + c4], We2[6 * HID + c4 + 1]);
    __half2 w6b = __floats2half2_rn(We2[6 * HID + c4 + 2], We2[6 * HID + c4 + 3]);
    __half2 bb01 = __floats2half2_rn(be2[c4], be2[c4 + 1]);
    __half2 bb23 = __floats2half2_rn(be2[c4 + 2], be2[c4 + 3]);
    const __half2 z2 = __float2half2_rn(0.f);

    // acc init = h[n] (fp8 -> fp16)
    __half2 acc0, acc1;
    {
        unsigned hv = h8[(size_t)n * 64 + lane];
        v2f f0 = __builtin_amdgcn_cvt_pk_f32_fp8((int)hv, false);
        v2f f1 = __builtin_amdgcn_cvt_pk_f32_fp8((int)hv, true);
        acc0 = __float22half2_rn(make_float2(f0.x, f0.y));
        acc1 = __float22half2_rn(make_float2(f1.x, f1.y));
    }
    const int s0 = __builtin_amdgcn_readfirstlane(base[n]);
    const int deg = __builtin_amdgcn_readfirstlane(base[n + 1]) - s0;
    const float4* rp = (const float4*)rec + (size_t)s0 * 2;
    const int ng = deg >> 2;

    float4 r0a, r0b, r1a, r1b, r2a, r2b, r3a, r3b;
    unsigned rh0, rh1, rh2, rh3;
    float4 t0a, t0b, t1a, t1b, t2a, t2b, t3a, t3b;
    unsigned th0, th1, th2, th3;

    if (ng > 0) {
        LOADG(r0a, r0b, r1a, r1b, r2a, r2b, r3a, r3b, rh0, rh1, rh2, rh3, 0);
        int g = 1;
        for (; g + 1 < ng; g += 2) {
            LOADG(t0a, t0b, t1a, t1b, t2a, t2b, t3a, t3b, th0, th1, th2, th3, g);
            CONS4(r0a, r0b, r1a, r1b, r2a, r2b, r3a, r3b, rh0, rh1, rh2, rh3);
            LOADG(r0a, r0b, r1a, r1b, r2a, r2b, r3a, r3b, rh0, rh1, rh2, rh3, g + 1);
            CONS4(t0a, t0b, t1a, t1b, t2a, t2b, t3a, t3b, th0, th1, th2, th3);
        }
        if (g < ng) {
            LOADG(t0a, t0b, t1a, t1b, t2a, t2b, t3a, t3b, th0, th1, th2, th3, g);
            CONS4(r0a, r0b, r1a, r1b, r2a, r2b, r3a, r3b, rh0, rh1, rh2, rh3);
            CONS4(t0a, t0b, t1a, t1b, t2a, t2b, t3a, t3b, th0, th1, th2, th3);
        } else {
            CONS4(r0a, r0b, r1a, r1b, r2a, r2b, r3a, r3b, rh0, rh1, rh2, rh3);
        }
    }
    for (int i = ng * 4; i < deg; ++i) {   // remainder 0..3 edges
        float4 ra = rp[(size_t)i * 2], rbv = rp[(size_t)i * 2 + 1];
        unsigned hv = HLOAD(rbv);
        EDGEH(ra, rbv, hv);
    }
    float2 of;
    *(__half2*)&of.x = acc0;
    *(__half2*)&of.y = acc1;
    *(float2*)&accum[(size_t)n * HID + c4] = of;
}

// ------------------------------------------------- W2 -> fp16 B-frag swizzle ---
// W2s[((ct*8+kc)*64+lane)*8 + j] = W2[kc*32 + (lane>>4)*8 + j][ct*16 + (lane&15)]
__global__ __launch_bounds__(256) void w2_swizzle_kernel(const float* __restrict__ W,
                                                         __half* __restrict__ W2s) {
    int t = blockIdx.x * 256 + threadIdx.x;   // 16*8*64 = 8192
    if (t >= 16 * 8 * 64) return;
    int lane = t & 63;
    int kc = (t >> 6) & 7;
    int ct = t >> 9;
    int k0 = kc * 32 + (lane >> 4) * 8;
    int col = ct * 16 + (lane & 15);
#pragma unroll
    for (int j = 0; j < 8; ++j)
        W2s[(size_t)t * 8 + j] = __float2half(W[(size_t)(k0 + j) * HID + col]);
}

// ---------------------------------------------------------------- node MLP ---
// relu(A @ W2 + b2) via mfma_f32_16x16x32_f16.
// FUSE_END=false: write h as fp8. FUSE_END=true: fuse the sigmoid head.
template <bool FUSE_END>
__global__ __launch_bounds__(256) void node2_mfma_kernel(
        const __half* __restrict__ A,     // [N][256] fp16 (accum)
        const __half* __restrict__ W2s,   // swizzled B-frags
        const float* __restrict__ b,      // [256]
        unsigned char* __restrict__ h8,   // [N][256] fp8 out (!FUSE_END)
        const float* __restrict__ Wend,   // [256] (FUSE_END)
        const float* __restrict__ bend,   // [1]   (FUSE_END)
        float* __restrict__ out) {        // [N] (FUSE_END)
    const int lane = threadIdx.x & 63;
    const int wv = threadIdx.x >> 6;
    const int n_base = blockIdx.x * 64 + wv * 16;
    if (n_base >= N_NODES) return;
    const int quad = lane >> 4;
    const int mrow = lane & 15;
    // A-frags for all 8 k-chunks: A[m=lane&15][k=quad*8+j]
    f16x8 af[8];
    const __half* ap = A + (size_t)(n_base + mrow) * HID + quad * 8;
#pragma unroll
    for (int kc = 0; kc < 8; ++kc)
        af[kc] = *(const f16x8*)(ap + kc * 32);
    float p0 = 0.f, p1 = 0.f, p2 = 0.f, p3 = 0.f;   // head partials (FUSE_END)
#pragma unroll
    for (int ct = 0; ct < 16; ++ct) {
        f32x4 c = {0.f, 0.f, 0.f, 0.f};
        const f16x8* bp = (const f16x8*)W2s + (size_t)(ct * 8) * 64 + lane;
#pragma unroll
        for (int kc = 0; kc < 8; ++kc)
            c = __builtin_amdgcn_mfma_f32_16x16x32_f16(af[kc], bp[(size_t)kc * 64],
                                                       c, 0, 0, 0);
        const int col = ct * 16 + mrow;            // D col = lane&15
        const float bias = b[col];
        if (!FUSE_END) {
#pragma unroll
            for (int r = 0; r < 4; ++r) {          // D row = quad*4 + r
                int n = n_base + quad * 4 + r;
                float v = fmaxf(c[r] + bias, 0.f);
                int pk = __builtin_amdgcn_cvt_pk_fp8_f32(v, v, 0, false);
                if (n < N_NODES)
                    h8[(size_t)n * HID + col] = (unsigned char)(pk & 0xff);
            }
        } else {
            const float we = Wend[col];
            p0 = fmaf(fmaxf(c[0] + bias, 0.f), we, p0);
            p1 = fmaf(fmaxf(c[1] + bias, 0.f), we, p1);
            p2 = fmaf(fmaxf(c[2] + bias, 0.f), we, p2);
            p3 = fmaf(fmaxf(c[3] + bias, 0.f), we, p3);
        }
    }
    if (FUSE_END) {
        // reduce over the 16 mrow lanes of each quad group
#pragma unroll
        for (int mask = 1; mask < 16; mask <<= 1) {
            p0 += __shfl_xor(p0, mask);
            p1 += __shfl_xor(p1, mask);
            p2 += __shfl_xor(p2, mask);
            p3 += __shfl_xor(p3, mask);
        }
        if (mrow == 0) {
            const float bd = bend[0];
            int n = n_base + quad * 4;
            if (n + 0 < N_NODES) out[n + 0] = 1.f / (1.f + expf(-(p0 + bd)));
            if (n + 1 < N_NODES) out[n + 1] = 1.f / (1.f + expf(-(p1 + bd)));
            if (n + 2 < N_NODES) out[n + 2] = 1.f / (1.f + expf(-(p2 + bd)));
            if (n + 3 < N_NODES) out[n + 3] = 1.f / (1.f + expf(-(p3 + bd)));
        }
    }
}

// ------------------------------------------------------------------ launch ---
extern "C" void kernel_launch(void* const* d_in, const int* in_sizes, int n_in,
                              void* d_out, int out_size, void* d_ws, size_t ws_size,
                              hipStream_t stream) {
    const float* x    = (const float*)d_in[0];
    const int*   ei   = (const int*)d_in[1];
    const float* ea   = (const float*)d_in[2];
    const float* We1  = (const float*)d_in[3];
    const float* be1  = (const float*)d_in[4];
    const float* W1   = (const float*)d_in[5];
    const float* b1   = (const float*)d_in[6];
    const float* We2  = (const float*)d_in[7];
    const float* be2  = (const float*)d_in[8];
    const float* W2   = (const float*)d_in[9];
    const float* b2   = (const float*)d_in[10];
    const float* Wend = (const float*)d_in[11];
    const float* bend = (const float*)d_in[12];
    float* out = (float*)d_out;

    const int* src = ei;
    const int* dst = ei + N_EDGES;

    const size_t HN = (size_t)N_NODES * HID;           // 12.8M elements
    __half*   Bh   = (__half*)d_ws;                    // [N][256] fp16 accum
    unsigned* Ah   = (unsigned*)(Bh + HN);             // [N][64] fp8x4 h
    float*    rec  = (float*)(Ah + (size_t)N_NODES * 64); // [E][8]
    __half*   W2s  = (__half*)(rec + (size_t)N_EDGES * 8);
    int*   deg    = (int*)(W2s + 16 * 8 * 64 * 8);     // [N]
    int*   cursor = deg + N_NODES;                     // [N]
    int*   base   = cursor + N_NODES;                  // [N+2]
    int*   bsum   = base + N_NODES + 2;                // [256]
    // total ≈ 90 MB

    const int E4_B = (N_EDGES + 4 * 256 - 1) / (4 * 256);   // 1563

    // ---- CSR build + record sort (shared by all 3 layers)
    hipMemsetAsync(deg, 0, (size_t)N_NODES * 2 * sizeof(int), stream);  // deg+cursor
    hist_kernel<<<E4_B, 256, 0, stream>>>(dst, deg);
    scan1_kernel<<<SCAN_B, 256, 0, stream>>>(deg, bsum);
    scan2_kernel<<<1, 256, 0, stream>>>(bsum);
    scan3_kernel<<<SCAN_B, 256, 0, stream>>>(deg, bsum, base);
    scatter_rec_kernel<<<E4_B, 256, 0, stream>>>(src, dst, ea, base, cursor, rec);
    w2_swizzle_kernel<<<32, 256, 0, stream>>>(W2, W2s);

    // ---- layer 1 (fused gather + MLP) -> Ah (fp8)
    layer1_kernel<<<(N_NODES + 3) / 4, 256, 0, stream>>>(x, rec, base, We1, be1,
                                                         W1, b1, Ah);

    const int N2_B = (N_NODES + 63) / 64;
    // ---- layer 2
    aggr2_kernel<<<(N_NODES + 3) / 4, 256, 0, stream>>>(Ah, rec, base, We2, be2, Bh);
    node2_mfma_kernel<false><<<N2_B, 256, 0, stream>>>(Bh, W2s, b2,
                                                       (unsigned char*)Ah,
                                                       nullptr, nullptr, nullptr);
    // ---- layer 3 + fused head
    aggr2_kernel<<<(N_NODES + 3) / 4, 256, 0, stream>>>(Ah, rec, base, We2, be2, Bh);
    node2_mfma_kernel<true><<<N2_B, 256, 0, stream>>>(Bh, W2s, b2, nullptr,
                                                      Wend, bend, out);
}